// Round 2
// baseline (1949.741 us; speedup 1.0000x reference)
//
#include <hip/hip_runtime.h>
#include <hip/hip_bf16.h>

constexpr int N_ = 4096;
constexpr float SQRT_E = 16.0f;                    // sqrt(256)
constexpr float SCALING = 0.17677669529663687f;    // 32^-0.5

// ---------------- K1: g_src [N,3,256], gram [N,1024] ----------------
__global__ __launch_bounds__(256) void k1_pre(
    const float* __restrict__ equ, const float* __restrict__ W_equ,
    const float* __restrict__ W_gproj,
    float* __restrict__ g_src, float* __restrict__ gram)
{
  __shared__ float eq[48];
  __shared__ float gs[768];
  __shared__ float g2p[96];
  const int i = blockIdx.x;
  const int t = threadIdx.x;
  if (t < 48) eq[t] = equ[(size_t)i*48 + t];
  __syncthreads();
  // g_src[i][j][e], e = t, K=16
  #pragma unroll
  for (int j = 0; j < 3; ++j) {
    float s = 0.f;
    #pragma unroll
    for (int m = 0; m < 16; ++m) s += eq[j*16+m] * W_equ[m*256 + t];
    s *= SQRT_E;
    gs[j*256 + t] = s;
    g_src[((size_t)i*3 + j)*256 + t] = s;
  }
  __syncthreads();
  // g2p[j][a] = g_src[i,j,:] @ W_gproj[:,a]
  if (t < 96) {
    const int j = t >> 5, a = t & 31;
    float s = 0.f;
    for (int e = 0; e < 256; ++e) s += gs[j*256+e] * W_gproj[e*32 + a];
    g2p[t] = s;
  }
  __syncthreads();
  // gram[a][b] = sum_j g2p[j][a]*g2p[j][b]
  #pragma unroll
  for (int r = 0; r < 4; ++r) {
    const int idx = r*256 + t;
    const int a = idx >> 5, b = idx & 31;
    const float s = g2p[a]*g2p[b] + g2p[32+a]*g2p[32+b] + g2p[64+a]*g2p[64+b];
    gram[(size_t)i*1024 + idx] = s;
  }
}

// ---------------- K2: gram MLP -> h2 -> q,k,v ; vg -> vext ----------------
__global__ __launch_bounds__(256) void k2_mlp_qkv(
    const float* __restrict__ h, const float* __restrict__ gram,
    const float* __restrict__ g_src,
    const float* __restrict__ W_g1, const float* __restrict__ b_g1,
    const float* __restrict__ W_g2, const float* __restrict__ b_g2,
    const float* __restrict__ W_q, const float* __restrict__ b_q,
    const float* __restrict__ W_k, const float* __restrict__ b_k,
    const float* __restrict__ W_v, const float* __restrict__ b_v,
    const float* __restrict__ W_vg,
    float* __restrict__ q_ws, float* __restrict__ k_ws, float* __restrict__ vext)
{
  __shared__ float gr[1024];
  __shared__ float hid[512];
  __shared__ float h2[512];
  __shared__ float gsl[768];
  const int i = blockIdx.x;
  const int t = threadIdx.x;
  #pragma unroll
  for (int r = 0; r < 4; ++r) gr[r*256+t] = gram[(size_t)i*1024 + r*256 + t];
  #pragma unroll
  for (int r = 0; r < 3; ++r) gsl[r*256+t] = g_src[(size_t)i*768 + r*256 + t];
  h2[256 + t] = h[(size_t)i*256 + t] * SQRT_E;   // h_src half of concat
  __syncthreads();
  // hidden = relu(gram @ W_g1 + b_g1), 512 outputs, K=1024
  {
    float s0 = b_g1[t], s1 = b_g1[t+256];
    for (int kk = 0; kk < 1024; ++kk) {
      const float g = gr[kk];
      s0 += g * W_g1[(size_t)kk*512 + t];
      s1 += g * W_g1[(size_t)kk*512 + t + 256];
    }
    hid[t]     = fmaxf(s0, 0.f);
    hid[t+256] = fmaxf(s1, 0.f);
  }
  __syncthreads();
  // g2 = hidden @ W_g2 + b_g2 -> first half of h2
  {
    float s = b_g2[t];
    for (int kk = 0; kk < 512; ++kk) s += hid[kk] * W_g2[kk*256 + t];
    h2[t] = s;
  }
  __syncthreads();
  const int hh = t >> 5, d = t & 31;
  // q, k, v: K=512 over h2
  {
    float sq = b_q[t], sk = b_k[t], sv = b_v[t];
    for (int kk = 0; kk < 512; ++kk) {
      const float x = h2[kk];
      sq += x * W_q[kk*256 + t];
      sk += x * W_k[kk*256 + t];
      sv += x * W_v[kk*256 + t];
    }
    q_ws[((size_t)hh*N_ + i)*32 + d] = sq * SCALING;
    k_ws[((size_t)hh*N_ + i)*32 + d] = sk;
    vext[((size_t)hh*N_ + i)*128 + d] = sv;          // cols 0..31 = v
  }
  // vg[j] = g_src[i,j,:] @ W_vg -> vext cols 32+32j..63+32j
  {
    float s0 = 0.f, s1 = 0.f, s2 = 0.f;
    for (int e = 0; e < 256; ++e) {
      const float w = W_vg[e*256 + t];
      s0 += gsl[e] * w; s1 += gsl[256+e] * w; s2 += gsl[512+e] * w;
    }
    vext[((size_t)hh*N_ + i)*128 + 32 + d] = s0;
    vext[((size_t)hh*N_ + i)*128 + 64 + d] = s1;
    vext[((size_t)hh*N_ + i)*128 + 96 + d] = s2;
  }
}

// ---------------- K3: flash attention, fused v||vg value (128 cols) ----------------
__global__ __launch_bounds__(256, 2) void k3_attn(
    const float* __restrict__ q_ws, const float* __restrict__ k_ws,
    const float* __restrict__ vext,
    float* __restrict__ out_v, float* __restrict__ out_g)
{
  __shared__ __align__(16) float Kl[1024];     // 32 keys x 32
  __shared__ __align__(16) float Vl[4096];     // 32 keys x 128
  __shared__ float S[64*33];                   // stride 33: bank-conflict pad
  __shared__ float alpha_s[64];
  __shared__ float li_s[64];
  const int t  = threadIdx.x;
  const int q  = t & 63;        // query within tile
  const int wv = t >> 6;        // wave id = 32-col group of the 128-wide value
  const int hh = blockIdx.y;
  const int n0 = blockIdx.x * 64;

  float qreg[32];
  {
    const float* qp = q_ws + ((size_t)hh*N_ + n0 + q)*32;
    #pragma unroll
    for (int dd = 0; dd < 32; ++dd) qreg[dd] = qp[dd];
  }
  float acc[32];
  #pragma unroll
  for (int c = 0; c < 32; ++c) acc[c] = 0.f;
  float mi = -3.0e38f, li = 0.f;

  for (int kt = 0; kt < 128; ++kt) {
    const int m0 = kt * 32;
    {
      const float* kp = k_ws + ((size_t)hh*N_ + m0)*32;
      for (int r = t; r < 1024; r += 256) Kl[r] = kp[r];
      const float* vp = vext + ((size_t)hh*N_ + m0)*128;
      for (int r = t; r < 4096; r += 256) Vl[r] = vp[r];
    }
    __syncthreads();
    // scores: wave wv handles keys m = wv*8 .. wv*8+7
    #pragma unroll
    for (int mm = 0; mm < 8; ++mm) {
      const int m = wv*8 + mm;
      const float4* kr = (const float4*)&Kl[m*32];
      float s = 0.f;
      #pragma unroll
      for (int d4 = 0; d4 < 8; ++d4) {
        const float4 kv = kr[d4];
        s += qreg[d4*4+0]*kv.x + qreg[d4*4+1]*kv.y
           + qreg[d4*4+2]*kv.z + qreg[d4*4+3]*kv.w;
      }
      S[q*33 + m] = s;
    }
    __syncthreads();
    // online softmax per query row (thread t<64 owns row t)
    if (t < 64) {
      float mx = mi;
      #pragma unroll
      for (int m = 0; m < 32; ++m) mx = fmaxf(mx, S[t*33+m]);
      const float al = __expf(mi - mx);
      float sum = 0.f;
      #pragma unroll
      for (int m = 0; m < 32; ++m) {
        const float p = __expf(S[t*33+m] - mx);
        S[t*33+m] = p;
        sum += p;
      }
      li = li*al + sum;
      mi = mx;
      alpha_s[t] = al;
    }
    __syncthreads();
    // acc = alpha*acc + P @ Vtile
    {
      const float al = alpha_s[q];
      #pragma unroll
      for (int c = 0; c < 32; ++c) acc[c] *= al;
      for (int m = 0; m < 32; ++m) {
        const float pm = S[q*33 + m];
        const float4* vr = (const float4*)&Vl[m*128 + wv*32];
        #pragma unroll
        for (int c4 = 0; c4 < 8; ++c4) {
          const float4 vv = vr[c4];
          acc[c4*4+0] += pm*vv.x; acc[c4*4+1] += pm*vv.y;
          acc[c4*4+2] += pm*vv.z; acc[c4*4+3] += pm*vv.w;
        }
      }
    }
    __syncthreads();
  }
  if (t < 64) li_s[t] = li;
  __syncthreads();
  const float linv = 1.0f / li_s[q];
  const int n = n0 + q;
  if (wv == 0) {
    #pragma unroll
    for (int c = 0; c < 32; ++c)
      out_v[(size_t)n*256 + hh*32 + c] = acc[c] * linv;
  } else {
    const int j = wv - 1;
    #pragma unroll
    for (int c = 0; c < 32; ++c)
      out_g[((size_t)n*3 + j)*256 + hh*32 + c] = acc[c] * linv;
  }
}

// ---------------- K4: output projections + residuals -> f32 out ----------------
__global__ __launch_bounds__(256) void k4_out(
    const float* __restrict__ h, const float* __restrict__ g_src,
    const float* __restrict__ out_v, const float* __restrict__ out_g,
    const float* __restrict__ W_ng, const float* __restrict__ b_ng,
    const float* __restrict__ W_gout, const float* __restrict__ W_gdec,
    const float* __restrict__ W_hdec, const float* __restrict__ b_hdec,
    float* __restrict__ out)
{
  __shared__ float ov[256];
  __shared__ float og[768];
  __shared__ float tmp[256];
  __shared__ float gsum[768];
  const int i = blockIdx.x;
  const int t = threadIdx.x;
  ov[t] = out_v[(size_t)i*256 + t];
  #pragma unroll
  for (int r = 0; r < 3; ++r) og[r*256+t] = out_g[(size_t)i*768 + r*256 + t];
  __syncthreads();
  // h path: tmp = h_src + out_v @ W_ng + b_ng
  {
    float s = b_ng[t];
    for (int kk = 0; kk < 256; ++kk) s += ov[kk] * W_ng[kk*256 + t];
    tmp[t] = s + h[(size_t)i*256 + t] * SQRT_E;
  }
  // g path: gsum[j] = g_src[j] + out_g[j] @ W_gout
  {
    float s0 = 0.f, s1 = 0.f, s2 = 0.f;
    for (int kk = 0; kk < 256; ++kk) {
      const float w = W_gout[kk*256 + t];
      s0 += og[kk]*w; s1 += og[256+kk]*w; s2 += og[512+kk]*w;
    }
    gsum[t]       = s0 + g_src[(size_t)i*768 + t];
    gsum[256 + t] = s1 + g_src[(size_t)i*768 + 256 + t];
    gsum[512 + t] = s2 + g_src[(size_t)i*768 + 512 + t];
  }
  __syncthreads();
  // h_out = tmp @ W_hdec + b_hdec
  {
    float s = b_hdec[t];
    for (int kk = 0; kk < 256; ++kk) s += tmp[kk] * W_hdec[kk*256 + t];
    out[196608 + (size_t)i*256 + t] = s;
  }
  // equ_out = gsum @ W_gdec  [3,16]
  if (t < 48) {
    const int j = t >> 4, m = t & 15;
    float s = 0.f;
    for (int e = 0; e < 256; ++e) s += gsum[j*256 + e] * W_gdec[e*16 + m];
    out[(size_t)i*48 + j*16 + m] = s;
  }
}

extern "C" void kernel_launch(void* const* d_in, const int* in_sizes, int n_in,
                              void* d_out, int out_size, void* d_ws, size_t ws_size,
                              hipStream_t stream) {
  const float* equ    = (const float*)d_in[0];
  const float* h      = (const float*)d_in[1];
  // d_in[2] edge_index, d_in[3] edge_fea: dead args in the reference
  const float* W_equ  = (const float*)d_in[4];
  const float* W_gproj= (const float*)d_in[5];
  const float* W_vg   = (const float*)d_in[6];
  const float* W_g1   = (const float*)d_in[7];
  const float* b_g1   = (const float*)d_in[8];
  const float* W_g2   = (const float*)d_in[9];
  const float* b_g2   = (const float*)d_in[10];
  const float* W_q    = (const float*)d_in[11];
  const float* b_q    = (const float*)d_in[12];
  const float* W_k    = (const float*)d_in[13];
  const float* b_k    = (const float*)d_in[14];
  const float* W_v    = (const float*)d_in[15];
  const float* b_v    = (const float*)d_in[16];
  const float* W_ng   = (const float*)d_in[17];
  const float* b_ng   = (const float*)d_in[18];
  const float* W_gout = (const float*)d_in[19];
  const float* W_gdec = (const float*)d_in[20];
  const float* W_hdec = (const float*)d_in[21];
  const float* b_hdec = (const float*)d_in[22];
  float* out = (float*)d_out;

  // workspace layout (floats):
  float* ws    = (float*)d_ws;
  float* g_src = ws;                  // [4096*3*256]  = 3,145,728
  float* gram  = ws + 3145728;        // [4096*1024]   = 4,194,304
  float* q_ws  = ws + 7340032;        // [8][4096][32] = 1,048,576
  float* k_ws  = ws + 8388608;        // [8][4096][32] = 1,048,576
  float* vext  = ws + 9437184;        // [8][4096][128]= 4,194,304
  // out_v/out_g alias gram (gram fully consumed by k2 before k3 writes):
  float* out_v = gram;                // [4096*256]
  float* out_g = gram + 1048576;      // [4096*3*256]
  // total ws use: 13,631,488 floats = 52 MiB

  k1_pre<<<4096, 256, 0, stream>>>(equ, W_equ, W_gproj, g_src, gram);
  k2_mlp_qkv<<<4096, 256, 0, stream>>>(h, gram, g_src,
                                       W_g1, b_g1, W_g2, b_g2,
                                       W_q, b_q, W_k, b_k, W_v, b_v,
                                       W_vg, q_ws, k_ws, vext);
  dim3 g3(64, 8);
  k3_attn<<<g3, 256, 0, stream>>>(q_ws, k_ws, vext, out_v, out_g);
  k4_out<<<4096, 256, 0, stream>>>(h, g_src, out_v, out_g,
                                   W_ng, b_ng, W_gout, W_gdec, W_hdec, b_hdec,
                                   out);
}

// Round 3
// 1007.724 us; speedup vs baseline: 1.9348x; 1.9348x over previous
//
#include <hip/hip_runtime.h>
#include <hip/hip_bf16.h>

typedef __attribute__((ext_vector_type(8))) short short8;
typedef __attribute__((ext_vector_type(4))) float floatx4;

constexpr int N_ = 4096;
constexpr float SQRT_E = 16.0f;                    // sqrt(256)
constexpr float SCALING = 0.17677669529663687f;    // 32^-0.5

__device__ __forceinline__ ushort f2bf(float x) {
  __hip_bfloat16 h = __float2bfloat16(x);
  return *reinterpret_cast<ushort*>(&h);
}
__device__ __forceinline__ float bf2f(ushort b) {
  unsigned int u = ((unsigned int)b) << 16;
  return __uint_as_float(u);
}

// ---------------- K1: g_src [N,3,256], gram [N,1024] ----------------
__global__ __launch_bounds__(256) void k1_pre(
    const float* __restrict__ equ, const float* __restrict__ W_equ,
    const float* __restrict__ W_gproj,
    float* __restrict__ g_src, float* __restrict__ gram)
{
  __shared__ float eq[48];
  __shared__ float gs[768];
  __shared__ float g2p[96];
  const int i = blockIdx.x;
  const int t = threadIdx.x;
  if (t < 48) eq[t] = equ[(size_t)i*48 + t];
  __syncthreads();
  #pragma unroll
  for (int j = 0; j < 3; ++j) {
    float s = 0.f;
    #pragma unroll
    for (int m = 0; m < 16; ++m) s += eq[j*16+m] * W_equ[m*256 + t];
    s *= SQRT_E;
    gs[j*256 + t] = s;
    g_src[((size_t)i*3 + j)*256 + t] = s;
  }
  __syncthreads();
  if (t < 96) {
    const int j = t >> 5, a = t & 31;
    float s = 0.f;
    for (int e = 0; e < 256; ++e) s += gs[j*256+e] * W_gproj[e*32 + a];
    g2p[t] = s;
  }
  __syncthreads();
  #pragma unroll
  for (int r = 0; r < 4; ++r) {
    const int idx = r*256 + t;
    const int a = idx >> 5, b = idx & 31;
    const float s = g2p[a]*g2p[b] + g2p[32+a]*g2p[32+b] + g2p[64+a]*g2p[64+b];
    gram[(size_t)i*1024 + idx] = s;
  }
}

// ---------------- K2: gram MLP -> h2 -> q,k,v ; vg -> vext ----------------
__global__ __launch_bounds__(256) void k2_mlp_qkv(
    const float* __restrict__ h, const float* __restrict__ gram,
    const float* __restrict__ g_src,
    const float* __restrict__ W_g1, const float* __restrict__ b_g1,
    const float* __restrict__ W_g2, const float* __restrict__ b_g2,
    const float* __restrict__ W_q, const float* __restrict__ b_q,
    const float* __restrict__ W_k, const float* __restrict__ b_k,
    const float* __restrict__ W_v, const float* __restrict__ b_v,
    const float* __restrict__ W_vg,
    float* __restrict__ q_ws, float* __restrict__ k_ws, float* __restrict__ vext)
{
  __shared__ float gr[1024];
  __shared__ float hid[512];
  __shared__ float h2[512];
  __shared__ float gsl[768];
  const int i = blockIdx.x;
  const int t = threadIdx.x;
  #pragma unroll
  for (int r = 0; r < 4; ++r) gr[r*256+t] = gram[(size_t)i*1024 + r*256 + t];
  #pragma unroll
  for (int r = 0; r < 3; ++r) gsl[r*256+t] = g_src[(size_t)i*768 + r*256 + t];
  h2[256 + t] = h[(size_t)i*256 + t] * SQRT_E;
  __syncthreads();
  {
    float s0 = b_g1[t], s1 = b_g1[t+256];
    for (int kk = 0; kk < 1024; ++kk) {
      const float g = gr[kk];
      s0 += g * W_g1[(size_t)kk*512 + t];
      s1 += g * W_g1[(size_t)kk*512 + t + 256];
    }
    hid[t]     = fmaxf(s0, 0.f);
    hid[t+256] = fmaxf(s1, 0.f);
  }
  __syncthreads();
  {
    float s = b_g2[t];
    for (int kk = 0; kk < 512; ++kk) s += hid[kk] * W_g2[kk*256 + t];
    h2[t] = s;
  }
  __syncthreads();
  const int hh = t >> 5, d = t & 31;
  {
    float sq = b_q[t], sk = b_k[t], sv = b_v[t];
    for (int kk = 0; kk < 512; ++kk) {
      const float x = h2[kk];
      sq += x * W_q[kk*256 + t];
      sk += x * W_k[kk*256 + t];
      sv += x * W_v[kk*256 + t];
    }
    q_ws[((size_t)hh*N_ + i)*32 + d] = sq * SCALING;
    k_ws[((size_t)hh*N_ + i)*32 + d] = sk;
    vext[((size_t)hh*N_ + i)*128 + d] = sv;
  }
  {
    float s0 = 0.f, s1 = 0.f, s2 = 0.f;
    for (int e = 0; e < 256; ++e) {
      const float w = W_vg[e*256 + t];
      s0 += gsl[e] * w; s1 += gsl[256+e] * w; s2 += gsl[512+e] * w;
    }
    vext[((size_t)hh*N_ + i)*128 + 32 + d] = s0;
    vext[((size_t)hh*N_ + i)*128 + 64 + d] = s1;
    vext[((size_t)hh*N_ + i)*128 + 96 + d] = s2;
  }
}

// ---------------- K3: MFMA flash attention, fused v||vg value (128 cols) --------
// Per block: 64 q-rows x 1 head. 4 waves x 16 q-rows. K-tiles of 64 keys.
// QK^T: bf16 MFMA with hi/lo split of Q and K (precision: logits sigma~52,
// near-one-hot softmax needs <~1e-2 logit error; raw bf16 would give ~0.2).
// LDS strides: 40 (rows of 32) / 72 (rows of 64) elements -> 16B-aligned b128.
__global__ __launch_bounds__(256, 2) void k3_attn(
    const float* __restrict__ q_ws, const float* __restrict__ k_ws,
    const float* __restrict__ vext,
    float* __restrict__ out_v, float* __restrict__ out_g)
{
  __shared__ __align__(16) ushort Qh[64*40], Qlo[64*40];
  __shared__ __align__(16) ushort Kh[64*40], Klo[64*40];
  __shared__ __align__(16) ushort Vt[128*72];      // Vt[col][key]
  __shared__ __align__(16) ushort Pl[4*16*72];     // per-wave P rows

  const int t    = threadIdx.x;
  const int wave = t >> 6;
  const int lane = t & 63;
  const int quad = lane >> 4;
  const int m    = lane & 15;
  const int h    = blockIdx.y;
  const int n0q  = blockIdx.x * 64;

  // ---- stage Q (hi/lo bf16 split) ----
  #pragma unroll
  for (int r = 0; r < 4; ++r) {
    const int p = r*256 + t;
    const int row = p >> 4, dp = p & 15;
    const float2 qv = *(const float2*)&q_ws[((size_t)h*N_ + n0q + row)*32 + dp*2];
    const ushort h0 = f2bf(qv.x), h1 = f2bf(qv.y);
    const ushort l0 = f2bf(qv.x - bf2f(h0)), l1 = f2bf(qv.y - bf2f(h1));
    *(unsigned int*)&Qh[row*40 + dp*2]  = (unsigned int)h0 | ((unsigned int)h1 << 16);
    *(unsigned int*)&Qlo[row*40 + dp*2] = (unsigned int)l0 | ((unsigned int)l1 << 16);
  }
  __syncthreads();
  const short8 aqh = *(const short8*)&Qh[(wave*16 + m)*40 + quad*8];
  const short8 aql = *(const short8*)&Qlo[(wave*16 + m)*40 + quad*8];

  floatx4 Of[8];
  #pragma unroll
  for (int nt = 0; nt < 8; ++nt) Of[nt] = {0.f, 0.f, 0.f, 0.f};
  float mi[4], li[4];
  #pragma unroll
  for (int r = 0; r < 4; ++r) { mi[r] = -3.0e38f; li[r] = 0.f; }

  for (int kt = 0; kt < 64; ++kt) {
    const int n0k = kt * 64;
    __syncthreads();   // previous iteration's reads of Kh/Klo/Vt complete
    // ---- stage K tile (hi/lo split) ----
    #pragma unroll
    for (int r = 0; r < 4; ++r) {
      const int p = r*256 + t;
      const int row = p >> 4, dp = p & 15;
      const float2 kv = *(const float2*)&k_ws[((size_t)h*N_ + n0k + row)*32 + dp*2];
      const ushort h0 = f2bf(kv.x), h1 = f2bf(kv.y);
      const ushort l0 = f2bf(kv.x - bf2f(h0)), l1 = f2bf(kv.y - bf2f(h1));
      *(unsigned int*)&Kh[row*40 + dp*2]  = (unsigned int)h0 | ((unsigned int)h1 << 16);
      *(unsigned int*)&Klo[row*40 + dp*2] = (unsigned int)l0 | ((unsigned int)l1 << 16);
    }
    // ---- stage V tile transposed: Vt[col][key] ----
    #pragma unroll
    for (int r = 0; r < 32; ++r) {
      const int idx = r*256 + t;
      const int key = idx >> 7, col = idx & 127;
      const float vv = vext[((size_t)h*N_ + n0k + key)*128 + col];
      Vt[col*72 + key] = f2bf(vv);
    }
    __syncthreads();

    // ---- S = Q K^T (3-term hi/lo MFMA) ----
    floatx4 sf[4];
    #pragma unroll
    for (int kb = 0; kb < 4; ++kb) {
      const short8 bkh = *(const short8*)&Kh[(kb*16 + m)*40 + quad*8];
      const short8 bkl = *(const short8*)&Klo[(kb*16 + m)*40 + quad*8];
      floatx4 s = {0.f, 0.f, 0.f, 0.f};
      s = __builtin_amdgcn_mfma_f32_16x16x32_bf16(aqh, bkl, s, 0, 0, 0);
      s = __builtin_amdgcn_mfma_f32_16x16x32_bf16(aql, bkh, s, 0, 0, 0);
      s = __builtin_amdgcn_mfma_f32_16x16x32_bf16(aqh, bkh, s, 0, 0, 0);
      sf[kb] = s;
    }

    // ---- online softmax (rows = quad*4+reg, cols = kb*16 + m) ----
    float nm[4];
    #pragma unroll
    for (int r = 0; r < 4; ++r) {
      nm[r] = fmaxf(fmaxf(sf[0][r], sf[1][r]), fmaxf(sf[2][r], sf[3][r]));
      #pragma unroll
      for (int x = 1; x < 16; x <<= 1)
        nm[r] = fmaxf(nm[r], __shfl_xor(nm[r], x, 64));
    }
    float al[4];
    float p[4][4];
    #pragma unroll
    for (int r = 0; r < 4; ++r) {
      const float mn = fmaxf(mi[r], nm[r]);
      al[r] = __expf(mi[r] - mn);
      mi[r] = mn;
      float rs = 0.f;
      #pragma unroll
      for (int kb = 0; kb < 4; ++kb) {
        const float pv = __expf(sf[kb][r] - mn);
        p[kb][r] = pv;
        rs += pv;
      }
      #pragma unroll
      for (int x = 1; x < 16; x <<= 1) rs += __shfl_xor(rs, x, 64);
      li[r] = li[r]*al[r] + rs;
    }
    // rescale accumulators (same row mapping as C-layout)
    #pragma unroll
    for (int nt = 0; nt < 8; ++nt)
      #pragma unroll
      for (int r = 0; r < 4; ++r) Of[nt][r] *= al[r];
    // write P (bf16) to per-wave LDS in A-operand-friendly row-major
    #pragma unroll
    for (int kb = 0; kb < 4; ++kb)
      #pragma unroll
      for (int r = 0; r < 4; ++r)
        Pl[wave*1152 + (quad*4 + r)*72 + kb*16 + m] = f2bf(p[kb][r]);

    // ---- O += P @ V  (A = P [16 x 64], B = Vt [64 x 128]) ----
    #pragma unroll
    for (int ks = 0; ks < 2; ++ks) {
      const short8 ap = *(const short8*)&Pl[wave*1152 + m*72 + ks*32 + quad*8];
      #pragma unroll
      for (int nt = 0; nt < 8; ++nt) {
        const short8 bv = *(const short8*)&Vt[(nt*16 + m)*72 + ks*32 + quad*8];
        Of[nt] = __builtin_amdgcn_mfma_f32_16x16x32_bf16(ap, bv, Of[nt], 0, 0, 0);
      }
    }
  }

  // ---- normalize + write out ----
  float linv[4];
  #pragma unroll
  for (int r = 0; r < 4; ++r) linv[r] = 1.0f / li[r];
  #pragma unroll
  for (int nt = 0; nt < 8; ++nt) {
    #pragma unroll
    for (int r = 0; r < 4; ++r) {
      const float val = Of[nt][r] * linv[r];
      const int n = n0q + wave*16 + quad*4 + r;
      const int c = nt*16 + m;
      if (c < 32) {
        out_v[(size_t)n*256 + h*32 + c] = val;
      } else {
        const int j = (c - 32) >> 5, cc = (c - 32) & 31;
        out_g[((size_t)n*3 + j)*256 + h*32 + cc] = val;
      }
    }
  }
}

// ---------------- K4: output projections + residuals -> f32 out ----------------
__global__ __launch_bounds__(256) void k4_out(
    const float* __restrict__ h, const float* __restrict__ g_src,
    const float* __restrict__ out_v, const float* __restrict__ out_g,
    const float* __restrict__ W_ng, const float* __restrict__ b_ng,
    const float* __restrict__ W_gout, const float* __restrict__ W_gdec,
    const float* __restrict__ W_hdec, const float* __restrict__ b_hdec,
    float* __restrict__ out)
{
  __shared__ float ov[256];
  __shared__ float og[768];
  __shared__ float tmp[256];
  __shared__ float gsum[768];
  const int i = blockIdx.x;
  const int t = threadIdx.x;
  ov[t] = out_v[(size_t)i*256 + t];
  #pragma unroll
  for (int r = 0; r < 3; ++r) og[r*256+t] = out_g[(size_t)i*768 + r*256 + t];
  __syncthreads();
  {
    float s = b_ng[t];
    for (int kk = 0; kk < 256; ++kk) s += ov[kk] * W_ng[kk*256 + t];
    tmp[t] = s + h[(size_t)i*256 + t] * SQRT_E;
  }
  {
    float s0 = 0.f, s1 = 0.f, s2 = 0.f;
    for (int kk = 0; kk < 256; ++kk) {
      const float w = W_gout[kk*256 + t];
      s0 += og[kk]*w; s1 += og[256+kk]*w; s2 += og[512+kk]*w;
    }
    gsum[t]       = s0 + g_src[(size_t)i*768 + t];
    gsum[256 + t] = s1 + g_src[(size_t)i*768 + 256 + t];
    gsum[512 + t] = s2 + g_src[(size_t)i*768 + 512 + t];
  }
  __syncthreads();
  {
    float s = b_hdec[t];
    for (int kk = 0; kk < 256; ++kk) s += tmp[kk] * W_hdec[kk*256 + t];
    out[196608 + (size_t)i*256 + t] = s;
  }
  if (t < 48) {
    const int j = t >> 4, m = t & 15;
    float s = 0.f;
    for (int e = 0; e < 256; ++e) s += gsum[j*256 + e] * W_gdec[e*16 + m];
    out[(size_t)i*48 + j*16 + m] = s;
  }
}

extern "C" void kernel_launch(void* const* d_in, const int* in_sizes, int n_in,
                              void* d_out, int out_size, void* d_ws, size_t ws_size,
                              hipStream_t stream) {
  const float* equ    = (const float*)d_in[0];
  const float* h      = (const float*)d_in[1];
  // d_in[2] edge_index, d_in[3] edge_fea: dead args in the reference
  const float* W_equ  = (const float*)d_in[4];
  const float* W_gproj= (const float*)d_in[5];
  const float* W_vg   = (const float*)d_in[6];
  const float* W_g1   = (const float*)d_in[7];
  const float* b_g1   = (const float*)d_in[8];
  const float* W_g2   = (const float*)d_in[9];
  const float* b_g2   = (const float*)d_in[10];
  const float* W_q    = (const float*)d_in[11];
  const float* b_q    = (const float*)d_in[12];
  const float* W_k    = (const float*)d_in[13];
  const float* b_k    = (const float*)d_in[14];
  const float* W_v    = (const float*)d_in[15];
  const float* b_v    = (const float*)d_in[16];
  const float* W_ng   = (const float*)d_in[17];
  const float* b_ng   = (const float*)d_in[18];
  const float* W_gout = (const float*)d_in[19];
  const float* W_gdec = (const float*)d_in[20];
  const float* W_hdec = (const float*)d_in[21];
  const float* b_hdec = (const float*)d_in[22];
  float* out = (float*)d_out;

  float* ws    = (float*)d_ws;
  float* g_src = ws;                  // [4096*3*256]  = 3,145,728
  float* gram  = ws + 3145728;        // [4096*1024]   = 4,194,304
  float* q_ws  = ws + 7340032;        // [8][4096][32] = 1,048,576
  float* k_ws  = ws + 8388608;        // [8][4096][32] = 1,048,576
  float* vext  = ws + 9437184;        // [8][4096][128]= 4,194,304
  float* out_v = gram;                // alias: gram consumed by k2 before k3 writes
  float* out_g = gram + 1048576;

  k1_pre<<<4096, 256, 0, stream>>>(equ, W_equ, W_gproj, g_src, gram);
  k2_mlp_qkv<<<4096, 256, 0, stream>>>(h, gram, g_src,
                                       W_g1, b_g1, W_g2, b_g2,
                                       W_q, b_q, W_k, b_k, W_v, b_v,
                                       W_vg, q_ws, k_ws, vext);
  dim3 g3(64, 8);
  k3_attn<<<g3, 256, 0, stream>>>(q_ws, k_ws, vext, out_v, out_g);
  k4_out<<<4096, 256, 0, stream>>>(h, g_src, out_v, out_g,
                                   W_ng, b_ng, W_gout, W_gdec, W_hdec, b_hdec,
                                   out);
}

// Round 4
// 518.013 us; speedup vs baseline: 3.7639x; 1.9454x over previous
//
#include <hip/hip_runtime.h>
#include <hip/hip_bf16.h>

typedef __attribute__((ext_vector_type(8))) short short8;
typedef __attribute__((ext_vector_type(4))) float floatx4;

constexpr int N_ = 4096;
constexpr float SQRT_E = 16.0f;
constexpr float SCALING = 0.17677669529663687f;    // 32^-0.5

__device__ __forceinline__ ushort f2bf(float x) {
  __hip_bfloat16 h = __float2bfloat16(x);
  return *reinterpret_cast<ushort*>(&h);
}
__device__ __forceinline__ float bf2f(ushort b) {
  unsigned int u = ((unsigned int)b) << 16;
  return __uint_as_float(u);
}

// ---------------- K1: g_src_b [N*3,256]bf16, gram_b [N,1024]bf16 ----------------
__global__ __launch_bounds__(256) void k1_pre(
    const float* __restrict__ equ, const float* __restrict__ W_equ,
    const float* __restrict__ W_gproj,
    ushort* __restrict__ g_src_b, ushort* __restrict__ gram_b)
{
  __shared__ float eq[48];
  __shared__ float gs[768];
  __shared__ float g2p[96];
  const int i = blockIdx.x;
  const int t = threadIdx.x;
  if (t < 48) eq[t] = equ[(size_t)i*48 + t];
  __syncthreads();
  #pragma unroll
  for (int j = 0; j < 3; ++j) {
    float s = 0.f;
    #pragma unroll
    for (int m = 0; m < 16; ++m) s += eq[j*16+m] * W_equ[m*256 + t];
    s *= SQRT_E;
    gs[j*256 + t] = s;
    g_src_b[((size_t)i*3 + j)*256 + t] = f2bf(s);
  }
  __syncthreads();
  if (t < 96) {
    const int j = t >> 5, a = t & 31;
    float s = 0.f;
    for (int e = 0; e < 256; ++e) s += gs[j*256+e] * W_gproj[e*32 + a];
    g2p[t] = s;
  }
  __syncthreads();
  #pragma unroll
  for (int r = 0; r < 4; ++r) {
    const int idx = r*256 + t;
    const int a = idx >> 5, b = idx & 31;
    const float s = g2p[a]*g2p[b] + g2p[32+a]*g2p[32+b] + g2p[64+a]*g2p[64+b];
    gram_b[(size_t)i*1024 + idx] = f2bf(s);
  }
}

// ---------------- prep: weight transpose + bf16 (optional hi/lo) ----------------
// src [R][C] f32 -> dst [C][R] bf16 (dst row length R)
__global__ __launch_bounds__(256) void k_transpose(
    const float* __restrict__ src, ushort* __restrict__ dsth,
    ushort* __restrict__ dstl, int R, int C, int hasLo)
{
  __shared__ float tile[32][33];
  const int r0 = blockIdx.x * 32, c0 = blockIdx.y * 32;
  const int tx = threadIdx.x & 31, ty = threadIdx.x >> 5;
  #pragma unroll
  for (int p = 0; p < 4; ++p) {
    const int lr = p*8 + ty;
    tile[lr][tx] = src[(size_t)(r0+lr)*C + c0 + tx];
  }
  __syncthreads();
  #pragma unroll
  for (int p = 0; p < 4; ++p) {
    const int dc = p*8 + ty;
    const float v = tile[tx][dc];
    const ushort hi = f2bf(v);
    dsth[(size_t)(c0+dc)*R + r0 + tx] = hi;
    if (hasLo) dstl[(size_t)(c0+dc)*R + r0 + tx] = f2bf(v - bf2f(hi));
  }
}

// h_src half of h2 (cols 256..511), hi/lo split of h*16
__global__ __launch_bounds__(256) void k_hsplit(
    const float* __restrict__ h, ushort* __restrict__ h2h, ushort* __restrict__ h2l)
{
  const int i = blockIdx.x, t = threadIdx.x;
  const float v = h[(size_t)i*256 + t] * SQRT_E;
  const ushort hi = f2bf(v);
  h2h[(size_t)i*512 + 256 + t] = hi;
  h2l[(size_t)i*512 + 256 + t] = f2bf(v - bf2f(hi));
}

// ---------------- shared GEMM core: C[64x64] = A[64xK] * Bt[64xK]^T ----------------
// A row-major [M][K] bf16, Bt row-major [N][K] bf16 (pre-transposed weights).
template<int KTOT>
__device__ __forceinline__ void gemm_core(
    const ushort* __restrict__ A, const ushort* __restrict__ Bt,
    int bM, int bN, floatx4 acc[4], ushort* As, ushort* Bs)
{
  const int t = threadIdx.x;
  const int wave = t >> 6, lane = t & 63, quad = lane >> 4, m = lane & 15;
  #pragma unroll
  for (int ct = 0; ct < 4; ++ct) acc[ct] = {0.f, 0.f, 0.f, 0.f};
  const int row = t >> 2, kq = (t & 3) * 8;
  for (int k0 = 0; k0 < KTOT; k0 += 32) {
    __syncthreads();
    *(short8*)&As[row*40 + kq] = *(const short8*)&A[(size_t)(bM+row)*KTOT + k0 + kq];
    *(short8*)&Bs[row*40 + kq] = *(const short8*)&Bt[(size_t)(bN+row)*KTOT + k0 + kq];
    __syncthreads();
    const short8 af = *(const short8*)&As[(wave*16 + m)*40 + quad*8];
    #pragma unroll
    for (int ct = 0; ct < 4; ++ct) {
      const short8 bf = *(const short8*)&Bs[(ct*16 + m)*40 + quad*8];
      acc[ct] = __builtin_amdgcn_mfma_f32_16x16x32_bf16(af, bf, acc[ct], 0, 0, 0);
    }
  }
}

// 3-term hi/lo core (for q/k/v precision)
template<int KTOT>
__device__ __forceinline__ void gemm_core3(
    const ushort* __restrict__ Ah, const ushort* __restrict__ Al,
    const ushort* __restrict__ Bth, const ushort* __restrict__ Btl,
    int bM, int bN, floatx4 acc[4],
    ushort* Ash, ushort* Asl, ushort* Bsh, ushort* Bsl)
{
  const int t = threadIdx.x;
  const int wave = t >> 6, lane = t & 63, quad = lane >> 4, m = lane & 15;
  #pragma unroll
  for (int ct = 0; ct < 4; ++ct) acc[ct] = {0.f, 0.f, 0.f, 0.f};
  const int row = t >> 2, kq = (t & 3) * 8;
  for (int k0 = 0; k0 < KTOT; k0 += 32) {
    __syncthreads();
    *(short8*)&Ash[row*40 + kq] = *(const short8*)&Ah[(size_t)(bM+row)*KTOT + k0 + kq];
    *(short8*)&Asl[row*40 + kq] = *(const short8*)&Al[(size_t)(bM+row)*KTOT + k0 + kq];
    *(short8*)&Bsh[row*40 + kq] = *(const short8*)&Bth[(size_t)(bN+row)*KTOT + k0 + kq];
    *(short8*)&Bsl[row*40 + kq] = *(const short8*)&Btl[(size_t)(bN+row)*KTOT + k0 + kq];
    __syncthreads();
    const short8 ah = *(const short8*)&Ash[(wave*16 + m)*40 + quad*8];
    const short8 al = *(const short8*)&Asl[(wave*16 + m)*40 + quad*8];
    #pragma unroll
    for (int ct = 0; ct < 4; ++ct) {
      const short8 bh = *(const short8*)&Bsh[(ct*16 + m)*40 + quad*8];
      const short8 bl = *(const short8*)&Bsl[(ct*16 + m)*40 + quad*8];
      acc[ct] = __builtin_amdgcn_mfma_f32_16x16x32_bf16(ah, bl, acc[ct], 0, 0, 0);
      acc[ct] = __builtin_amdgcn_mfma_f32_16x16x32_bf16(al, bh, acc[ct], 0, 0, 0);
      acc[ct] = __builtin_amdgcn_mfma_f32_16x16x32_bf16(ah, bh, acc[ct], 0, 0, 0);
    }
  }
}

// G1: hidden = relu(gram @ W_g1 + b_g1) -> bf16 [4096][512]
__global__ __launch_bounds__(256) void k_g1(
    const ushort* __restrict__ gram_b, const ushort* __restrict__ Wg1t,
    const float* __restrict__ b_g1, ushort* __restrict__ hidden)
{
  __shared__ __align__(16) ushort As[64*40], Bs[64*40];
  floatx4 acc[4];
  const int bM = blockIdx.x*64, bN = blockIdx.y*64;
  gemm_core<1024>(gram_b, Wg1t, bM, bN, acc, As, Bs);
  const int lane = threadIdx.x & 63, wave = threadIdx.x >> 6;
  const int quad = lane >> 4, m = lane & 15;
  #pragma unroll
  for (int ct = 0; ct < 4; ++ct) {
    const int c = bN + ct*16 + m;
    #pragma unroll
    for (int r = 0; r < 4; ++r) {
      const int i = bM + wave*16 + quad*4 + r;
      hidden[(size_t)i*512 + c] = f2bf(fmaxf(acc[ct][r] + b_g1[c], 0.f));
    }
  }
}

// G2: g2 = hidden @ W_g2 + b_g2 -> hi/lo into h2 cols 0..255
__global__ __launch_bounds__(256) void k_g2(
    const ushort* __restrict__ hidden, const ushort* __restrict__ Wg2t,
    const float* __restrict__ b_g2, ushort* __restrict__ h2h, ushort* __restrict__ h2l)
{
  __shared__ __align__(16) ushort As[64*40], Bs[64*40];
  floatx4 acc[4];
  const int bM = blockIdx.x*64, bN = blockIdx.y*64;
  gemm_core<512>(hidden, Wg2t, bM, bN, acc, As, Bs);
  const int lane = threadIdx.x & 63, wave = threadIdx.x >> 6;
  const int quad = lane >> 4, m = lane & 15;
  #pragma unroll
  for (int ct = 0; ct < 4; ++ct) {
    const int c = bN + ct*16 + m;
    #pragma unroll
    for (int r = 0; r < 4; ++r) {
      const int i = bM + wave*16 + quad*4 + r;
      const float s = acc[ct][r] + b_g2[c];
      const ushort hi = f2bf(s);
      h2h[(size_t)i*512 + c] = hi;
      h2l[(size_t)i*512 + c] = f2bf(s - bf2f(hi));
    }
  }
}

// G3: [q|k|v] = h2 @ [Wq|Wk|Wv] + bias (3-term hi/lo), scatter to q_ws/k_ws/vext
__global__ __launch_bounds__(256) void k_g3(
    const ushort* __restrict__ h2h, const ushort* __restrict__ h2l,
    const ushort* __restrict__ Wth, const ushort* __restrict__ Wtl,
    const float* __restrict__ b_q, const float* __restrict__ b_k,
    const float* __restrict__ b_v,
    float* __restrict__ q_ws, float* __restrict__ k_ws, float* __restrict__ vext)
{
  __shared__ __align__(16) ushort Ash[64*40], Asl[64*40], Bsh[64*40], Bsl[64*40];
  floatx4 acc[4];
  const int bM = blockIdx.x*64, bN = blockIdx.y*64;
  gemm_core3<512>(h2h, h2l, Wth, Wtl, bM, bN, acc, Ash, Asl, Bsh, Bsl);
  const int lane = threadIdx.x & 63, wave = threadIdx.x >> 6;
  const int quad = lane >> 4, m = lane & 15;
  #pragma unroll
  for (int ct = 0; ct < 4; ++ct) {
    const int c = bN + ct*16 + m;
    #pragma unroll
    for (int r = 0; r < 4; ++r) {
      const int i = bM + wave*16 + quad*4 + r;
      if (c < 256) {
        const float s = acc[ct][r] + b_q[c];
        q_ws[((size_t)(c >> 5)*N_ + i)*32 + (c & 31)] = s * SCALING;
      } else if (c < 512) {
        const int cc = c - 256;
        const float s = acc[ct][r] + b_k[cc];
        k_ws[((size_t)(cc >> 5)*N_ + i)*32 + (cc & 31)] = s;
      } else {
        const int cc = c - 512;
        const float s = acc[ct][r] + b_v[cc];
        vext[((size_t)(cc >> 5)*N_ + i)*128 + (cc & 31)] = s;
      }
    }
  }
}

// G4: vg = g_src @ W_vg, rows are (node,j) pairs; scatter to vext cols 32..127
__global__ __launch_bounds__(256) void k_g4(
    const ushort* __restrict__ g_src_b, const ushort* __restrict__ Wvgt,
    float* __restrict__ vext)
{
  __shared__ __align__(16) ushort As[64*40], Bs[64*40];
  floatx4 acc[4];
  const int bM = blockIdx.x*64, bN = blockIdx.y*64;
  gemm_core<256>(g_src_b, Wvgt, bM, bN, acc, As, Bs);
  const int lane = threadIdx.x & 63, wave = threadIdx.x >> 6;
  const int quad = lane >> 4, m = lane & 15;
  #pragma unroll
  for (int ct = 0; ct < 4; ++ct) {
    const int c = bN + ct*16 + m;
    #pragma unroll
    for (int r = 0; r < 4; ++r) {
      const int i3 = bM + wave*16 + quad*4 + r;
      const int i = i3 / 3, j = i3 - 3*i;
      vext[((size_t)(c >> 5)*N_ + i)*128 + 32 + j*32 + (c & 31)] = acc[ct][r];
    }
  }
}

// ---------------- K3: MFMA flash attention (unchanged from round 3) ----------------
__global__ __launch_bounds__(256, 2) void k3_attn(
    const float* __restrict__ q_ws, const float* __restrict__ k_ws,
    const float* __restrict__ vext,
    float* __restrict__ out_v, float* __restrict__ out_g)
{
  __shared__ __align__(16) ushort Qh[64*40], Qlo[64*40];
  __shared__ __align__(16) ushort Kh[64*40], Klo[64*40];
  __shared__ __align__(16) ushort Vt[128*72];
  __shared__ __align__(16) ushort Pl[4*16*72];

  const int t    = threadIdx.x;
  const int wave = t >> 6;
  const int lane = t & 63;
  const int quad = lane >> 4;
  const int m    = lane & 15;
  const int h    = blockIdx.y;
  const int n0q  = blockIdx.x * 64;

  #pragma unroll
  for (int r = 0; r < 4; ++r) {
    const int p = r*256 + t;
    const int row = p >> 4, dp = p & 15;
    const float2 qv = *(const float2*)&q_ws[((size_t)h*N_ + n0q + row)*32 + dp*2];
    const ushort h0 = f2bf(qv.x), h1 = f2bf(qv.y);
    const ushort l0 = f2bf(qv.x - bf2f(h0)), l1 = f2bf(qv.y - bf2f(h1));
    *(unsigned int*)&Qh[row*40 + dp*2]  = (unsigned int)h0 | ((unsigned int)h1 << 16);
    *(unsigned int*)&Qlo[row*40 + dp*2] = (unsigned int)l0 | ((unsigned int)l1 << 16);
  }
  __syncthreads();
  const short8 aqh = *(const short8*)&Qh[(wave*16 + m)*40 + quad*8];
  const short8 aql = *(const short8*)&Qlo[(wave*16 + m)*40 + quad*8];

  floatx4 Of[8];
  #pragma unroll
  for (int nt = 0; nt < 8; ++nt) Of[nt] = {0.f, 0.f, 0.f, 0.f};
  float mi[4], li[4];
  #pragma unroll
  for (int r = 0; r < 4; ++r) { mi[r] = -3.0e38f; li[r] = 0.f; }

  for (int kt = 0; kt < 64; ++kt) {
    const int n0k = kt * 64;
    __syncthreads();
    #pragma unroll
    for (int r = 0; r < 4; ++r) {
      const int p = r*256 + t;
      const int row = p >> 4, dp = p & 15;
      const float2 kv = *(const float2*)&k_ws[((size_t)h*N_ + n0k + row)*32 + dp*2];
      const ushort h0 = f2bf(kv.x), h1 = f2bf(kv.y);
      const ushort l0 = f2bf(kv.x - bf2f(h0)), l1 = f2bf(kv.y - bf2f(h1));
      *(unsigned int*)&Kh[row*40 + dp*2]  = (unsigned int)h0 | ((unsigned int)h1 << 16);
      *(unsigned int*)&Klo[row*40 + dp*2] = (unsigned int)l0 | ((unsigned int)l1 << 16);
    }
    #pragma unroll
    for (int r = 0; r < 32; ++r) {
      const int idx = r*256 + t;
      const int key = idx >> 7, col = idx & 127;
      const float vv = vext[((size_t)h*N_ + n0k + key)*128 + col];
      Vt[col*72 + key] = f2bf(vv);
    }
    __syncthreads();

    floatx4 sf[4];
    #pragma unroll
    for (int kb = 0; kb < 4; ++kb) {
      const short8 bkh = *(const short8*)&Kh[(kb*16 + m)*40 + quad*8];
      const short8 bkl = *(const short8*)&Klo[(kb*16 + m)*40 + quad*8];
      floatx4 s = {0.f, 0.f, 0.f, 0.f};
      s = __builtin_amdgcn_mfma_f32_16x16x32_bf16(aqh, bkl, s, 0, 0, 0);
      s = __builtin_amdgcn_mfma_f32_16x16x32_bf16(aql, bkh, s, 0, 0, 0);
      s = __builtin_amdgcn_mfma_f32_16x16x32_bf16(aqh, bkh, s, 0, 0, 0);
      sf[kb] = s;
    }

    float nm[4];
    #pragma unroll
    for (int r = 0; r < 4; ++r) {
      nm[r] = fmaxf(fmaxf(sf[0][r], sf[1][r]), fmaxf(sf[2][r], sf[3][r]));
      #pragma unroll
      for (int x = 1; x < 16; x <<= 1)
        nm[r] = fmaxf(nm[r], __shfl_xor(nm[r], x, 64));
    }
    float al[4];
    float p[4][4];
    #pragma unroll
    for (int r = 0; r < 4; ++r) {
      const float mn = fmaxf(mi[r], nm[r]);
      al[r] = __expf(mi[r] - mn);
      mi[r] = mn;
      float rs = 0.f;
      #pragma unroll
      for (int kb = 0; kb < 4; ++kb) {
        const float pv = __expf(sf[kb][r] - mn);
        p[kb][r] = pv;
        rs += pv;
      }
      #pragma unroll
      for (int x = 1; x < 16; x <<= 1) rs += __shfl_xor(rs, x, 64);
      li[r] = li[r]*al[r] + rs;
    }
    #pragma unroll
    for (int nt = 0; nt < 8; ++nt)
      #pragma unroll
      for (int r = 0; r < 4; ++r) Of[nt][r] *= al[r];
    #pragma unroll
    for (int kb = 0; kb < 4; ++kb)
      #pragma unroll
      for (int r = 0; r < 4; ++r)
        Pl[wave*1152 + (quad*4 + r)*72 + kb*16 + m] = f2bf(p[kb][r]);

    #pragma unroll
    for (int ks = 0; ks < 2; ++ks) {
      const short8 ap = *(const short8*)&Pl[wave*1152 + m*72 + ks*32 + quad*8];
      #pragma unroll
      for (int nt = 0; nt < 8; ++nt) {
        const short8 bv = *(const short8*)&Vt[(nt*16 + m)*72 + ks*32 + quad*8];
        Of[nt] = __builtin_amdgcn_mfma_f32_16x16x32_bf16(ap, bv, Of[nt], 0, 0, 0);
      }
    }
  }

  float linv[4];
  #pragma unroll
  for (int r = 0; r < 4; ++r) linv[r] = 1.0f / li[r];
  #pragma unroll
  for (int nt = 0; nt < 8; ++nt) {
    #pragma unroll
    for (int r = 0; r < 4; ++r) {
      const float val = Of[nt][r] * linv[r];
      const int n = n0q + wave*16 + quad*4 + r;
      const int c = nt*16 + m;
      if (c < 32) {
        out_v[(size_t)n*256 + h*32 + c] = val;
      } else {
        const int j = (c - 32) >> 5, cc = (c - 32) & 31;
        out_g[((size_t)n*3 + j)*256 + h*32 + cc] = val;
      }
    }
  }
}

// ---------------- K4: output projections + residuals -> f32 out ----------------
__global__ __launch_bounds__(256) void k4_out(
    const float* __restrict__ h, const ushort* __restrict__ g_src_b,
    const float* __restrict__ out_v, const float* __restrict__ out_g,
    const float* __restrict__ W_ng, const float* __restrict__ b_ng,
    const float* __restrict__ W_gout, const float* __restrict__ W_gdec,
    const float* __restrict__ W_hdec, const float* __restrict__ b_hdec,
    float* __restrict__ out)
{
  __shared__ float ov[256];
  __shared__ float og[768];
  __shared__ float tmp[256];
  __shared__ float gsum[768];
  const int i = blockIdx.x;
  const int t = threadIdx.x;
  ov[t] = out_v[(size_t)i*256 + t];
  #pragma unroll
  for (int r = 0; r < 3; ++r) og[r*256+t] = out_g[(size_t)i*768 + r*256 + t];
  __syncthreads();
  {
    float s = b_ng[t];
    for (int kk = 0; kk < 256; ++kk) s += ov[kk] * W_ng[kk*256 + t];
    tmp[t] = s + h[(size_t)i*256 + t] * SQRT_E;
  }
  {
    float s0 = 0.f, s1 = 0.f, s2 = 0.f;
    for (int kk = 0; kk < 256; ++kk) {
      const float w = W_gout[kk*256 + t];
      s0 += og[kk]*w; s1 += og[256+kk]*w; s2 += og[512+kk]*w;
    }
    gsum[t]       = s0 + bf2f(g_src_b[(size_t)i*768 + t]);
    gsum[256 + t] = s1 + bf2f(g_src_b[(size_t)i*768 + 256 + t]);
    gsum[512 + t] = s2 + bf2f(g_src_b[(size_t)i*768 + 512 + t]);
  }
  __syncthreads();
  {
    float s = b_hdec[t];
    for (int kk = 0; kk < 256; ++kk) s += tmp[kk] * W_hdec[kk*256 + t];
    out[196608 + (size_t)i*256 + t] = s;
  }
  if (t < 48) {
    const int j = t >> 4, m = t & 15;
    float s = 0.f;
    for (int e = 0; e < 256; ++e) s += gsum[j*256 + e] * W_gdec[e*16 + m];
    out[(size_t)i*48 + j*16 + m] = s;
  }
}

extern "C" void kernel_launch(void* const* d_in, const int* in_sizes, int n_in,
                              void* d_out, int out_size, void* d_ws, size_t ws_size,
                              hipStream_t stream) {
  const float* equ    = (const float*)d_in[0];
  const float* h      = (const float*)d_in[1];
  const float* W_equ  = (const float*)d_in[4];
  const float* W_gproj= (const float*)d_in[5];
  const float* W_vg   = (const float*)d_in[6];
  const float* W_g1   = (const float*)d_in[7];
  const float* b_g1   = (const float*)d_in[8];
  const float* W_g2   = (const float*)d_in[9];
  const float* b_g2   = (const float*)d_in[10];
  const float* W_q    = (const float*)d_in[11];
  const float* b_q    = (const float*)d_in[12];
  const float* W_k    = (const float*)d_in[13];
  const float* b_k    = (const float*)d_in[14];
  const float* W_v    = (const float*)d_in[15];
  const float* b_v    = (const float*)d_in[16];
  const float* W_ng   = (const float*)d_in[17];
  const float* b_ng   = (const float*)d_in[18];
  const float* W_gout = (const float*)d_in[19];
  const float* W_gdec = (const float*)d_in[20];
  const float* W_hdec = (const float*)d_in[21];
  const float* b_hdec = (const float*)d_in[22];
  float* out = (float*)d_out;

  // ---- workspace layout (byte offsets; lifetimes annotated) ----
  char* wsb = (char*)d_ws;
  constexpr size_t MiB = 1048576;
  float*  q_ws    = (float*) (wsb + 0*MiB);    // 4 MiB  [G3 -> k3]
  float*  k_ws    = (float*) (wsb + 4*MiB);    // 4 MiB  [G3 -> k3]
  float*  vext    = (float*) (wsb + 8*MiB);    // 16 MiB [G3/G4 -> k3]
  ushort* hidden  = (ushort*)(wsb + 8*MiB);    // 4 MiB  [G1 -> G2] alias vext (dead before G3)
  ushort* h2h     = (ushort*)(wsb + 24*MiB);   // 4 MiB  [prep/G2 -> G3]
  ushort* h2l     = (ushort*)(wsb + 28*MiB);   // 4 MiB
  ushort* g_src_b = (ushort*)(wsb + 32*MiB);   // 6 MiB  [k1 -> G4,k4]
  ushort* wbase   = (ushort*)(wsb + 38*MiB);   // 2.875 MiB weights [prep -> G4]
  ushort* Wg1t = wbase;                        // 512x1024
  ushort* Wg2t = wbase + 524288;               // 256x512
  ushort* Wth  = wbase + 655360;               // 768x512 (q|k|v hi)
  ushort* Wtl  = wbase + 1048576;              // 768x512 (q|k|v lo)
  ushort* Wvgt = wbase + 1441792;              // 256x256
  ushort* gram_b  = (ushort*)(wsb + 42*MiB);   // 8 MiB  [k1 -> G1]
  float*  out_g   = (float*) (wsb + 38*MiB);   // 12 MiB [k3 -> k4] alias weights+gram (dead)
  float*  out_v   = (float*) (wsb + 24*MiB);   // 4 MiB  [k3 -> k4] alias h2h (dead)
  // peak use: 50 MiB <= 52 MiB proven available

  // ---- prep: weight transposes (+hi/lo), h_src split, k1 ----
  k_transpose<<<dim3(32,16), 256, 0, stream>>>(W_g1, Wg1t, nullptr, 1024, 512, 0);
  k_transpose<<<dim3(16, 8), 256, 0, stream>>>(W_g2, Wg2t, nullptr,  512, 256, 0);
  k_transpose<<<dim3(16, 8), 256, 0, stream>>>(W_q,  Wth,          Wtl,          512, 256, 1);
  k_transpose<<<dim3(16, 8), 256, 0, stream>>>(W_k,  Wth + 256*512, Wtl + 256*512, 512, 256, 1);
  k_transpose<<<dim3(16, 8), 256, 0, stream>>>(W_v,  Wth + 512*512, Wtl + 512*512, 512, 256, 1);
  k_transpose<<<dim3( 8, 8), 256, 0, stream>>>(W_vg, Wvgt, nullptr,  256, 256, 0);
  k_hsplit<<<4096, 256, 0, stream>>>(h, h2h, h2l);
  k1_pre<<<4096, 256, 0, stream>>>(equ, W_equ, W_gproj, g_src_b, gram_b);

  // ---- MFMA GEMM chain (replaces old k2) ----
  k_g1<<<dim3(64, 8), 256, 0, stream>>>(gram_b, Wg1t, b_g1, hidden);
  k_g2<<<dim3(64, 4), 256, 0, stream>>>(hidden, Wg2t, b_g2, h2h, h2l);
  k_g3<<<dim3(64,12), 256, 0, stream>>>(h2h, h2l, Wth, Wtl, b_q, b_k, b_v,
                                        q_ws, k_ws, vext);
  k_g4<<<dim3(192,4), 256, 0, stream>>>(g_src_b, Wvgt, vext);

  // ---- attention + epilogue ----
  dim3 g3(64, 8);
  k3_attn<<<g3, 256, 0, stream>>>(q_ws, k_ws, vext, out_v, out_g);
  k4_out<<<4096, 256, 0, stream>>>(h, g_src_b, out_v, out_g,
                                   W_ng, b_ng, W_gout, W_gdec, W_hdec, b_hdec,
                                   out);
}

// Round 5
// 469.466 us; speedup vs baseline: 4.1531x; 1.1034x over previous
//
#include <hip/hip_runtime.h>
#include <hip/hip_bf16.h>

typedef __attribute__((ext_vector_type(8))) short short8;
typedef __attribute__((ext_vector_type(4))) float floatx4;

constexpr int N_ = 4096;
constexpr float SQRT_E = 16.0f;
constexpr float SCALING = 0.17677669529663687f;    // 32^-0.5

__device__ __forceinline__ ushort f2bf(float x) {
  __hip_bfloat16 h = __float2bfloat16(x);
  return *reinterpret_cast<ushort*>(&h);
}
__device__ __forceinline__ float bf2f(ushort b) {
  unsigned int u = ((unsigned int)b) << 16;
  return __uint_as_float(u);
}

// ---------------- K1: g_src_b [N*3,256]bf16, gram_b [N,1024]bf16 ----------------
__global__ __launch_bounds__(256) void k1_pre(
    const float* __restrict__ equ, const float* __restrict__ W_equ,
    const float* __restrict__ W_gproj,
    ushort* __restrict__ g_src_b, ushort* __restrict__ gram_b)
{
  __shared__ float eq[48];
  __shared__ float gs[768];
  __shared__ float g2p[96];
  const int i = blockIdx.x;
  const int t = threadIdx.x;
  if (t < 48) eq[t] = equ[(size_t)i*48 + t];
  __syncthreads();
  #pragma unroll
  for (int j = 0; j < 3; ++j) {
    float s = 0.f;
    #pragma unroll
    for (int m = 0; m < 16; ++m) s += eq[j*16+m] * W_equ[m*256 + t];
    s *= SQRT_E;
    gs[j*256 + t] = s;
    g_src_b[((size_t)i*3 + j)*256 + t] = f2bf(s);
  }
  __syncthreads();
  if (t < 96) {
    const int j = t >> 5, a = t & 31;
    float s = 0.f;
    for (int e = 0; e < 256; ++e) s += gs[j*256+e] * W_gproj[e*32 + a];
    g2p[t] = s;
  }
  __syncthreads();
  #pragma unroll
  for (int r = 0; r < 4; ++r) {
    const int idx = r*256 + t;
    const int a = idx >> 5, b = idx & 31;
    const float s = g2p[a]*g2p[b] + g2p[32+a]*g2p[32+b] + g2p[64+a]*g2p[64+b];
    gram_b[(size_t)i*1024 + idx] = f2bf(s);
  }
}

// ---------------- prep: weight transpose + bf16 (optional hi/lo) ----------------
__global__ __launch_bounds__(256) void k_transpose(
    const float* __restrict__ src, ushort* __restrict__ dsth,
    ushort* __restrict__ dstl, int R, int C, int hasLo)
{
  __shared__ float tile[32][33];
  const int r0 = blockIdx.x * 32, c0 = blockIdx.y * 32;
  const int tx = threadIdx.x & 31, ty = threadIdx.x >> 5;
  #pragma unroll
  for (int p = 0; p < 4; ++p) {
    const int lr = p*8 + ty;
    tile[lr][tx] = src[(size_t)(r0+lr)*C + c0 + tx];
  }
  __syncthreads();
  #pragma unroll
  for (int p = 0; p < 4; ++p) {
    const int dc = p*8 + ty;
    const float v = tile[tx][dc];
    const ushort hi = f2bf(v);
    dsth[(size_t)(c0+dc)*R + r0 + tx] = hi;
    if (hasLo) dstl[(size_t)(c0+dc)*R + r0 + tx] = f2bf(v - bf2f(hi));
  }
}

// h_src half of h2 (cols 256..511), hi/lo split of h*16
__global__ __launch_bounds__(256) void k_hsplit(
    const float* __restrict__ h, ushort* __restrict__ h2h, ushort* __restrict__ h2l)
{
  const int i = blockIdx.x, t = threadIdx.x;
  const float v = h[(size_t)i*256 + t] * SQRT_E;
  const ushort hi = f2bf(v);
  h2h[(size_t)i*512 + 256 + t] = hi;
  h2l[(size_t)i*512 + 256 + t] = f2bf(v - bf2f(hi));
}

// ---------------- shared GEMM core: C[64x64] = A[64xK] * Bt[64xK]^T ----------------
template<int KTOT>
__device__ __forceinline__ void gemm_core(
    const ushort* __restrict__ A, const ushort* __restrict__ Bt,
    int bM, int bN, floatx4 acc[4], ushort* As, ushort* Bs)
{
  const int t = threadIdx.x;
  const int wave = t >> 6, lane = t & 63, quad = lane >> 4, m = lane & 15;
  #pragma unroll
  for (int ct = 0; ct < 4; ++ct) acc[ct] = {0.f, 0.f, 0.f, 0.f};
  const int row = t >> 2, kq = (t & 3) * 8;
  for (int k0 = 0; k0 < KTOT; k0 += 32) {
    __syncthreads();
    *(short8*)&As[row*40 + kq] = *(const short8*)&A[(size_t)(bM+row)*KTOT + k0 + kq];
    *(short8*)&Bs[row*40 + kq] = *(const short8*)&Bt[(size_t)(bN+row)*KTOT + k0 + kq];
    __syncthreads();
    const short8 af = *(const short8*)&As[(wave*16 + m)*40 + quad*8];
    #pragma unroll
    for (int ct = 0; ct < 4; ++ct) {
      const short8 bf = *(const short8*)&Bs[(ct*16 + m)*40 + quad*8];
      acc[ct] = __builtin_amdgcn_mfma_f32_16x16x32_bf16(af, bf, acc[ct], 0, 0, 0);
    }
  }
}

// 3-term hi/lo core (for q/k/v precision)
template<int KTOT>
__device__ __forceinline__ void gemm_core3(
    const ushort* __restrict__ Ah, const ushort* __restrict__ Al,
    const ushort* __restrict__ Bth, const ushort* __restrict__ Btl,
    int bM, int bN, floatx4 acc[4],
    ushort* Ash, ushort* Asl, ushort* Bsh, ushort* Bsl)
{
  const int t = threadIdx.x;
  const int wave = t >> 6, lane = t & 63, quad = lane >> 4, m = lane & 15;
  #pragma unroll
  for (int ct = 0; ct < 4; ++ct) acc[ct] = {0.f, 0.f, 0.f, 0.f};
  const int row = t >> 2, kq = (t & 3) * 8;
  for (int k0 = 0; k0 < KTOT; k0 += 32) {
    __syncthreads();
    *(short8*)&Ash[row*40 + kq] = *(const short8*)&Ah[(size_t)(bM+row)*KTOT + k0 + kq];
    *(short8*)&Asl[row*40 + kq] = *(const short8*)&Al[(size_t)(bM+row)*KTOT + k0 + kq];
    *(short8*)&Bsh[row*40 + kq] = *(const short8*)&Bth[(size_t)(bN+row)*KTOT + k0 + kq];
    *(short8*)&Bsl[row*40 + kq] = *(const short8*)&Btl[(size_t)(bN+row)*KTOT + k0 + kq];
    __syncthreads();
    const short8 ah = *(const short8*)&Ash[(wave*16 + m)*40 + quad*8];
    const short8 al = *(const short8*)&Asl[(wave*16 + m)*40 + quad*8];
    #pragma unroll
    for (int ct = 0; ct < 4; ++ct) {
      const short8 bh = *(const short8*)&Bsh[(ct*16 + m)*40 + quad*8];
      const short8 bl = *(const short8*)&Bsl[(ct*16 + m)*40 + quad*8];
      acc[ct] = __builtin_amdgcn_mfma_f32_16x16x32_bf16(ah, bl, acc[ct], 0, 0, 0);
      acc[ct] = __builtin_amdgcn_mfma_f32_16x16x32_bf16(al, bh, acc[ct], 0, 0, 0);
      acc[ct] = __builtin_amdgcn_mfma_f32_16x16x32_bf16(ah, bh, acc[ct], 0, 0, 0);
    }
  }
}

// G1: hidden = relu(gram @ W_g1 + b_g1) -> bf16 [4096][512]
__global__ __launch_bounds__(256) void k_g1(
    const ushort* __restrict__ gram_b, const ushort* __restrict__ Wg1t,
    const float* __restrict__ b_g1, ushort* __restrict__ hidden)
{
  __shared__ __align__(16) ushort As[64*40], Bs[64*40];
  floatx4 acc[4];
  const int bM = blockIdx.x*64, bN = blockIdx.y*64;
  gemm_core<1024>(gram_b, Wg1t, bM, bN, acc, As, Bs);
  const int lane = threadIdx.x & 63, wave = threadIdx.x >> 6;
  const int quad = lane >> 4, m = lane & 15;
  #pragma unroll
  for (int ct = 0; ct < 4; ++ct) {
    const int c = bN + ct*16 + m;
    #pragma unroll
    for (int r = 0; r < 4; ++r) {
      const int i = bM + wave*16 + quad*4 + r;
      hidden[(size_t)i*512 + c] = f2bf(fmaxf(acc[ct][r] + b_g1[c], 0.f));
    }
  }
}

// G2: g2 = hidden @ W_g2 + b_g2 -> hi/lo into h2 cols 0..255
__global__ __launch_bounds__(256) void k_g2(
    const ushort* __restrict__ hidden, const ushort* __restrict__ Wg2t,
    const float* __restrict__ b_g2, ushort* __restrict__ h2h, ushort* __restrict__ h2l)
{
  __shared__ __align__(16) ushort As[64*40], Bs[64*40];
  floatx4 acc[4];
  const int bM = blockIdx.x*64, bN = blockIdx.y*64;
  gemm_core<512>(hidden, Wg2t, bM, bN, acc, As, Bs);
  const int lane = threadIdx.x & 63, wave = threadIdx.x >> 6;
  const int quad = lane >> 4, m = lane & 15;
  #pragma unroll
  for (int ct = 0; ct < 4; ++ct) {
    const int c = bN + ct*16 + m;
    #pragma unroll
    for (int r = 0; r < 4; ++r) {
      const int i = bM + wave*16 + quad*4 + r;
      const float s = acc[ct][r] + b_g2[c];
      const ushort hi = f2bf(s);
      h2h[(size_t)i*512 + c] = hi;
      h2l[(size_t)i*512 + c] = f2bf(s - bf2f(hi));
    }
  }
}

// G3: [q|k|v] = h2 @ [Wq|Wk|Wv] + bias (3-term hi/lo).
// q -> f32 q_ws[h][n][32]; k -> hi/lo bf16 kh/kl[h][n][32]; v -> bf16 vt[h][col][n]
__global__ __launch_bounds__(256) void k_g3(
    const ushort* __restrict__ h2h, const ushort* __restrict__ h2l,
    const ushort* __restrict__ Wth, const ushort* __restrict__ Wtl,
    const float* __restrict__ b_q, const float* __restrict__ b_k,
    const float* __restrict__ b_v,
    float* __restrict__ q_ws, ushort* __restrict__ kh, ushort* __restrict__ kl,
    ushort* __restrict__ vt)
{
  __shared__ __align__(16) ushort Ash[64*40], Asl[64*40], Bsh[64*40], Bsl[64*40];
  floatx4 acc[4];
  const int bM = blockIdx.x*64, bN = blockIdx.y*64;
  gemm_core3<512>(h2h, h2l, Wth, Wtl, bM, bN, acc, Ash, Asl, Bsh, Bsl);
  const int lane = threadIdx.x & 63, wave = threadIdx.x >> 6;
  const int quad = lane >> 4, m = lane & 15;
  #pragma unroll
  for (int ct = 0; ct < 4; ++ct) {
    const int c = bN + ct*16 + m;
    #pragma unroll
    for (int r = 0; r < 4; ++r) {
      const int i = bM + wave*16 + quad*4 + r;
      if (c < 256) {
        const float s = acc[ct][r] + b_q[c];
        q_ws[((size_t)(c >> 5)*N_ + i)*32 + (c & 31)] = s * SCALING;
      } else if (c < 512) {
        const int cc = c - 256;
        const float s = acc[ct][r] + b_k[cc];
        const ushort hi = f2bf(s);
        kh[((size_t)(cc >> 5)*N_ + i)*32 + (cc & 31)] = hi;
        kl[((size_t)(cc >> 5)*N_ + i)*32 + (cc & 31)] = f2bf(s - bf2f(hi));
      } else {
        const int cc = c - 512;
        const float s = acc[ct][r] + b_v[cc];
        vt[((size_t)(cc >> 5)*128 + (cc & 31))*N_ + i] = f2bf(s);
      }
    }
  }
}

// G4: vg = g_src @ W_vg -> vt cols 32..127 (bf16, transposed layout)
__global__ __launch_bounds__(256) void k_g4(
    const ushort* __restrict__ g_src_b, const ushort* __restrict__ Wvgt,
    ushort* __restrict__ vt)
{
  __shared__ __align__(16) ushort As[64*40], Bs[64*40];
  floatx4 acc[4];
  const int bM = blockIdx.x*64, bN = blockIdx.y*64;
  gemm_core<256>(g_src_b, Wvgt, bM, bN, acc, As, Bs);
  const int lane = threadIdx.x & 63, wave = threadIdx.x >> 6;
  const int quad = lane >> 4, m = lane & 15;
  #pragma unroll
  for (int ct = 0; ct < 4; ++ct) {
    const int c = bN + ct*16 + m;
    const int hh = c >> 5, d = c & 31;
    #pragma unroll
    for (int r = 0; r < 4; ++r) {
      const int i3 = bM + wave*16 + quad*4 + r;
      const int i = i3 / 3, j = i3 - 3*i;
      vt[((size_t)hh*128 + 32 + j*32 + d)*N_ + i] = f2bf(acc[ct][r]);
    }
  }
}

// ---------------- K3: MFMA flash attention (bf16-staged, swizzled V) -----------
// Per block: 64 q-rows x 1 head, 4 waves x 16 rows, K-tiles of 64.
// K staged LDS stride-40 (pad); V staged with XOR chunk swizzle (conflict-free).
__global__ __launch_bounds__(256) void k3_attn(
    const float* __restrict__ q_ws, const ushort* __restrict__ kh,
    const ushort* __restrict__ kl, const ushort* __restrict__ vt,
    float* __restrict__ out_v, float* __restrict__ out_g)
{
  __shared__ __align__(16) ushort Khs[64*40], Kls[64*40];  // 5 KiB each
  __shared__ __align__(16) ushort Vs[128*64];              // 16 KiB, swizzled chunks
  __shared__ __align__(16) ushort Pl[4*16*72];             // 9 KiB

  const int t    = threadIdx.x;
  const int wave = t >> 6;
  const int lane = t & 63;
  const int quad = lane >> 4;
  const int m    = lane & 15;
  const int h    = blockIdx.y;
  const int n0q  = blockIdx.x * 64;

  // ---- Q fragments: direct global load + hi/lo split in registers ----
  union { short8 v; ushort u[8]; } Aqh, Aql;
  {
    const float* qp = q_ws + ((size_t)h*N_ + n0q + wave*16 + m)*32 + quad*8;
    #pragma unroll
    for (int jj = 0; jj < 8; ++jj) {
      const float x = qp[jj];
      const ushort hi = f2bf(x);
      Aqh.u[jj] = hi;
      Aql.u[jj] = f2bf(x - bf2f(hi));
    }
  }

  floatx4 Of[8];
  #pragma unroll
  for (int nt = 0; nt < 8; ++nt) Of[nt] = {0.f, 0.f, 0.f, 0.f};
  float mi[4], li[4];
  #pragma unroll
  for (int r = 0; r < 4; ++r) { mi[r] = -3.0e38f; li[r] = 0.f; }

  const int krow = t >> 2, kch = (t & 3) * 8;   // K staging coords

  for (int kt = 0; kt < 64; ++kt) {
    const int n0k = kt * 64;
    __syncthreads();
    // ---- stage K hi/lo (bf16, pure copy) ----
    *(short8*)&Khs[krow*40 + kch] =
        *(const short8*)&kh[((size_t)h*N_ + n0k + krow)*32 + kch];
    *(short8*)&Kls[krow*40 + kch] =
        *(const short8*)&kl[((size_t)h*N_ + n0k + krow)*32 + kch];
    // ---- stage V (pre-transposed global, XOR-swizzled LDS chunks) ----
    #pragma unroll
    for (int p = 0; p < 4; ++p) {
      const int idx = p*256 + t;
      const int row = idx >> 3, g = idx & 7;          // row = V col 0..127
      const int pos = g ^ (row & 7);
      *(short8*)&Vs[(row*8 + pos)*8] =
          *(const short8*)&vt[((size_t)h*128 + row)*N_ + n0k + g*8];
    }
    __syncthreads();

    // ---- S = Q K^T (3-term hi/lo MFMA) ----
    floatx4 sf[4];
    #pragma unroll
    for (int kb = 0; kb < 4; ++kb) {
      const short8 bkh = *(const short8*)&Khs[(kb*16 + m)*40 + quad*8];
      const short8 bkl = *(const short8*)&Kls[(kb*16 + m)*40 + quad*8];
      floatx4 s = {0.f, 0.f, 0.f, 0.f};
      s = __builtin_amdgcn_mfma_f32_16x16x32_bf16(Aqh.v, bkl, s, 0, 0, 0);
      s = __builtin_amdgcn_mfma_f32_16x16x32_bf16(Aql.v, bkh, s, 0, 0, 0);
      s = __builtin_amdgcn_mfma_f32_16x16x32_bf16(Aqh.v, bkh, s, 0, 0, 0);
      sf[kb] = s;
    }

    // ---- online softmax (rows = quad*4+r, cols = kb*16+m) ----
    float nm[4];
    #pragma unroll
    for (int r = 0; r < 4; ++r) {
      nm[r] = fmaxf(fmaxf(sf[0][r], sf[1][r]), fmaxf(sf[2][r], sf[3][r]));
      #pragma unroll
      for (int x = 1; x < 16; x <<= 1)
        nm[r] = fmaxf(nm[r], __shfl_xor(nm[r], x, 64));
    }
    float al[4];
    float p[4][4];
    #pragma unroll
    for (int r = 0; r < 4; ++r) {
      const float mn = fmaxf(mi[r], nm[r]);
      al[r] = __expf(mi[r] - mn);
      mi[r] = mn;
      float rs = 0.f;
      #pragma unroll
      for (int kb = 0; kb < 4; ++kb) {
        const float pv = __expf(sf[kb][r] - mn);
        p[kb][r] = pv;
        rs += pv;
      }
      #pragma unroll
      for (int x = 1; x < 16; x <<= 1) rs += __shfl_xor(rs, x, 64);
      li[r] = li[r]*al[r] + rs;
    }
    #pragma unroll
    for (int nt = 0; nt < 8; ++nt)
      #pragma unroll
      for (int r = 0; r < 4; ++r) Of[nt][r] *= al[r];
    #pragma unroll
    for (int kb = 0; kb < 4; ++kb)
      #pragma unroll
      for (int r = 0; r < 4; ++r)
        Pl[wave*1152 + (quad*4 + r)*72 + kb*16 + m] = f2bf(p[kb][r]);

    // ---- O += P @ V (B rows = V cols, swizzled chunk read) ----
    #pragma unroll
    for (int ks = 0; ks < 2; ++ks) {
      const short8 ap = *(const short8*)&Pl[wave*1152 + m*72 + ks*32 + quad*8];
      #pragma unroll
      for (int nt = 0; nt < 8; ++nt) {
        const int row = nt*16 + m;
        const int pos = (ks*4 + quad) ^ (row & 7);
        const short8 bv = *(const short8*)&Vs[(row*8 + pos)*8];
        Of[nt] = __builtin_amdgcn_mfma_f32_16x16x32_bf16(ap, bv, Of[nt], 0, 0, 0);
      }
    }
  }

  // ---- normalize + write out ----
  float linv[4];
  #pragma unroll
  for (int r = 0; r < 4; ++r) linv[r] = 1.0f / li[r];
  #pragma unroll
  for (int nt = 0; nt < 8; ++nt) {
    #pragma unroll
    for (int r = 0; r < 4; ++r) {
      const float val = Of[nt][r] * linv[r];
      const int n = n0q + wave*16 + quad*4 + r;
      const int c = nt*16 + m;
      if (c < 32) {
        out_v[(size_t)n*256 + h*32 + c] = val;
      } else {
        const int j = (c - 32) >> 5, cc = (c - 32) & 31;
        out_g[((size_t)n*3 + j)*256 + h*32 + cc] = val;
      }
    }
  }
}

// ---------------- K4: output projections + residuals -> f32 out ----------------
__global__ __launch_bounds__(256) void k4_out(
    const float* __restrict__ h, const ushort* __restrict__ g_src_b,
    const float* __restrict__ out_v, const float* __restrict__ out_g,
    const float* __restrict__ W_ng, const float* __restrict__ b_ng,
    const float* __restrict__ W_gout, const float* __restrict__ W_gdec,
    const float* __restrict__ W_hdec, const float* __restrict__ b_hdec,
    float* __restrict__ out)
{
  __shared__ float ov[256];
  __shared__ float og[768];
  __shared__ float tmp[256];
  __shared__ float gsum[768];
  const int i = blockIdx.x;
  const int t = threadIdx.x;
  ov[t] = out_v[(size_t)i*256 + t];
  #pragma unroll
  for (int r = 0; r < 3; ++r) og[r*256+t] = out_g[(size_t)i*768 + r*256 + t];
  __syncthreads();
  {
    float s = b_ng[t];
    for (int kk = 0; kk < 256; ++kk) s += ov[kk] * W_ng[kk*256 + t];
    tmp[t] = s + h[(size_t)i*256 + t] * SQRT_E;
  }
  {
    float s0 = 0.f, s1 = 0.f, s2 = 0.f;
    for (int kk = 0; kk < 256; ++kk) {
      const float w = W_gout[kk*256 + t];
      s0 += og[kk]*w; s1 += og[256+kk]*w; s2 += og[512+kk]*w;
    }
    gsum[t]       = s0 + bf2f(g_src_b[(size_t)i*768 + t]);
    gsum[256 + t] = s1 + bf2f(g_src_b[(size_t)i*768 + 256 + t]);
    gsum[512 + t] = s2 + bf2f(g_src_b[(size_t)i*768 + 512 + t]);
  }
  __syncthreads();
  {
    float s = b_hdec[t];
    for (int kk = 0; kk < 256; ++kk) s += tmp[kk] * W_hdec[kk*256 + t];
    out[196608 + (size_t)i*256 + t] = s;
  }
  if (t < 48) {
    const int j = t >> 4, m = t & 15;
    float s = 0.f;
    for (int e = 0; e < 256; ++e) s += gsum[j*256 + e] * W_gdec[e*16 + m];
    out[(size_t)i*48 + j*16 + m] = s;
  }
}

extern "C" void kernel_launch(void* const* d_in, const int* in_sizes, int n_in,
                              void* d_out, int out_size, void* d_ws, size_t ws_size,
                              hipStream_t stream) {
  const float* equ    = (const float*)d_in[0];
  const float* h      = (const float*)d_in[1];
  const float* W_equ  = (const float*)d_in[4];
  const float* W_gproj= (const float*)d_in[5];
  const float* W_vg   = (const float*)d_in[6];
  const float* W_g1   = (const float*)d_in[7];
  const float* b_g1   = (const float*)d_in[8];
  const float* W_g2   = (const float*)d_in[9];
  const float* b_g2   = (const float*)d_in[10];
  const float* W_q    = (const float*)d_in[11];
  const float* b_q    = (const float*)d_in[12];
  const float* W_k    = (const float*)d_in[13];
  const float* b_k    = (const float*)d_in[14];
  const float* W_v    = (const float*)d_in[15];
  const float* b_v    = (const float*)d_in[16];
  const float* W_ng   = (const float*)d_in[17];
  const float* b_ng   = (const float*)d_in[18];
  const float* W_gout = (const float*)d_in[19];
  const float* W_gdec = (const float*)d_in[20];
  const float* W_hdec = (const float*)d_in[21];
  const float* b_hdec = (const float*)d_in[22];
  float* out = (float*)d_out;

  // ---- workspace layout (byte offsets; lifetimes annotated) ----
  char* wsb = (char*)d_ws;
  constexpr size_t MiB = 1048576;
  float*  q_ws    = (float*) (wsb +  0*MiB);   // 4 MiB  [G3 -> k3]
  ushort* kh      = (ushort*)(wsb +  4*MiB);   // 2 MiB  [G3 -> k3]
  ushort* kl      = (ushort*)(wsb +  6*MiB);   // 2 MiB  [G3 -> k3]
  ushort* vt      = (ushort*)(wsb +  8*MiB);   // 8 MiB  [G3/G4 -> k3]
  ushort* h2h     = (ushort*)(wsb + 16*MiB);   // 4 MiB  [prep/G2 -> G3]
  ushort* h2l     = (ushort*)(wsb + 20*MiB);   // 4 MiB
  ushort* g_src_b = (ushort*)(wsb + 24*MiB);   // 6 MiB  [k1 -> G4,k4]
  ushort* wbase   = (ushort*)(wsb + 30*MiB);   // 2.875 MiB weights [prep -> G4]
  ushort* Wg1t = wbase;                        // 512x1024
  ushort* Wg2t = wbase + 524288;               // 256x512
  ushort* Wth  = wbase + 655360;               // 768x512 (q|k|v hi)
  ushort* Wtl  = wbase + 1048576;              // 768x512 (q|k|v lo)
  ushort* Wvgt = wbase + 1441792;              // 256x256
  ushort* gram_b  = (ushort*)(wsb + 33*MiB);   // 8 MiB  [k1 -> G1]
  ushort* hidden  = (ushort*)(wsb + 41*MiB);   // 4 MiB  [G1 -> G2]
  float*  out_v   = (float*) (wsb + 33*MiB);   // 4 MiB  [k3 -> k4] alias gram_b (dead)
  float*  out_g   = (float*) (wsb + 37*MiB);   // 12 MiB [k3 -> k4] alias gram/hidden (dead)
  // peak use: 49 MiB <= 52 MiB proven available

  // ---- prep: weight transposes (+hi/lo), h_src split, k1 ----
  k_transpose<<<dim3(32,16), 256, 0, stream>>>(W_g1, Wg1t, nullptr, 1024, 512, 0);
  k_transpose<<<dim3(16, 8), 256, 0, stream>>>(W_g2, Wg2t, nullptr,  512, 256, 0);
  k_transpose<<<dim3(16, 8), 256, 0, stream>>>(W_q,  Wth,           Wtl,           512, 256, 1);
  k_transpose<<<dim3(16, 8), 256, 0, stream>>>(W_k,  Wth + 256*512, Wtl + 256*512, 512, 256, 1);
  k_transpose<<<dim3(16, 8), 256, 0, stream>>>(W_v,  Wth + 512*512, Wtl + 512*512, 512, 256, 1);
  k_transpose<<<dim3( 8, 8), 256, 0, stream>>>(W_vg, Wvgt, nullptr,  256, 256, 0);
  k_hsplit<<<4096, 256, 0, stream>>>(h, h2h, h2l);
  k1_pre<<<4096, 256, 0, stream>>>(equ, W_equ, W_gproj, g_src_b, gram_b);

  // ---- MFMA GEMM chain ----
  k_g1<<<dim3(64, 8), 256, 0, stream>>>(gram_b, Wg1t, b_g1, hidden);
  k_g2<<<dim3(64, 4), 256, 0, stream>>>(hidden, Wg2t, b_g2, h2h, h2l);
  k_g3<<<dim3(64,12), 256, 0, stream>>>(h2h, h2l, Wth, Wtl, b_q, b_k, b_v,
                                        q_ws, kh, kl, vt);
  k_g4<<<dim3(192,4), 256, 0, stream>>>(g_src_b, Wvgt, vt);

  // ---- attention + epilogue ----
  dim3 g3(64, 8);
  k3_attn<<<g3, 256, 0, stream>>>(q_ws, kh, kl, vt, out_v, out_g);
  k4_out<<<4096, 256, 0, stream>>>(h, g_src_b, out_v, out_g,
                                   W_ng, b_ng, W_gout, W_gdec, W_hdec, b_hdec,
                                   out);
}

// Round 6
// 434.759 us; speedup vs baseline: 4.4847x; 1.0798x over previous
//
#include <hip/hip_runtime.h>
#include <hip/hip_bf16.h>

typedef __attribute__((ext_vector_type(8))) short short8;
typedef __attribute__((ext_vector_type(4))) float floatx4;

constexpr int N_ = 4096;
constexpr float SQRT_E = 16.0f;
// q scale folded with log2(e): softmax computed in exp2 domain
constexpr float QSCALE = 0.17677669529663687f * 1.4426950408889634f;

__device__ __forceinline__ ushort f2bf(float x) {
  __hip_bfloat16 h = __float2bfloat16(x);
  return *reinterpret_cast<ushort*>(&h);
}
__device__ __forceinline__ float bf2f(ushort b) {
  unsigned int u = ((unsigned int)b) << 16;
  return __uint_as_float(u);
}

// all 16 lanes of each aligned 16-lane group get the group max (VALU DPP, not LDS)
__device__ __forceinline__ float dpp_max16(float x) {
  int v = __float_as_int(x);
  int y;
  y = __builtin_amdgcn_update_dpp(v, v, 0x128, 0xf, 0xf, false); // row_ror:8
  v = __float_as_int(fmaxf(__int_as_float(v), __int_as_float(y)));
  y = __builtin_amdgcn_update_dpp(v, v, 0x124, 0xf, 0xf, false); // row_ror:4
  v = __float_as_int(fmaxf(__int_as_float(v), __int_as_float(y)));
  y = __builtin_amdgcn_update_dpp(v, v, 0x122, 0xf, 0xf, false); // row_ror:2
  v = __float_as_int(fmaxf(__int_as_float(v), __int_as_float(y)));
  y = __builtin_amdgcn_update_dpp(v, v, 0x121, 0xf, 0xf, false); // row_ror:1
  v = __float_as_int(fmaxf(__int_as_float(v), __int_as_float(y)));
  return __int_as_float(v);
}

// ---------------- K1: g_src_b [N*3,256]bf16, gram_b [N,1024]bf16 ----------------
__global__ __launch_bounds__(256) void k1_pre(
    const float* __restrict__ equ, const float* __restrict__ W_equ,
    const float* __restrict__ W_gproj,
    ushort* __restrict__ g_src_b, ushort* __restrict__ gram_b)
{
  __shared__ float eq[48];
  __shared__ float gs[768];
  __shared__ float g2p[96];
  const int i = blockIdx.x;
  const int t = threadIdx.x;
  if (t < 48) eq[t] = equ[(size_t)i*48 + t];
  __syncthreads();
  #pragma unroll
  for (int j = 0; j < 3; ++j) {
    float s = 0.f;
    #pragma unroll
    for (int m = 0; m < 16; ++m) s += eq[j*16+m] * W_equ[m*256 + t];
    s *= SQRT_E;
    gs[j*256 + t] = s;
    g_src_b[((size_t)i*3 + j)*256 + t] = f2bf(s);
  }
  __syncthreads();
  if (t < 96) {
    const int j = t >> 5, a = t & 31;
    float s = 0.f;
    for (int e = 0; e < 256; ++e) s += gs[j*256+e] * W_gproj[e*32 + a];
    g2p[t] = s;
  }
  __syncthreads();
  #pragma unroll
  for (int r = 0; r < 4; ++r) {
    const int idx = r*256 + t;
    const int a = idx >> 5, b = idx & 31;
    const float s = g2p[a]*g2p[b] + g2p[32+a]*g2p[32+b] + g2p[64+a]*g2p[64+b];
    gram_b[(size_t)i*1024 + idx] = f2bf(s);
  }
}

// ---------------- prep: guarded weight transpose + bf16 (optional hi/lo) --------
__global__ __launch_bounds__(256) void k_transpose(
    const float* __restrict__ src, ushort* __restrict__ dsth,
    ushort* __restrict__ dstl, int R, int C, int hasLo)
{
  __shared__ float tile[32][33];
  const int r0 = blockIdx.x * 32, c0 = blockIdx.y * 32;
  const int tx = threadIdx.x & 31, ty = threadIdx.x >> 5;
  #pragma unroll
  for (int p = 0; p < 4; ++p) {
    const int lr = p*8 + ty;
    tile[lr][tx] = (r0+lr < R && c0+tx < C) ? src[(size_t)(r0+lr)*C + c0 + tx] : 0.f;
  }
  __syncthreads();
  #pragma unroll
  for (int p = 0; p < 4; ++p) {
    const int dc = p*8 + ty;
    if (c0+dc < C && r0+tx < R) {
      const float v = tile[tx][dc];
      const ushort hi = f2bf(v);
      dsth[(size_t)(c0+dc)*R + r0 + tx] = hi;
      if (hasLo) dstl[(size_t)(c0+dc)*R + r0 + tx] = f2bf(v - bf2f(hi));
    }
  }
}

// h_src half of h2 (cols 256..511), hi/lo split of h*16
__global__ __launch_bounds__(256) void k_hsplit(
    const float* __restrict__ h, ushort* __restrict__ h2h, ushort* __restrict__ h2l)
{
  const int i = blockIdx.x, t = threadIdx.x;
  const float v = h[(size_t)i*256 + t] * SQRT_E;
  const ushort hi = f2bf(v);
  h2h[(size_t)i*512 + 256 + t] = hi;
  h2l[(size_t)i*512 + 256 + t] = f2bf(v - bf2f(hi));
}

// init V extension cols 128..143 (col 128 = ones -> softmax denominator via MFMA)
__global__ __launch_bounds__(256) void k_vinit(ushort* __restrict__ vt) {
  const int idx = blockIdx.x*256 + threadIdx.x;   // 8*16*4096 = 524288 total
  const int n = idx & 4095;
  const int c16 = (idx >> 12) & 15;
  const int h = idx >> 16;
  vt[((size_t)h*144 + 128 + c16)*N_ + n] = (c16 == 0) ? (ushort)0x3F80 : (ushort)0;
}

// ---------------- shared GEMM core: C[64x64] = A[64xK] * Bt[64xK]^T ----------------
template<int KTOT>
__device__ __forceinline__ void gemm_core(
    const ushort* __restrict__ A, const ushort* __restrict__ Bt,
    int bM, int bN, floatx4 acc[4], ushort* As, ushort* Bs)
{
  const int t = threadIdx.x;
  const int wave = t >> 6, lane = t & 63, quad = lane >> 4, m = lane & 15;
  #pragma unroll
  for (int ct = 0; ct < 4; ++ct) acc[ct] = {0.f, 0.f, 0.f, 0.f};
  const int row = t >> 2, kq = (t & 3) * 8;
  for (int k0 = 0; k0 < KTOT; k0 += 32) {
    __syncthreads();
    *(short8*)&As[row*40 + kq] = *(const short8*)&A[(size_t)(bM+row)*KTOT + k0 + kq];
    *(short8*)&Bs[row*40 + kq] = *(const short8*)&Bt[(size_t)(bN+row)*KTOT + k0 + kq];
    __syncthreads();
    const short8 af = *(const short8*)&As[(wave*16 + m)*40 + quad*8];
    #pragma unroll
    for (int ct = 0; ct < 4; ++ct) {
      const short8 bf = *(const short8*)&Bs[(ct*16 + m)*40 + quad*8];
      acc[ct] = __builtin_amdgcn_mfma_f32_16x16x32_bf16(af, bf, acc[ct], 0, 0, 0);
    }
  }
}

// 3-term hi/lo core (q/k/v precision)
template<int KTOT>
__device__ __forceinline__ void gemm_core3(
    const ushort* __restrict__ Ah, const ushort* __restrict__ Al,
    const ushort* __restrict__ Bth, const ushort* __restrict__ Btl,
    int bM, int bN, floatx4 acc[4],
    ushort* Ash, ushort* Asl, ushort* Bsh, ushort* Bsl)
{
  const int t = threadIdx.x;
  const int wave = t >> 6, lane = t & 63, quad = lane >> 4, m = lane & 15;
  #pragma unroll
  for (int ct = 0; ct < 4; ++ct) acc[ct] = {0.f, 0.f, 0.f, 0.f};
  const int row = t >> 2, kq = (t & 3) * 8;
  for (int k0 = 0; k0 < KTOT; k0 += 32) {
    __syncthreads();
    *(short8*)&Ash[row*40 + kq] = *(const short8*)&Ah[(size_t)(bM+row)*KTOT + k0 + kq];
    *(short8*)&Asl[row*40 + kq] = *(const short8*)&Al[(size_t)(bM+row)*KTOT + k0 + kq];
    *(short8*)&Bsh[row*40 + kq] = *(const short8*)&Bth[(size_t)(bN+row)*KTOT + k0 + kq];
    *(short8*)&Bsl[row*40 + kq] = *(const short8*)&Btl[(size_t)(bN+row)*KTOT + k0 + kq];
    __syncthreads();
    const short8 ah = *(const short8*)&Ash[(wave*16 + m)*40 + quad*8];
    const short8 al = *(const short8*)&Asl[(wave*16 + m)*40 + quad*8];
    #pragma unroll
    for (int ct = 0; ct < 4; ++ct) {
      const short8 bh = *(const short8*)&Bsh[(ct*16 + m)*40 + quad*8];
      const short8 bl = *(const short8*)&Bsl[(ct*16 + m)*40 + quad*8];
      acc[ct] = __builtin_amdgcn_mfma_f32_16x16x32_bf16(ah, bl, acc[ct], 0, 0, 0);
      acc[ct] = __builtin_amdgcn_mfma_f32_16x16x32_bf16(al, bh, acc[ct], 0, 0, 0);
      acc[ct] = __builtin_amdgcn_mfma_f32_16x16x32_bf16(ah, bh, acc[ct], 0, 0, 0);
    }
  }
}

// G1: hidden = relu(gram @ W_g1 + b_g1)
__global__ __launch_bounds__(256) void k_g1(
    const ushort* __restrict__ gram_b, const ushort* __restrict__ Wg1t,
    const float* __restrict__ b_g1, ushort* __restrict__ hidden)
{
  __shared__ __align__(16) ushort As[64*40], Bs[64*40];
  floatx4 acc[4];
  const int bM = blockIdx.x*64, bN = blockIdx.y*64;
  gemm_core<1024>(gram_b, Wg1t, bM, bN, acc, As, Bs);
  const int lane = threadIdx.x & 63, wave = threadIdx.x >> 6;
  const int quad = lane >> 4, m = lane & 15;
  #pragma unroll
  for (int ct = 0; ct < 4; ++ct) {
    const int c = bN + ct*16 + m;
    #pragma unroll
    for (int r = 0; r < 4; ++r) {
      const int i = bM + wave*16 + quad*4 + r;
      hidden[(size_t)i*512 + c] = f2bf(fmaxf(acc[ct][r] + b_g1[c], 0.f));
    }
  }
}

// G2: g2 = hidden @ W_g2 + b_g2 -> hi/lo into h2 cols 0..255
__global__ __launch_bounds__(256) void k_g2(
    const ushort* __restrict__ hidden, const ushort* __restrict__ Wg2t,
    const float* __restrict__ b_g2, ushort* __restrict__ h2h, ushort* __restrict__ h2l)
{
  __shared__ __align__(16) ushort As[64*40], Bs[64*40];
  floatx4 acc[4];
  const int bM = blockIdx.x*64, bN = blockIdx.y*64;
  gemm_core<512>(hidden, Wg2t, bM, bN, acc, As, Bs);
  const int lane = threadIdx.x & 63, wave = threadIdx.x >> 6;
  const int quad = lane >> 4, m = lane & 15;
  #pragma unroll
  for (int ct = 0; ct < 4; ++ct) {
    const int c = bN + ct*16 + m;
    #pragma unroll
    for (int r = 0; r < 4; ++r) {
      const int i = bM + wave*16 + quad*4 + r;
      const float s = acc[ct][r] + b_g2[c];
      const ushort hi = f2bf(s);
      h2h[(size_t)i*512 + c] = hi;
      h2l[(size_t)i*512 + c] = f2bf(s - bf2f(hi));
    }
  }
}

// G3: [q|k|v] = h2 @ [Wq|Wk|Wv] + bias (3-term hi/lo)
__global__ __launch_bounds__(256) void k_g3(
    const ushort* __restrict__ h2h, const ushort* __restrict__ h2l,
    const ushort* __restrict__ Wth, const ushort* __restrict__ Wtl,
    const float* __restrict__ b_q, const float* __restrict__ b_k,
    const float* __restrict__ b_v,
    float* __restrict__ q_ws, ushort* __restrict__ kh, ushort* __restrict__ kl,
    ushort* __restrict__ vt)
{
  __shared__ __align__(16) ushort Ash[64*40], Asl[64*40], Bsh[64*40], Bsl[64*40];
  floatx4 acc[4];
  const int bM = blockIdx.x*64, bN = blockIdx.y*64;
  gemm_core3<512>(h2h, h2l, Wth, Wtl, bM, bN, acc, Ash, Asl, Bsh, Bsl);
  const int lane = threadIdx.x & 63, wave = threadIdx.x >> 6;
  const int quad = lane >> 4, m = lane & 15;
  #pragma unroll
  for (int ct = 0; ct < 4; ++ct) {
    const int c = bN + ct*16 + m;
    #pragma unroll
    for (int r = 0; r < 4; ++r) {
      const int i = bM + wave*16 + quad*4 + r;
      if (c < 256) {
        const float s = acc[ct][r] + b_q[c];
        q_ws[((size_t)(c >> 5)*N_ + i)*32 + (c & 31)] = s * QSCALE;
      } else if (c < 512) {
        const int cc = c - 256;
        const float s = acc[ct][r] + b_k[cc];
        const ushort hi = f2bf(s);
        kh[((size_t)(cc >> 5)*N_ + i)*32 + (cc & 31)] = hi;
        kl[((size_t)(cc >> 5)*N_ + i)*32 + (cc & 31)] = f2bf(s - bf2f(hi));
      } else {
        const int cc = c - 512;
        const float s = acc[ct][r] + b_v[cc];
        vt[((size_t)(cc >> 5)*144 + (cc & 31))*N_ + i] = f2bf(s);
      }
    }
  }
}

// G4: vg = g_src @ W_vg -> vt cols 32..127
__global__ __launch_bounds__(256) void k_g4(
    const ushort* __restrict__ g_src_b, const ushort* __restrict__ Wvgt,
    ushort* __restrict__ vt)
{
  __shared__ __align__(16) ushort As[64*40], Bs[64*40];
  floatx4 acc[4];
  const int bM = blockIdx.x*64, bN = blockIdx.y*64;
  gemm_core<256>(g_src_b, Wvgt, bM, bN, acc, As, Bs);
  const int lane = threadIdx.x & 63, wave = threadIdx.x >> 6;
  const int quad = lane >> 4, m = lane & 15;
  #pragma unroll
  for (int ct = 0; ct < 4; ++ct) {
    const int c = bN + ct*16 + m;
    const int hh = c >> 5, d = c & 31;
    #pragma unroll
    for (int r = 0; r < 4; ++r) {
      const int i3 = bM + wave*16 + quad*4 + r;
      const int i = i3 / 3, j = i3 - 3*i;
      vt[((size_t)hh*144 + 32 + j*32 + d)*N_ + i] = f2bf(acc[ct][r]);
    }
  }
}

// ---------------- K3: MFMA flash attention v3 -----------------------------------
// ones-col V (denominator via MFMA), DPP max (VALU pipe), exp2-domain softmax.
__global__ __launch_bounds__(256, 2) void k3_attn(
    const float* __restrict__ q_ws, const ushort* __restrict__ kh,
    const ushort* __restrict__ kl, const ushort* __restrict__ vt,
    ushort* __restrict__ out_v_b, ushort* __restrict__ out_g_b)
{
  __shared__ __align__(16) ushort Khs[64*40], Kls[64*40];  // 5 KiB each
  __shared__ __align__(16) ushort Vs[144*64];              // 18 KiB swizzled
  __shared__ __align__(16) ushort Pl[4*16*72];             // 9 KiB
  __shared__ float li_s[64];

  const int t    = threadIdx.x;
  const int wave = t >> 6;
  const int lane = t & 63;
  const int quad = lane >> 4;
  const int m    = lane & 15;
  const int h    = blockIdx.y;
  const int n0q  = blockIdx.x * 64;

  // Q fragments: direct global load + hi/lo split in registers
  union { short8 v; ushort u[8]; } Aqh, Aql;
  {
    const float* qp = q_ws + ((size_t)h*N_ + n0q + wave*16 + m)*32 + quad*8;
    #pragma unroll
    for (int jj = 0; jj < 8; ++jj) {
      const float x = qp[jj];
      const ushort hi = f2bf(x);
      Aqh.u[jj] = hi;
      Aql.u[jj] = f2bf(x - bf2f(hi));
    }
  }

  floatx4 Of[9];                     // nt 0..7 = values, nt 8 = denominator col
  #pragma unroll
  for (int nt = 0; nt < 9; ++nt) Of[nt] = {0.f, 0.f, 0.f, 0.f};
  float mi[4];
  #pragma unroll
  for (int r = 0; r < 4; ++r) mi[r] = -3.0e38f;

  const int krow = t >> 2, kch = (t & 3) * 8;

  for (int kt = 0; kt < 64; ++kt) {
    const int n0k = kt * 64;
    __syncthreads();
    // stage K hi/lo
    *(short8*)&Khs[krow*40 + kch] =
        *(const short8*)&kh[((size_t)h*N_ + n0k + krow)*32 + kch];
    *(short8*)&Kls[krow*40 + kch] =
        *(const short8*)&kl[((size_t)h*N_ + n0k + krow)*32 + kch];
    // stage V (144 cols incl. ones-col), XOR-swizzled 16B chunks
    #pragma unroll
    for (int p = 0; p < 5; ++p) {
      const int idx = p*256 + t;
      if (idx < 1152) {
        const int row = idx >> 3, g = idx & 7;
        const int pos = g ^ (row & 7);
        *(short8*)&Vs[(row*8 + pos)*8] =
            *(const short8*)&vt[((size_t)h*144 + row)*N_ + n0k + g*8];
      }
    }
    __syncthreads();

    // S = Q K^T (3-term hi/lo MFMA), exp2-domain logits
    floatx4 sf[4];
    #pragma unroll
    for (int kb = 0; kb < 4; ++kb) {
      const short8 bkh = *(const short8*)&Khs[(kb*16 + m)*40 + quad*8];
      const short8 bkl = *(const short8*)&Kls[(kb*16 + m)*40 + quad*8];
      floatx4 s = {0.f, 0.f, 0.f, 0.f};
      s = __builtin_amdgcn_mfma_f32_16x16x32_bf16(Aqh.v, bkl, s, 0, 0, 0);
      s = __builtin_amdgcn_mfma_f32_16x16x32_bf16(Aql.v, bkh, s, 0, 0, 0);
      s = __builtin_amdgcn_mfma_f32_16x16x32_bf16(Aqh.v, bkh, s, 0, 0, 0);
      sf[kb] = s;
    }

    // online max (DPP, VALU pipe); no sum reduction (ones-col handles it)
    float al[4];
    float p[4][4];
    #pragma unroll
    for (int r = 0; r < 4; ++r) {
      float nm = fmaxf(fmaxf(sf[0][r], sf[1][r]), fmaxf(sf[2][r], sf[3][r]));
      nm = dpp_max16(nm);
      const float mn = fmaxf(mi[r], nm);
      al[r] = exp2f(mi[r] - mn);
      mi[r] = mn;
      #pragma unroll
      for (int kb = 0; kb < 4; ++kb) p[kb][r] = exp2f(sf[kb][r] - mn);
    }
    #pragma unroll
    for (int nt = 0; nt < 9; ++nt)
      #pragma unroll
      for (int r = 0; r < 4; ++r) Of[nt][r] *= al[r];
    #pragma unroll
    for (int kb = 0; kb < 4; ++kb)
      #pragma unroll
      for (int r = 0; r < 4; ++r)
        Pl[wave*1152 + (quad*4 + r)*72 + kb*16 + m] = f2bf(p[kb][r]);

    // O += P @ V (9 n-tiles; nt 8 accumulates the denominator)
    #pragma unroll
    for (int ks = 0; ks < 2; ++ks) {
      const short8 ap = *(const short8*)&Pl[wave*1152 + m*72 + ks*32 + quad*8];
      #pragma unroll
      for (int nt = 0; nt < 9; ++nt) {
        const int row = nt*16 + m;
        const int pos = (ks*4 + quad) ^ (row & 7);
        const short8 bv = *(const short8*)&Vs[(row*8 + pos)*8];
        Of[nt] = __builtin_amdgcn_mfma_f32_16x16x32_bf16(ap, bv, Of[nt], 0, 0, 0);
      }
    }
  }

  // denominator lives at col 128 -> lanes m==0 of n-tile 8
  if (m == 0) {
    #pragma unroll
    for (int r = 0; r < 4; ++r) li_s[wave*16 + quad*4 + r] = Of[8][r];
  }
  __syncthreads();
  const floatx4 liv = *(const floatx4*)&li_s[wave*16 + quad*4];
  float linv[4];
  #pragma unroll
  for (int r = 0; r < 4; ++r) linv[r] = 1.0f / liv[r];
  #pragma unroll
  for (int nt = 0; nt < 8; ++nt) {
    #pragma unroll
    for (int r = 0; r < 4; ++r) {
      const float val = Of[nt][r] * linv[r];
      const int n = n0q + wave*16 + quad*4 + r;
      const int c = nt*16 + m;
      if (c < 32) {
        out_v_b[(size_t)n*256 + h*32 + c] = f2bf(val);
      } else {
        const int j = (c - 32) >> 5, cc = (c - 32) & 31;
        out_g_b[((size_t)n*3 + j)*256 + h*32 + cc] = f2bf(val);
      }
    }
  }
}

// ---------------- K5 chain: epilogue GEMMs (replace old k4 GEMV) ----------------
// k5a: tmp = out_v @ W_ng + b_ng + h*16  -> bf16
__global__ __launch_bounds__(256) void k5a_ng(
    const ushort* __restrict__ out_v_b, const ushort* __restrict__ Wngt,
    const float* __restrict__ b_ng, const float* __restrict__ h,
    ushort* __restrict__ tmp_b)
{
  __shared__ __align__(16) ushort As[64*40], Bs[64*40];
  floatx4 acc[4];
  const int bM = blockIdx.x*64, bN = blockIdx.y*64;
  gemm_core<256>(out_v_b, Wngt, bM, bN, acc, As, Bs);
  const int lane = threadIdx.x & 63, wave = threadIdx.x >> 6;
  const int quad = lane >> 4, m = lane & 15;
  #pragma unroll
  for (int ct = 0; ct < 4; ++ct) {
    const int c = bN + ct*16 + m;
    #pragma unroll
    for (int r = 0; r < 4; ++r) {
      const int i = bM + wave*16 + quad*4 + r;
      tmp_b[(size_t)i*256 + c] =
          f2bf(acc[ct][r] + b_ng[c] + h[(size_t)i*256 + c] * SQRT_E);
    }
  }
}

// k5b: gsum = out_g @ W_gout + g_src  -> bf16 (rows = node*3+j)
__global__ __launch_bounds__(256) void k5b_gout(
    const ushort* __restrict__ out_g_b, const ushort* __restrict__ Wgoutt,
    const ushort* __restrict__ g_src_b, ushort* __restrict__ gsum_b)
{
  __shared__ __align__(16) ushort As[64*40], Bs[64*40];
  floatx4 acc[4];
  const int bM = blockIdx.x*64, bN = blockIdx.y*64;
  gemm_core<256>(out_g_b, Wgoutt, bM, bN, acc, As, Bs);
  const int lane = threadIdx.x & 63, wave = threadIdx.x >> 6;
  const int quad = lane >> 4, m = lane & 15;
  #pragma unroll
  for (int ct = 0; ct < 4; ++ct) {
    const int c = bN + ct*16 + m;
    #pragma unroll
    for (int r = 0; r < 4; ++r) {
      const int i = bM + wave*16 + quad*4 + r;
      gsum_b[(size_t)i*256 + c] =
          f2bf(acc[ct][r] + bf2f(g_src_b[(size_t)i*256 + c]));
    }
  }
}

// k5c: h_out = tmp @ W_hdec + b_hdec -> f32 out[196608..]
__global__ __launch_bounds__(256) void k5c_hdec(
    const ushort* __restrict__ tmp_b, const ushort* __restrict__ Whdect,
    const float* __restrict__ b_hdec, float* __restrict__ out)
{
  __shared__ __align__(16) ushort As[64*40], Bs[64*40];
  floatx4 acc[4];
  const int bM = blockIdx.x*64, bN = blockIdx.y*64;
  gemm_core<256>(tmp_b, Whdect, bM, bN, acc, As, Bs);
  const int lane = threadIdx.x & 63, wave = threadIdx.x >> 6;
  const int quad = lane >> 4, m = lane & 15;
  #pragma unroll
  for (int ct = 0; ct < 4; ++ct) {
    const int c = bN + ct*16 + m;
    #pragma unroll
    for (int r = 0; r < 4; ++r) {
      const int i = bM + wave*16 + quad*4 + r;
      out[196608 + (size_t)i*256 + c] = acc[ct][r] + b_hdec[c];
    }
  }
}

// k5d: equ_out = gsum @ W_gdec -> f32 out[0..196608]  (M=12288, N=16, K=256)
__global__ __launch_bounds__(256) void k5d_gdec(
    const ushort* __restrict__ gsum_b, const ushort* __restrict__ Wgdect,
    float* __restrict__ out)
{
  __shared__ __align__(16) ushort As[64*40];
  __shared__ __align__(16) ushort Bs[16*40];
  const int t = threadIdx.x;
  const int wave = t >> 6, lane = t & 63, quad = lane >> 4, m = lane & 15;
  const int bM = blockIdx.x * 64;
  floatx4 acc = {0.f, 0.f, 0.f, 0.f};
  const int row = t >> 2, kq = (t & 3) * 8;
  for (int k0 = 0; k0 < 256; k0 += 32) {
    __syncthreads();
    *(short8*)&As[row*40 + kq] = *(const short8*)&gsum_b[(size_t)(bM+row)*256 + k0 + kq];
    if (t < 64)
      *(short8*)&Bs[(t>>2)*40 + kq] = *(const short8*)&Wgdect[(size_t)(t>>2)*256 + k0 + kq];
    __syncthreads();
    const short8 af = *(const short8*)&As[(wave*16 + m)*40 + quad*8];
    const short8 bf = *(const short8*)&Bs[m*40 + quad*8];
    acc = __builtin_amdgcn_mfma_f32_16x16x32_bf16(af, bf, acc, 0, 0, 0);
  }
  #pragma unroll
  for (int r = 0; r < 4; ++r)
    out[(size_t)(bM + wave*16 + quad*4 + r)*16 + m] = acc[r];
}

extern "C" void kernel_launch(void* const* d_in, const int* in_sizes, int n_in,
                              void* d_out, int out_size, void* d_ws, size_t ws_size,
                              hipStream_t stream) {
  const float* equ    = (const float*)d_in[0];
  const float* h      = (const float*)d_in[1];
  const float* W_equ  = (const float*)d_in[4];
  const float* W_gproj= (const float*)d_in[5];
  const float* W_vg   = (const float*)d_in[6];
  const float* W_g1   = (const float*)d_in[7];
  const float* b_g1   = (const float*)d_in[8];
  const float* W_g2   = (const float*)d_in[9];
  const float* b_g2   = (const float*)d_in[10];
  const float* W_q    = (const float*)d_in[11];
  const float* b_q    = (const float*)d_in[12];
  const float* W_k    = (const float*)d_in[13];
  const float* b_k    = (const float*)d_in[14];
  const float* W_v    = (const float*)d_in[15];
  const float* b_v    = (const float*)d_in[16];
  const float* W_ng   = (const float*)d_in[17];
  const float* b_ng   = (const float*)d_in[18];
  const float* W_gout = (const float*)d_in[19];
  const float* W_gdec = (const float*)d_in[20];
  const float* W_hdec = (const float*)d_in[21];
  const float* b_hdec = (const float*)d_in[22];
  float* out = (float*)d_out;

  // ---- workspace layout (lifetimes annotated), peak 46.5 MiB ----
  char* wsb = (char*)d_ws;
  constexpr size_t MiB = 1048576;
  float*  q_ws    = (float*) (wsb +  0*MiB);            // 4 MiB [G3 -> k3]
  ushort* kh      = (ushort*)(wsb +  4*MiB);            // 2 MiB [G3 -> k3]
  ushort* kl      = (ushort*)(wsb +  6*MiB);            // 2 MiB [G3 -> k3]
  ushort* vt      = (ushort*)(wsb +  8*MiB);            // 9 MiB [8][144][4096] [init/G3/G4 -> k3]
  ushort* h2h     = (ushort*)(wsb + 17*MiB);            // 4 MiB [prep/G2 -> G3]
  ushort* h2l     = (ushort*)(wsb + 21*MiB);            // 4 MiB
  ushort* g_src_b = (ushort*)(wsb + 25*MiB);            // 6 MiB [k1 -> G4,k5b]
  ushort* wbase   = (ushort*)(wsb + 31*MiB);            // 2.875 MiB [prep -> G4]
  ushort* Wg1t = wbase;                                 // 512x1024
  ushort* Wg2t = wbase + 524288;                        // 256x512
  ushort* Wth  = wbase + 655360;                        // 768x512 hi
  ushort* Wtl  = wbase + 1048576;                       // 768x512 lo
  ushort* Wvgt = wbase + 1441792;                       // 256x256
  ushort* wbase2  = (ushort*)(wsb + 34*MiB);            // 0.4 MiB [prep -> k5*]
  ushort* Wngt   = wbase2;                              // 256x256
  ushort* Wgoutt = wbase2 + 65536;                      // 256x256
  ushort* Whdect = wbase2 + 131072;                     // 256x256
  ushort* Wgdect = wbase2 + 196608;                     // 16x256
  ushort* gram_b  = (ushort*)(wsb + 34*MiB + 524288);   // 8 MiB [k1 -> G1]
  ushort* hidden  = (ushort*)(wsb + 42*MiB + 524288);   // 4 MiB [G1 -> G2]
  ushort* out_v_b = (ushort*)(wsb + 17*MiB);            // 2 MiB [k3 -> k5a] alias h2h
  ushort* out_g_b = (ushort*)(wsb + 19*MiB);            // 6 MiB [k3 -> k5b] alias h2h/h2l
  ushort* tmp_b   = (ushort*)(wsb + 42*MiB + 524288);   // 2 MiB [k5a -> k5c] alias hidden
  ushort* gsum_b  = (ushort*)(wsb + 34*MiB + 524288);   // 6 MiB [k5b -> k5d] alias gram_b

  // ---- prep ----
  k_transpose<<<dim3(32,16), 256, 0, stream>>>(W_g1,  Wg1t,   nullptr, 1024, 512, 0);
  k_transpose<<<dim3(16, 8), 256, 0, stream>>>(W_g2,  Wg2t,   nullptr,  512, 256, 0);
  k_transpose<<<dim3(16, 8), 256, 0, stream>>>(W_q,   Wth,           Wtl,           512, 256, 1);
  k_transpose<<<dim3(16, 8), 256, 0, stream>>>(W_k,   Wth + 256*512, Wtl + 256*512, 512, 256, 1);
  k_transpose<<<dim3(16, 8), 256, 0, stream>>>(W_v,   Wth + 512*512, Wtl + 512*512, 512, 256, 1);
  k_transpose<<<dim3( 8, 8), 256, 0, stream>>>(W_vg,  Wvgt,   nullptr,  256, 256, 0);
  k_transpose<<<dim3( 8, 8), 256, 0, stream>>>(W_ng,  Wngt,   nullptr,  256, 256, 0);
  k_transpose<<<dim3( 8, 8), 256, 0, stream>>>(W_gout,Wgoutt, nullptr,  256, 256, 0);
  k_transpose<<<dim3( 8, 8), 256, 0, stream>>>(W_hdec,Whdect, nullptr,  256, 256, 0);
  k_transpose<<<dim3( 8, 1), 256, 0, stream>>>(W_gdec,Wgdect, nullptr,  256,  16, 0);
  k_hsplit<<<4096, 256, 0, stream>>>(h, h2h, h2l);
  k_vinit<<<2048, 256, 0, stream>>>(vt);
  k1_pre<<<4096, 256, 0, stream>>>(equ, W_equ, W_gproj, g_src_b, gram_b);

  // ---- GEMM chain ----
  k_g1<<<dim3(64, 8), 256, 0, stream>>>(gram_b, Wg1t, b_g1, hidden);
  k_g2<<<dim3(64, 4), 256, 0, stream>>>(hidden, Wg2t, b_g2, h2h, h2l);
  k_g3<<<dim3(64,12), 256, 0, stream>>>(h2h, h2l, Wth, Wtl, b_q, b_k, b_v,
                                        q_ws, kh, kl, vt);
  k_g4<<<dim3(192,4), 256, 0, stream>>>(g_src_b, Wvgt, vt);

  // ---- attention ----
  dim3 g3(64, 8);
  k3_attn<<<g3, 256, 0, stream>>>(q_ws, kh, kl, vt, out_v_b, out_g_b);

  // ---- epilogue GEMMs ----
  k5a_ng  <<<dim3(64, 4), 256, 0, stream>>>(out_v_b, Wngt, b_ng, h, tmp_b);
  k5b_gout<<<dim3(192,4), 256, 0, stream>>>(out_g_b, Wgoutt, g_src_b, gsum_b);
  k5c_hdec<<<dim3(64, 4), 256, 0, stream>>>(tmp_b, Whdect, b_hdec, out);
  k5d_gdec<<<192, 256, 0, stream>>>(gsum_b, Wgdect, out);
}

// Round 7
// 381.353 us; speedup vs baseline: 5.1127x; 1.1400x over previous
//
#include <hip/hip_runtime.h>
#include <hip/hip_bf16.h>

typedef __attribute__((ext_vector_type(8))) short short8;
typedef __attribute__((ext_vector_type(4))) float floatx4;

constexpr int N_ = 4096;
constexpr float SQRT_E = 16.0f;
// q scale folded with log2(e): softmax computed in exp2 domain
constexpr float QSCALE = 0.17677669529663687f * 1.4426950408889634f;

__device__ __forceinline__ ushort f2bf(float x) {
  __hip_bfloat16 h = __float2bfloat16(x);
  return *reinterpret_cast<ushort*>(&h);
}
__device__ __forceinline__ float bf2f(ushort b) {
  unsigned int u = ((unsigned int)b) << 16;
  return __uint_as_float(u);
}

// all 16 lanes of each aligned 16-lane group get the group max (VALU DPP, not LDS)
__device__ __forceinline__ float dpp_max16(float x) {
  int v = __float_as_int(x);
  int y;
  y = __builtin_amdgcn_update_dpp(v, v, 0x128, 0xf, 0xf, false); // row_ror:8
  v = __float_as_int(fmaxf(__int_as_float(v), __int_as_float(y)));
  y = __builtin_amdgcn_update_dpp(v, v, 0x124, 0xf, 0xf, false); // row_ror:4
  v = __float_as_int(fmaxf(__int_as_float(v), __int_as_float(y)));
  y = __builtin_amdgcn_update_dpp(v, v, 0x122, 0xf, 0xf, false); // row_ror:2
  v = __float_as_int(fmaxf(__int_as_float(v), __int_as_float(y)));
  y = __builtin_amdgcn_update_dpp(v, v, 0x121, 0xf, 0xf, false); // row_ror:1
  v = __float_as_int(fmaxf(__int_as_float(v), __int_as_float(y)));
  return __int_as_float(v);
}

// ---------------- K1: g_src_b [N*3,256]bf16, gram_b [N,1024]bf16 ----------------
__global__ __launch_bounds__(256) void k1_pre(
    const float* __restrict__ equ, const float* __restrict__ W_equ,
    const float* __restrict__ W_gproj,
    ushort* __restrict__ g_src_b, ushort* __restrict__ gram_b)
{
  __shared__ float eq[48];
  __shared__ float gs[768];
  __shared__ float g2p[96];
  const int i = blockIdx.x;
  const int t = threadIdx.x;
  if (t < 48) eq[t] = equ[(size_t)i*48 + t];
  __syncthreads();
  #pragma unroll
  for (int j = 0; j < 3; ++j) {
    float s = 0.f;
    #pragma unroll
    for (int m = 0; m < 16; ++m) s += eq[j*16+m] * W_equ[m*256 + t];
    s *= SQRT_E;
    gs[j*256 + t] = s;
    g_src_b[((size_t)i*3 + j)*256 + t] = f2bf(s);
  }
  __syncthreads();
  if (t < 96) {
    const int j = t >> 5, a = t & 31;
    float s = 0.f;
    for (int e = 0; e < 256; ++e) s += gs[j*256+e] * W_gproj[e*32 + a];
    g2p[t] = s;
  }
  __syncthreads();
  #pragma unroll
  for (int r = 0; r < 4; ++r) {
    const int idx = r*256 + t;
    const int a = idx >> 5, b = idx & 31;
    const float s = g2p[a]*g2p[b] + g2p[32+a]*g2p[32+b] + g2p[64+a]*g2p[64+b];
    gram_b[(size_t)i*1024 + idx] = f2bf(s);
  }
}

// ---------------- prep: guarded weight transpose + bf16 (optional hi/lo) --------
__global__ __launch_bounds__(256) void k_transpose(
    const float* __restrict__ src, ushort* __restrict__ dsth,
    ushort* __restrict__ dstl, int R, int C, int hasLo)
{
  __shared__ float tile[32][33];
  const int r0 = blockIdx.x * 32, c0 = blockIdx.y * 32;
  const int tx = threadIdx.x & 31, ty = threadIdx.x >> 5;
  #pragma unroll
  for (int p = 0; p < 4; ++p) {
    const int lr = p*8 + ty;
    tile[lr][tx] = (r0+lr < R && c0+tx < C) ? src[(size_t)(r0+lr)*C + c0 + tx] : 0.f;
  }
  __syncthreads();
  #pragma unroll
  for (int p = 0; p < 4; ++p) {
    const int dc = p*8 + ty;
    if (c0+dc < C && r0+tx < R) {
      const float v = tile[tx][dc];
      const ushort hi = f2bf(v);
      dsth[(size_t)(c0+dc)*R + r0 + tx] = hi;
      if (hasLo) dstl[(size_t)(c0+dc)*R + r0 + tx] = f2bf(v - bf2f(hi));
    }
  }
}

// h_src half of h2 (cols 256..511), hi/lo split of h*16
__global__ __launch_bounds__(256) void k_hsplit(
    const float* __restrict__ h, ushort* __restrict__ h2h, ushort* __restrict__ h2l)
{
  const int i = blockIdx.x, t = threadIdx.x;
  const float v = h[(size_t)i*256 + t] * SQRT_E;
  const ushort hi = f2bf(v);
  h2h[(size_t)i*512 + 256 + t] = hi;
  h2l[(size_t)i*512 + 256 + t] = f2bf(v - bf2f(hi));
}

// init V extension cols 128..143 (col 128 = ones -> softmax denominator via MFMA)
__global__ __launch_bounds__(256) void k_vinit(ushort* __restrict__ vt) {
  const int idx = blockIdx.x*256 + threadIdx.x;   // 8*16*4096 = 524288 total
  const int n = idx & 4095;
  const int c16 = (idx >> 12) & 15;
  const int h = idx >> 16;
  vt[((size_t)h*144 + 128 + c16)*N_ + n] = (c16 == 0) ? (ushort)0x3F80 : (ushort)0;
}

// ---------------- shared GEMM core: C[64x64] = A[64xK] * Bt[64xK]^T ----------------
template<int KTOT>
__device__ __forceinline__ void gemm_core(
    const ushort* __restrict__ A, const ushort* __restrict__ Bt,
    int bM, int bN, floatx4 acc[4], ushort* As, ushort* Bs)
{
  const int t = threadIdx.x;
  const int wave = t >> 6, lane = t & 63, quad = lane >> 4, m = lane & 15;
  #pragma unroll
  for (int ct = 0; ct < 4; ++ct) acc[ct] = {0.f, 0.f, 0.f, 0.f};
  const int row = t >> 2, kq = (t & 3) * 8;
  for (int k0 = 0; k0 < KTOT; k0 += 32) {
    __syncthreads();
    *(short8*)&As[row*40 + kq] = *(const short8*)&A[(size_t)(bM+row)*KTOT + k0 + kq];
    *(short8*)&Bs[row*40 + kq] = *(const short8*)&Bt[(size_t)(bN+row)*KTOT + k0 + kq];
    __syncthreads();
    const short8 af = *(const short8*)&As[(wave*16 + m)*40 + quad*8];
    #pragma unroll
    for (int ct = 0; ct < 4; ++ct) {
      const short8 bf = *(const short8*)&Bs[(ct*16 + m)*40 + quad*8];
      acc[ct] = __builtin_amdgcn_mfma_f32_16x16x32_bf16(af, bf, acc[ct], 0, 0, 0);
    }
  }
}

// 3-term hi/lo core (q/k/v precision)
template<int KTOT>
__device__ __forceinline__ void gemm_core3(
    const ushort* __restrict__ Ah, const ushort* __restrict__ Al,
    const ushort* __restrict__ Bth, const ushort* __restrict__ Btl,
    int bM, int bN, floatx4 acc[4],
    ushort* Ash, ushort* Asl, ushort* Bsh, ushort* Bsl)
{
  const int t = threadIdx.x;
  const int wave = t >> 6, lane = t & 63, quad = lane >> 4, m = lane & 15;
  #pragma unroll
  for (int ct = 0; ct < 4; ++ct) acc[ct] = {0.f, 0.f, 0.f, 0.f};
  const int row = t >> 2, kq = (t & 3) * 8;
  for (int k0 = 0; k0 < KTOT; k0 += 32) {
    __syncthreads();
    *(short8*)&Ash[row*40 + kq] = *(const short8*)&Ah[(size_t)(bM+row)*KTOT + k0 + kq];
    *(short8*)&Asl[row*40 + kq] = *(const short8*)&Al[(size_t)(bM+row)*KTOT + k0 + kq];
    *(short8*)&Bsh[row*40 + kq] = *(const short8*)&Bth[(size_t)(bN+row)*KTOT + k0 + kq];
    *(short8*)&Bsl[row*40 + kq] = *(const short8*)&Btl[(size_t)(bN+row)*KTOT + k0 + kq];
    __syncthreads();
    const short8 ah = *(const short8*)&Ash[(wave*16 + m)*40 + quad*8];
    const short8 al = *(const short8*)&Asl[(wave*16 + m)*40 + quad*8];
    #pragma unroll
    for (int ct = 0; ct < 4; ++ct) {
      const short8 bh = *(const short8*)&Bsh[(ct*16 + m)*40 + quad*8];
      const short8 bl = *(const short8*)&Bsl[(ct*16 + m)*40 + quad*8];
      acc[ct] = __builtin_amdgcn_mfma_f32_16x16x32_bf16(ah, bl, acc[ct], 0, 0, 0);
      acc[ct] = __builtin_amdgcn_mfma_f32_16x16x32_bf16(al, bh, acc[ct], 0, 0, 0);
      acc[ct] = __builtin_amdgcn_mfma_f32_16x16x32_bf16(ah, bh, acc[ct], 0, 0, 0);
    }
  }
}

// G1: hidden = relu(gram @ W_g1 + b_g1)
__global__ __launch_bounds__(256) void k_g1(
    const ushort* __restrict__ gram_b, const ushort* __restrict__ Wg1t,
    const float* __restrict__ b_g1, ushort* __restrict__ hidden)
{
  __shared__ __align__(16) ushort As[64*40], Bs[64*40];
  floatx4 acc[4];
  const int bM = blockIdx.x*64, bN = blockIdx.y*64;
  gemm_core<1024>(gram_b, Wg1t, bM, bN, acc, As, Bs);
  const int lane = threadIdx.x & 63, wave = threadIdx.x >> 6;
  const int quad = lane >> 4, m = lane & 15;
  #pragma unroll
  for (int ct = 0; ct < 4; ++ct) {
    const int c = bN + ct*16 + m;
    #pragma unroll
    for (int r = 0; r < 4; ++r) {
      const int i = bM + wave*16 + quad*4 + r;
      hidden[(size_t)i*512 + c] = f2bf(fmaxf(acc[ct][r] + b_g1[c], 0.f));
    }
  }
}

// G2: g2 = hidden @ W_g2 + b_g2 -> hi/lo into h2 cols 0..255
__global__ __launch_bounds__(256) void k_g2(
    const ushort* __restrict__ hidden, const ushort* __restrict__ Wg2t,
    const float* __restrict__ b_g2, ushort* __restrict__ h2h, ushort* __restrict__ h2l)
{
  __shared__ __align__(16) ushort As[64*40], Bs[64*40];
  floatx4 acc[4];
  const int bM = blockIdx.x*64, bN = blockIdx.y*64;
  gemm_core<512>(hidden, Wg2t, bM, bN, acc, As, Bs);
  const int lane = threadIdx.x & 63, wave = threadIdx.x >> 6;
  const int quad = lane >> 4, m = lane & 15;
  #pragma unroll
  for (int ct = 0; ct < 4; ++ct) {
    const int c = bN + ct*16 + m;
    #pragma unroll
    for (int r = 0; r < 4; ++r) {
      const int i = bM + wave*16 + quad*4 + r;
      const float s = acc[ct][r] + b_g2[c];
      const ushort hi = f2bf(s);
      h2h[(size_t)i*512 + c] = hi;
      h2l[(size_t)i*512 + c] = f2bf(s - bf2f(hi));
    }
  }
}

// G3: [q|k|v] = h2 @ [Wq|Wk|Wv] + bias (3-term hi/lo)
__global__ __launch_bounds__(256) void k_g3(
    const ushort* __restrict__ h2h, const ushort* __restrict__ h2l,
    const ushort* __restrict__ Wth, const ushort* __restrict__ Wtl,
    const float* __restrict__ b_q, const float* __restrict__ b_k,
    const float* __restrict__ b_v,
    float* __restrict__ q_ws, ushort* __restrict__ kh, ushort* __restrict__ kl,
    ushort* __restrict__ vt)
{
  __shared__ __align__(16) ushort Ash[64*40], Asl[64*40], Bsh[64*40], Bsl[64*40];
  floatx4 acc[4];
  const int bM = blockIdx.x*64, bN = blockIdx.y*64;
  gemm_core3<512>(h2h, h2l, Wth, Wtl, bM, bN, acc, Ash, Asl, Bsh, Bsl);
  const int lane = threadIdx.x & 63, wave = threadIdx.x >> 6;
  const int quad = lane >> 4, m = lane & 15;
  #pragma unroll
  for (int ct = 0; ct < 4; ++ct) {
    const int c = bN + ct*16 + m;
    #pragma unroll
    for (int r = 0; r < 4; ++r) {
      const int i = bM + wave*16 + quad*4 + r;
      if (c < 256) {
        const float s = acc[ct][r] + b_q[c];
        q_ws[((size_t)(c >> 5)*N_ + i)*32 + (c & 31)] = s * QSCALE;
      } else if (c < 512) {
        const int cc = c - 256;
        const float s = acc[ct][r] + b_k[cc];
        const ushort hi = f2bf(s);
        kh[((size_t)(cc >> 5)*N_ + i)*32 + (cc & 31)] = hi;
        kl[((size_t)(cc >> 5)*N_ + i)*32 + (cc & 31)] = f2bf(s - bf2f(hi));
      } else {
        const int cc = c - 512;
        const float s = acc[ct][r] + b_v[cc];
        vt[((size_t)(cc >> 5)*144 + (cc & 31))*N_ + i] = f2bf(s);
      }
    }
  }
}

// G4: vg = g_src @ W_vg -> vt cols 32..127
__global__ __launch_bounds__(256) void k_g4(
    const ushort* __restrict__ g_src_b, const ushort* __restrict__ Wvgt,
    ushort* __restrict__ vt)
{
  __shared__ __align__(16) ushort As[64*40], Bs[64*40];
  floatx4 acc[4];
  const int bM = blockIdx.x*64, bN = blockIdx.y*64;
  gemm_core<256>(g_src_b, Wvgt, bM, bN, acc, As, Bs);
  const int lane = threadIdx.x & 63, wave = threadIdx.x >> 6;
  const int quad = lane >> 4, m = lane & 15;
  #pragma unroll
  for (int ct = 0; ct < 4; ++ct) {
    const int c = bN + ct*16 + m;
    const int hh = c >> 5, d = c & 31;
    #pragma unroll
    for (int r = 0; r < 4; ++r) {
      const int i3 = bM + wave*16 + quad*4 + r;
      const int i = i3 / 3, j = i3 - 3*i;
      vt[((size_t)hh*144 + 32 + j*32 + d)*N_ + i] = f2bf(acc[ct][r]);
    }
  }
}

// ---------------- K3: MFMA flash attention v4 -----------------------------------
// Split-K x2 (flash-decoding, partials + merge), register-prefetch staging,
// ones-col denominator, DPP max, exp2 softmax, truncated-bf16 P.
__global__ __launch_bounds__(256, 4) void k3_attn(
    const float* __restrict__ q_ws, const ushort* __restrict__ kh,
    const ushort* __restrict__ kl, const ushort* __restrict__ vt,
    ushort* __restrict__ Po0, ushort* __restrict__ Po1,
    float* __restrict__ Pml)
{
  __shared__ __align__(16) ushort Khs[64*40], Kls[64*40];  // 5 KiB each
  __shared__ __align__(16) ushort Vs[144*64];              // 18 KiB swizzled
  __shared__ __align__(16) ushort Pl[4*16*72];             // 9 KiB
  __shared__ float li_s[64];

  const int t    = threadIdx.x;
  const int wave = t >> 6;
  const int lane = t & 63;
  const int quad = lane >> 4;
  const int m    = lane & 15;
  const int h    = blockIdx.y;
  const int s    = blockIdx.z;
  const int n0q  = blockIdx.x * 64;

  // Q fragments: direct global load + hi/lo split in registers
  union { short8 v; ushort u[8]; } Aqh, Aql;
  {
    const float* qp = q_ws + ((size_t)h*N_ + n0q + wave*16 + m)*32 + quad*8;
    #pragma unroll
    for (int jj = 0; jj < 8; ++jj) {
      const float x = qp[jj];
      const ushort hi = f2bf(x);
      Aqh.u[jj] = hi;
      Aql.u[jj] = f2bf(x - bf2f(hi));
    }
  }

  floatx4 Of[9];                     // nt 0..7 = values, nt 8 = denominator col
  #pragma unroll
  for (int nt = 0; nt < 9; ++nt) Of[nt] = {0.f, 0.f, 0.f, 0.f};
  float mi[4];
  #pragma unroll
  for (int r = 0; r < 4; ++r) mi[r] = -3.0e38f;

  const int krow = t >> 2, kch = (t & 3) * 8;

  // register prefetch buffers (global -> reg -> LDS pipeline)
  short8 rK0, rK1, rV[5];
  const int kt0 = s * 32;            // this split covers tiles kt0 .. kt0+31

  // fetch tile 0 of this split
  {
    const int n0k = kt0 * 64;
    rK0 = *(const short8*)&kh[((size_t)h*N_ + n0k + krow)*32 + kch];
    rK1 = *(const short8*)&kl[((size_t)h*N_ + n0k + krow)*32 + kch];
    #pragma unroll
    for (int p = 0; p < 4; ++p) {
      const int idx = p*256 + t, row = idx >> 3, g = idx & 7;
      rV[p] = *(const short8*)&vt[((size_t)h*144 + row)*N_ + n0k + g*8];
    }
    if (t < 128) {
      const int idx = 1024 + t, row = idx >> 3, g = idx & 7;
      rV[4] = *(const short8*)&vt[((size_t)h*144 + row)*N_ + n0k + g*8];
    }
  }

  for (int i = 0; i < 32; ++i) {
    __syncthreads();   // prior tile's LDS reads complete
    // regs -> LDS
    *(short8*)&Khs[krow*40 + kch] = rK0;
    *(short8*)&Kls[krow*40 + kch] = rK1;
    #pragma unroll
    for (int p = 0; p < 4; ++p) {
      const int idx = p*256 + t, row = idx >> 3, g = idx & 7;
      const int pos = g ^ (row & 7);
      *(short8*)&Vs[(row*8 + pos)*8] = rV[p];
    }
    if (t < 128) {
      const int idx = 1024 + t, row = idx >> 3, g = idx & 7;
      const int pos = g ^ (row & 7);
      *(short8*)&Vs[(row*8 + pos)*8] = rV[4];
    }
    // kick off next tile's global loads (overlap with compute below)
    if (i + 1 < 32) {
      const int n0k = (kt0 + i + 1) * 64;
      rK0 = *(const short8*)&kh[((size_t)h*N_ + n0k + krow)*32 + kch];
      rK1 = *(const short8*)&kl[((size_t)h*N_ + n0k + krow)*32 + kch];
      #pragma unroll
      for (int p = 0; p < 4; ++p) {
        const int idx = p*256 + t, row = idx >> 3, g = idx & 7;
        rV[p] = *(const short8*)&vt[((size_t)h*144 + row)*N_ + n0k + g*8];
      }
      if (t < 128) {
        const int idx = 1024 + t, row = idx >> 3, g = idx & 7;
        rV[4] = *(const short8*)&vt[((size_t)h*144 + row)*N_ + n0k + g*8];
      }
    }
    __syncthreads();   // LDS writes visible

    // S = Q K^T (3-term hi/lo MFMA), exp2-domain logits
    floatx4 sf[4];
    #pragma unroll
    for (int kb = 0; kb < 4; ++kb) {
      const short8 bkh = *(const short8*)&Khs[(kb*16 + m)*40 + quad*8];
      const short8 bkl = *(const short8*)&Kls[(kb*16 + m)*40 + quad*8];
      floatx4 sv = {0.f, 0.f, 0.f, 0.f};
      sv = __builtin_amdgcn_mfma_f32_16x16x32_bf16(Aqh.v, bkl, sv, 0, 0, 0);
      sv = __builtin_amdgcn_mfma_f32_16x16x32_bf16(Aql.v, bkh, sv, 0, 0, 0);
      sv = __builtin_amdgcn_mfma_f32_16x16x32_bf16(Aqh.v, bkh, sv, 0, 0, 0);
      sf[kb] = sv;
    }

    // online max (DPP, VALU pipe); sum comes from the ones-col MFMA
    float al[4];
    #pragma unroll
    for (int r = 0; r < 4; ++r) {
      float nm = fmaxf(fmaxf(sf[0][r], sf[1][r]), fmaxf(sf[2][r], sf[3][r]));
      nm = dpp_max16(nm);
      const float mn = fmaxf(mi[r], nm);
      al[r] = exp2f(mi[r] - mn);
      mi[r] = mn;
    }
    // P = exp2(S - m), truncated to bf16 (bias cancels: denominator uses same P)
    #pragma unroll
    for (int kb = 0; kb < 4; ++kb)
      #pragma unroll
      for (int r = 0; r < 4; ++r) {
        const float pv = exp2f(sf[kb][r] - mi[r]);
        Pl[wave*1152 + (quad*4 + r)*72 + kb*16 + m] =
            (ushort)(__float_as_uint(pv) >> 16);
      }
    #pragma unroll
    for (int nt = 0; nt < 9; ++nt)
      #pragma unroll
      for (int r = 0; r < 4; ++r) Of[nt][r] *= al[r];

    // O += P @ V (9 n-tiles; nt 8 accumulates the denominator)
    #pragma unroll
    for (int ks = 0; ks < 2; ++ks) {
      const short8 ap = *(const short8*)&Pl[wave*1152 + m*72 + ks*32 + quad*8];
      #pragma unroll
      for (int nt = 0; nt < 9; ++nt) {
        const int row = nt*16 + m;
        const int pos = (ks*4 + quad) ^ (row & 7);
        const short8 bv = *(const short8*)&Vs[(row*8 + pos)*8];
        Of[nt] = __builtin_amdgcn_mfma_f32_16x16x32_bf16(ap, bv, Of[nt], 0, 0, 0);
      }
    }
  }

  // denominator lives at col 128 -> lanes m==0 of n-tile 8
  if (m == 0) {
    #pragma unroll
    for (int r = 0; r < 4; ++r) li_s[wave*16 + quad*4 + r] = Of[8][r];
  }
  __syncthreads();
  const floatx4 liv = *(const floatx4*)&li_s[wave*16 + quad*4];
  float linv[4];
  #pragma unroll
  for (int r = 0; r < 4; ++r) linv[r] = 1.0f / liv[r];

  ushort* Po = s ? Po1 : Po0;
  #pragma unroll
  for (int nt = 0; nt < 8; ++nt) {
    #pragma unroll
    for (int r = 0; r < 4; ++r) {
      const int n = n0q + wave*16 + quad*4 + r;
      Po[((size_t)h*N_ + n)*128 + nt*16 + m] = f2bf(Of[nt][r] * linv[r]);
    }
  }
  if (m == 0) {
    #pragma unroll
    for (int r = 0; r < 4; ++r) {
      const int n = n0q + wave*16 + quad*4 + r;
      Pml[(((size_t)s*8 + h)*N_ + n)*2 + 0] = mi[r];
      Pml[(((size_t)s*8 + h)*N_ + n)*2 + 1] = Of[8][r];
    }
  }
}

// ---------------- merge: combine 2 split-K partials, scatter to out layouts -----
__global__ __launch_bounds__(256) void k_merge(
    const ushort* __restrict__ Po0, const ushort* __restrict__ Po1,
    const float* __restrict__ Pml,
    ushort* __restrict__ out_v_b, ushort* __restrict__ out_g_b)
{
  const int idx = blockIdx.x*256 + threadIdx.x;   // [h][n][128]
  const int c = idx & 127;
  const int n = (idx >> 7) & 4095;
  const int h = idx >> 19;
  const float m1 = Pml[(((size_t)0*8 + h)*N_ + n)*2 + 0];
  const float l1 = Pml[(((size_t)0*8 + h)*N_ + n)*2 + 1];
  const float m2 = Pml[(((size_t)1*8 + h)*N_ + n)*2 + 0];
  const float l2 = Pml[(((size_t)1*8 + h)*N_ + n)*2 + 1];
  const float M = fmaxf(m1, m2);
  const float w1 = exp2f(m1 - M) * l1;
  const float w2 = exp2f(m2 - M) * l2;
  const float v1 = bf2f(Po0[((size_t)h*N_ + n)*128 + c]);
  const float v2 = bf2f(Po1[((size_t)h*N_ + n)*128 + c]);
  const float val = (w1*v1 + w2*v2) / (w1 + w2);
  if (c < 32) {
    out_v_b[(size_t)n*256 + h*32 + c] = f2bf(val);
  } else {
    const int j = (c - 32) >> 5, cc = (c - 32) & 31;
    out_g_b[((size_t)n*3 + j)*256 + h*32 + cc] = f2bf(val);
  }
}

// ---------------- K5 chain: epilogue GEMMs ----------------
__global__ __launch_bounds__(256) void k5a_ng(
    const ushort* __restrict__ out_v_b, const ushort* __restrict__ Wngt,
    const float* __restrict__ b_ng, const float* __restrict__ h,
    ushort* __restrict__ tmp_b)
{
  __shared__ __align__(16) ushort As[64*40], Bs[64*40];
  floatx4 acc[4];
  const int bM = blockIdx.x*64, bN = blockIdx.y*64;
  gemm_core<256>(out_v_b, Wngt, bM, bN, acc, As, Bs);
  const int lane = threadIdx.x & 63, wave = threadIdx.x >> 6;
  const int quad = lane >> 4, m = lane & 15;
  #pragma unroll
  for (int ct = 0; ct < 4; ++ct) {
    const int c = bN + ct*16 + m;
    #pragma unroll
    for (int r = 0; r < 4; ++r) {
      const int i = bM + wave*16 + quad*4 + r;
      tmp_b[(size_t)i*256 + c] =
          f2bf(acc[ct][r] + b_ng[c] + h[(size_t)i*256 + c] * SQRT_E);
    }
  }
}

__global__ __launch_bounds__(256) void k5b_gout(
    const ushort* __restrict__ out_g_b, const ushort* __restrict__ Wgoutt,
    const ushort* __restrict__ g_src_b, ushort* __restrict__ gsum_b)
{
  __shared__ __align__(16) ushort As[64*40], Bs[64*40];
  floatx4 acc[4];
  const int bM = blockIdx.x*64, bN = blockIdx.y*64;
  gemm_core<256>(out_g_b, Wgoutt, bM, bN, acc, As, Bs);
  const int lane = threadIdx.x & 63, wave = threadIdx.x >> 6;
  const int quad = lane >> 4, m = lane & 15;
  #pragma unroll
  for (int ct = 0; ct < 4; ++ct) {
    const int c = bN + ct*16 + m;
    #pragma unroll
    for (int r = 0; r < 4; ++r) {
      const int i = bM + wave*16 + quad*4 + r;
      gsum_b[(size_t)i*256 + c] =
          f2bf(acc[ct][r] + bf2f(g_src_b[(size_t)i*256 + c]));
    }
  }
}

__global__ __launch_bounds__(256) void k5c_hdec(
    const ushort* __restrict__ tmp_b, const ushort* __restrict__ Whdect,
    const float* __restrict__ b_hdec, float* __restrict__ out)
{
  __shared__ __align__(16) ushort As[64*40], Bs[64*40];
  floatx4 acc[4];
  const int bM = blockIdx.x*64, bN = blockIdx.y*64;
  gemm_core<256>(tmp_b, Whdect, bM, bN, acc, As, Bs);
  const int lane = threadIdx.x & 63, wave = threadIdx.x >> 6;
  const int quad = lane >> 4, m = lane & 15;
  #pragma unroll
  for (int ct = 0; ct < 4; ++ct) {
    const int c = bN + ct*16 + m;
    #pragma unroll
    for (int r = 0; r < 4; ++r) {
      const int i = bM + wave*16 + quad*4 + r;
      out[196608 + (size_t)i*256 + c] = acc[ct][r] + b_hdec[c];
    }
  }
}

__global__ __launch_bounds__(256) void k5d_gdec(
    const ushort* __restrict__ gsum_b, const ushort* __restrict__ Wgdect,
    float* __restrict__ out)
{
  __shared__ __align__(16) ushort As[64*40];
  __shared__ __align__(16) ushort Bs[16*40];
  const int t = threadIdx.x;
  const int wave = t >> 6, lane = t & 63, quad = lane >> 4, m = lane & 15;
  const int bM = blockIdx.x * 64;
  floatx4 acc = {0.f, 0.f, 0.f, 0.f};
  const int row = t >> 2, kq = (t & 3) * 8;
  for (int k0 = 0; k0 < 256; k0 += 32) {
    __syncthreads();
    *(short8*)&As[row*40 + kq] = *(const short8*)&gsum_b[(size_t)(bM+row)*256 + k0 + kq];
    if (t < 64)
      *(short8*)&Bs[(t>>2)*40 + kq] = *(const short8*)&Wgdect[(size_t)(t>>2)*256 + k0 + kq];
    __syncthreads();
    const short8 af = *(const short8*)&As[(wave*16 + m)*40 + quad*8];
    const short8 bf = *(const short8*)&Bs[m*40 + quad*8];
    acc = __builtin_amdgcn_mfma_f32_16x16x32_bf16(af, bf, acc, 0, 0, 0);
  }
  #pragma unroll
  for (int r = 0; r < 4; ++r)
    out[(size_t)(bM + wave*16 + quad*4 + r)*16 + m] = acc[r];
}

extern "C" void kernel_launch(void* const* d_in, const int* in_sizes, int n_in,
                              void* d_out, int out_size, void* d_ws, size_t ws_size,
                              hipStream_t stream) {
  const float* equ    = (const float*)d_in[0];
  const float* h      = (const float*)d_in[1];
  const float* W_equ  = (const float*)d_in[4];
  const float* W_gproj= (const float*)d_in[5];
  const float* W_vg   = (const float*)d_in[6];
  const float* W_g1   = (const float*)d_in[7];
  const float* b_g1   = (const float*)d_in[8];
  const float* W_g2   = (const float*)d_in[9];
  const float* b_g2   = (const float*)d_in[10];
  const float* W_q    = (const float*)d_in[11];
  const float* b_q    = (const float*)d_in[12];
  const float* W_k    = (const float*)d_in[13];
  const float* b_k    = (const float*)d_in[14];
  const float* W_v    = (const float*)d_in[15];
  const float* b_v    = (const float*)d_in[16];
  const float* W_ng   = (const float*)d_in[17];
  const float* b_ng   = (const float*)d_in[18];
  const float* W_gout = (const float*)d_in[19];
  const float* W_gdec = (const float*)d_in[20];
  const float* W_hdec = (const float*)d_in[21];
  const float* b_hdec = (const float*)d_in[22];
  float* out = (float*)d_out;

  // ---- workspace layout (lifetimes annotated), peak 47.5 MiB ----
  char* wsb = (char*)d_ws;
  constexpr size_t MiB = 1048576;
  float*  q_ws    = (float*) (wsb +  0*MiB);            // 4 MiB [G3 -> k3]
  ushort* kh      = (ushort*)(wsb +  4*MiB);            // 2 MiB [G3 -> k3]
  ushort* kl      = (ushort*)(wsb +  6*MiB);            // 2 MiB [G3 -> k3]
  ushort* vt      = (ushort*)(wsb +  8*MiB);            // 9 MiB [init/G3/G4 -> k3]
  ushort* h2h     = (ushort*)(wsb + 17*MiB);            // 4 MiB [prep/G2 -> G3]
  ushort* h2l     = (ushort*)(wsb + 21*MiB);            // 4 MiB
  ushort* g_src_b = (ushort*)(wsb + 25*MiB);            // 6 MiB [k1 -> G4,k5b]
  ushort* wbase   = (ushort*)(wsb + 31*MiB);            // 2.875 MiB [prep -> G4]
  ushort* Wg1t = wbase;                                 // 512x1024
  ushort* Wg2t = wbase + 524288;                        // 256x512
  ushort* Wth  = wbase + 655360;                        // 768x512 hi
  ushort* Wtl  = wbase + 1048576;                       // 768x512 lo
  ushort* Wvgt = wbase + 1441792;                       // 256x256
  ushort* wbase2  = (ushort*)(wsb + 34*MiB);            // 0.4 MiB [prep -> k5*]
  ushort* Wngt   = wbase2;                              // 256x256
  ushort* Wgoutt = wbase2 + 65536;                      // 256x256
  ushort* Whdect = wbase2 + 131072;                     // 256x256
  ushort* Wgdect = wbase2 + 196608;                     // 16x256
  ushort* gram_b  = (ushort*)(wsb + 34*MiB + 524288);   // 8 MiB [k1 -> G1]
  ushort* hidden  = (ushort*)(wsb + 42*MiB + 524288);   // 4 MiB [G1 -> G2]
  // split-K attention partials:
  ushort* Po0     = (ushort*)(wsb + 17*MiB);            // 8 MiB [k3 -> merge] alias h2h/h2l (dead after G3)
  ushort* Po1     = (ushort*)(wsb + 34*MiB + 524288);   // 8 MiB [k3 -> merge] alias gram_b (dead after G1)
  float*  Pml     = (float*) (wsb + 47*MiB);            // 0.5 MiB [k3 -> merge]
  ushort* out_v_b = (ushort*)(wsb +  4*MiB);            // 2 MiB [merge -> k5a] alias kh/kl (dead after k3)
  ushort* out_g_b = (ushort*)(wsb +  8*MiB);            // 6 MiB [merge -> k5b] alias vt (dead after k3)
  ushort* tmp_b   = (ushort*)(wsb + 42*MiB + 524288);   // 2 MiB [k5a -> k5c] alias hidden (dead after G2)
  ushort* gsum_b  = (ushort*)(wsb + 34*MiB + 524288);   // 6 MiB [k5b -> k5d] alias Po1 (dead after merge)

  // ---- prep ----
  k_transpose<<<dim3(32,16), 256, 0, stream>>>(W_g1,  Wg1t,   nullptr, 1024, 512, 0);
  k_transpose<<<dim3(16, 8), 256, 0, stream>>>(W_g2,  Wg2t,   nullptr,  512, 256, 0);
  k_transpose<<<dim3(16, 8), 256, 0, stream>>>(W_q,   Wth,           Wtl,           512, 256, 1);
  k_transpose<<<dim3(16, 8), 256, 0, stream>>>(W_k,   Wth + 256*512, Wtl + 256*512, 512, 256, 1);
  k_transpose<<<dim3(16, 8), 256, 0, stream>>>(W_v,   Wth + 512*512, Wtl + 512*512, 512, 256, 1);
  k_transpose<<<dim3( 8, 8), 256, 0, stream>>>(W_vg,  Wvgt,   nullptr,  256, 256, 0);
  k_transpose<<<dim3( 8, 8), 256, 0, stream>>>(W_ng,  Wngt,   nullptr,  256, 256, 0);
  k_transpose<<<dim3( 8, 8), 256, 0, stream>>>(W_gout,Wgoutt, nullptr,  256, 256, 0);
  k_transpose<<<dim3( 8, 8), 256, 0, stream>>>(W_hdec,Whdect, nullptr,  256, 256, 0);
  k_transpose<<<dim3( 8, 1), 256, 0, stream>>>(W_gdec,Wgdect, nullptr,  256,  16, 0);
  k_hsplit<<<4096, 256, 0, stream>>>(h, h2h, h2l);
  k_vinit<<<2048, 256, 0, stream>>>(vt);
  k1_pre<<<4096, 256, 0, stream>>>(equ, W_equ, W_gproj, g_src_b, gram_b);

  // ---- GEMM chain ----
  k_g1<<<dim3(64, 8), 256, 0, stream>>>(gram_b, Wg1t, b_g1, hidden);
  k_g2<<<dim3(64, 4), 256, 0, stream>>>(hidden, Wg2t, b_g2, h2h, h2l);
  k_g3<<<dim3(64,12), 256, 0, stream>>>(h2h, h2l, Wth, Wtl, b_q, b_k, b_v,
                                        q_ws, kh, kl, vt);
  k_g4<<<dim3(192,4), 256, 0, stream>>>(g_src_b, Wvgt, vt);

  // ---- attention (split-K x2) + merge ----
  dim3 g3(64, 8, 2);
  k3_attn<<<g3, 256, 0, stream>>>(q_ws, kh, kl, vt, Po0, Po1, Pml);
  k_merge<<<16384, 256, 0, stream>>>(Po0, Po1, Pml, out_v_b, out_g_b);

  // ---- epilogue GEMMs ----
  k5a_ng  <<<dim3(64, 4), 256, 0, stream>>>(out_v_b, Wngt, b_ng, h, tmp_b);
  k5b_gout<<<dim3(192,4), 256, 0, stream>>>(out_g_b, Wgoutt, g_src_b, gsum_b);
  k5c_hdec<<<dim3(64, 4), 256, 0, stream>>>(tmp_b, Whdect, b_hdec, out);
  k5d_gdec<<<192, 256, 0, stream>>>(gsum_b, Wgdect, out);
}

// Round 8
// 316.872 us; speedup vs baseline: 6.1531x; 1.2035x over previous
//
#include <hip/hip_runtime.h>
#include <hip/hip_bf16.h>

typedef __attribute__((ext_vector_type(8))) short short8;
typedef __attribute__((ext_vector_type(4))) float floatx4;

constexpr int N_ = 4096;
constexpr float SQRT_E = 16.0f;
// q scale folded with log2(e): softmax computed in exp2 domain
constexpr float QSCALE = 0.17677669529663687f * 1.4426950408889634f;

__device__ __forceinline__ ushort f2bf(float x) {
  __hip_bfloat16 h = __float2bfloat16(x);
  return *reinterpret_cast<ushort*>(&h);
}
__device__ __forceinline__ float bf2f(ushort b) {
  unsigned int u = ((unsigned int)b) << 16;
  return __uint_as_float(u);
}

// all 16 lanes of each aligned 16-lane group get the group max (VALU DPP, not LDS)
__device__ __forceinline__ float dpp_max16(float x) {
  int v = __float_as_int(x);
  int y;
  y = __builtin_amdgcn_update_dpp(v, v, 0x128, 0xf, 0xf, false); // row_ror:8
  v = __float_as_int(fmaxf(__int_as_float(v), __int_as_float(y)));
  y = __builtin_amdgcn_update_dpp(v, v, 0x124, 0xf, 0xf, false); // row_ror:4
  v = __float_as_int(fmaxf(__int_as_float(v), __int_as_float(y)));
  y = __builtin_amdgcn_update_dpp(v, v, 0x122, 0xf, 0xf, false); // row_ror:2
  v = __float_as_int(fmaxf(__int_as_float(v), __int_as_float(y)));
  y = __builtin_amdgcn_update_dpp(v, v, 0x121, 0xf, 0xf, false); // row_ror:1
  v = __float_as_int(fmaxf(__int_as_float(v), __int_as_float(y)));
  return __int_as_float(v);
}

// ---------------- transpose helper (device side of mega-prep) ----------------
__device__ __forceinline__ void do_transpose(
    const float* __restrict__ src, ushort* __restrict__ dsth,
    ushort* __restrict__ dstl, int R, int C, int lb, int cb_shift,
    float* smem, int hasLo)
{
  float (*tile)[33] = (float(*)[33])smem;
  const int r0 = (lb >> cb_shift) * 32;
  const int c0 = (lb & ((1 << cb_shift) - 1)) * 32;
  const int tx = threadIdx.x & 31, ty = threadIdx.x >> 5;
  #pragma unroll
  for (int p = 0; p < 4; ++p) {
    const int lr = p*8 + ty;
    tile[lr][tx] = (r0+lr < R && c0+tx < C) ? src[(size_t)(r0+lr)*C + c0 + tx] : 0.f;
  }
  __syncthreads();
  #pragma unroll
  for (int p = 0; p < 4; ++p) {
    const int dc = p*8 + ty;
    if (c0+dc < C && r0+tx < R) {
      const float v = tile[tx][dc];
      const ushort hi = f2bf(v);
      dsth[(size_t)(c0+dc)*R + r0 + tx] = hi;
      if (hasLo) dstl[(size_t)(c0+dc)*R + r0 + tx] = f2bf(v - bf2f(hi));
    }
  }
}

// ---------------- mega-prep: all transposes + hsplit + vinit + k1 in ONE launch --
__global__ __launch_bounds__(256) void k_prep(
    const float* __restrict__ equ, const float* __restrict__ h,
    const float* __restrict__ W_equ, const float* __restrict__ W_gproj,
    const float* __restrict__ W_g1, const float* __restrict__ W_g2,
    const float* __restrict__ W_q, const float* __restrict__ W_k,
    const float* __restrict__ W_v, const float* __restrict__ W_vg,
    const float* __restrict__ W_ng, const float* __restrict__ W_gout,
    const float* __restrict__ W_hdec, const float* __restrict__ W_gdec,
    ushort* __restrict__ Wg1t, ushort* __restrict__ Wg2t,
    ushort* __restrict__ Wth, ushort* __restrict__ Wtl,
    ushort* __restrict__ Wvgt, ushort* __restrict__ Wngt,
    ushort* __restrict__ Wgoutt, ushort* __restrict__ Whdect,
    ushort* __restrict__ Wgdect,
    ushort* __restrict__ h2h, ushort* __restrict__ h2l,
    ushort* __restrict__ vt,
    ushort* __restrict__ g_src_b, ushort* __restrict__ gram_b)
{
  __shared__ __align__(16) float smem[1056];
  const int b = blockIdx.x;
  const int t = threadIdx.x;

  if (b < 512) {            // W_g1 [1024,512] -> Wg1t
    do_transpose(W_g1, Wg1t, nullptr, 1024, 512, b, 4, smem, 0);
  } else if (b < 640) {     // W_g2 [512,256]
    do_transpose(W_g2, Wg2t, nullptr, 512, 256, b-512, 3, smem, 0);
  } else if (b < 768) {     // W_q hi/lo
    do_transpose(W_q, Wth, Wtl, 512, 256, b-640, 3, smem, 1);
  } else if (b < 896) {     // W_k hi/lo
    do_transpose(W_k, Wth + 256*512, Wtl + 256*512, 512, 256, b-768, 3, smem, 1);
  } else if (b < 1024) {    // W_v hi/lo
    do_transpose(W_v, Wth + 512*512, Wtl + 512*512, 512, 256, b-896, 3, smem, 1);
  } else if (b < 1088) {    // W_vg
    do_transpose(W_vg, Wvgt, nullptr, 256, 256, b-1024, 3, smem, 0);
  } else if (b < 1152) {    // W_ng
    do_transpose(W_ng, Wngt, nullptr, 256, 256, b-1088, 3, smem, 0);
  } else if (b < 1216) {    // W_gout
    do_transpose(W_gout, Wgoutt, nullptr, 256, 256, b-1152, 3, smem, 0);
  } else if (b < 1280) {    // W_hdec
    do_transpose(W_hdec, Whdect, nullptr, 256, 256, b-1216, 3, smem, 0);
  } else if (b < 1288) {    // W_gdec [256,16]
    do_transpose(W_gdec, Wgdect, nullptr, 256, 16, b-1280, 0, smem, 0);
  } else if (b < 5384) {    // hsplit: h_src half of h2 (hi/lo)
    const int i = b - 1288;
    const float v = h[(size_t)i*256 + t] * SQRT_E;
    const ushort hi = f2bf(v);
    h2h[(size_t)i*512 + 256 + t] = hi;
    h2l[(size_t)i*512 + 256 + t] = f2bf(v - bf2f(hi));
  } else if (b < 7432) {    // vinit: ones-col + zero ext
    const int idx = (b - 5384)*256 + t;
    const int n = idx & 4095;
    const int c16 = (idx >> 12) & 15;
    const int hh = idx >> 16;
    vt[((size_t)hh*144 + 128 + c16)*N_ + n] = (c16 == 0) ? (ushort)0x3F80 : (ushort)0;
  } else {                  // k1: g_src_b + gram_b
    float* eq  = smem;        // 48
    float* gs  = smem + 48;   // 768
    float* g2p = smem + 816;  // 96
    const int i = b - 7432;
    if (t < 48) eq[t] = equ[(size_t)i*48 + t];
    __syncthreads();
    #pragma unroll
    for (int j = 0; j < 3; ++j) {
      float s = 0.f;
      #pragma unroll
      for (int m = 0; m < 16; ++m) s += eq[j*16+m] * W_equ[m*256 + t];
      s *= SQRT_E;
      gs[j*256 + t] = s;
      g_src_b[((size_t)i*3 + j)*256 + t] = f2bf(s);
    }
    __syncthreads();
    if (t < 96) {
      const int j = t >> 5, a = t & 31;
      float s = 0.f;
      for (int e = 0; e < 256; ++e) s += gs[j*256+e] * W_gproj[e*32 + a];
      g2p[t] = s;
    }
    __syncthreads();
    #pragma unroll
    for (int r = 0; r < 4; ++r) {
      const int idx = r*256 + t;
      const int a = idx >> 5, bb = idx & 31;
      const float s = g2p[a]*g2p[bb] + g2p[32+a]*g2p[32+bb] + g2p[64+a]*g2p[64+bb];
      gram_b[(size_t)i*1024 + idx] = f2bf(s);
    }
  }
}

// ---------------- shared GEMM cores ----------------
template<int KTOT>
__device__ __forceinline__ void gemm_core(
    const ushort* __restrict__ A, const ushort* __restrict__ Bt,
    int bM, int bN, floatx4 acc[4], ushort* As, ushort* Bs)
{
  const int t = threadIdx.x;
  const int wave = t >> 6, lane = t & 63, quad = lane >> 4, m = lane & 15;
  #pragma unroll
  for (int ct = 0; ct < 4; ++ct) acc[ct] = {0.f, 0.f, 0.f, 0.f};
  const int row = t >> 2, kq = (t & 3) * 8;
  for (int k0 = 0; k0 < KTOT; k0 += 32) {
    __syncthreads();
    *(short8*)&As[row*40 + kq] = *(const short8*)&A[(size_t)(bM+row)*KTOT + k0 + kq];
    *(short8*)&Bs[row*40 + kq] = *(const short8*)&Bt[(size_t)(bN+row)*KTOT + k0 + kq];
    __syncthreads();
    const short8 af = *(const short8*)&As[(wave*16 + m)*40 + quad*8];
    #pragma unroll
    for (int ct = 0; ct < 4; ++ct) {
      const short8 bf = *(const short8*)&Bs[(ct*16 + m)*40 + quad*8];
      acc[ct] = __builtin_amdgcn_mfma_f32_16x16x32_bf16(af, bf, acc[ct], 0, 0, 0);
    }
  }
}

template<int KTOT>
__device__ __forceinline__ void gemm_core3(
    const ushort* __restrict__ Ah, const ushort* __restrict__ Al,
    const ushort* __restrict__ Bth, const ushort* __restrict__ Btl,
    int bM, int bN, floatx4 acc[4],
    ushort* Ash, ushort* Asl, ushort* Bsh, ushort* Bsl)
{
  const int t = threadIdx.x;
  const int wave = t >> 6, lane = t & 63, quad = lane >> 4, m = lane & 15;
  #pragma unroll
  for (int ct = 0; ct < 4; ++ct) acc[ct] = {0.f, 0.f, 0.f, 0.f};
  const int row = t >> 2, kq = (t & 3) * 8;
  for (int k0 = 0; k0 < KTOT; k0 += 32) {
    __syncthreads();
    *(short8*)&Ash[row*40 + kq] = *(const short8*)&Ah[(size_t)(bM+row)*KTOT + k0 + kq];
    *(short8*)&Asl[row*40 + kq] = *(const short8*)&Al[(size_t)(bM+row)*KTOT + k0 + kq];
    *(short8*)&Bsh[row*40 + kq] = *(const short8*)&Bth[(size_t)(bN+row)*KTOT + k0 + kq];
    *(short8*)&Bsl[row*40 + kq] = *(const short8*)&Btl[(size_t)(bN+row)*KTOT + k0 + kq];
    __syncthreads();
    const short8 ah = *(const short8*)&Ash[(wave*16 + m)*40 + quad*8];
    const short8 al = *(const short8*)&Asl[(wave*16 + m)*40 + quad*8];
    #pragma unroll
    for (int ct = 0; ct < 4; ++ct) {
      const short8 bh = *(const short8*)&Bsh[(ct*16 + m)*40 + quad*8];
      const short8 bl = *(const short8*)&Bsl[(ct*16 + m)*40 + quad*8];
      acc[ct] = __builtin_amdgcn_mfma_f32_16x16x32_bf16(ah, bl, acc[ct], 0, 0, 0);
      acc[ct] = __builtin_amdgcn_mfma_f32_16x16x32_bf16(al, bh, acc[ct], 0, 0, 0);
      acc[ct] = __builtin_amdgcn_mfma_f32_16x16x32_bf16(ah, bh, acc[ct], 0, 0, 0);
    }
  }
}

// G1: hidden = relu(gram @ W_g1 + b_g1)
__global__ __launch_bounds__(256) void k_g1(
    const ushort* __restrict__ gram_b, const ushort* __restrict__ Wg1t,
    const float* __restrict__ b_g1, ushort* __restrict__ hidden)
{
  __shared__ __align__(16) ushort As[64*40], Bs[64*40];
  floatx4 acc[4];
  const int bM = blockIdx.x*64, bN = blockIdx.y*64;
  gemm_core<1024>(gram_b, Wg1t, bM, bN, acc, As, Bs);
  const int lane = threadIdx.x & 63, wave = threadIdx.x >> 6;
  const int quad = lane >> 4, m = lane & 15;
  #pragma unroll
  for (int ct = 0; ct < 4; ++ct) {
    const int c = bN + ct*16 + m;
    #pragma unroll
    for (int r = 0; r < 4; ++r) {
      const int i = bM + wave*16 + quad*4 + r;
      hidden[(size_t)i*512 + c] = f2bf(fmaxf(acc[ct][r] + b_g1[c], 0.f));
    }
  }
}

// G2: g2 = hidden @ W_g2 + b_g2 -> hi/lo into h2 cols 0..255
__global__ __launch_bounds__(256) void k_g2(
    const ushort* __restrict__ hidden, const ushort* __restrict__ Wg2t,
    const float* __restrict__ b_g2, ushort* __restrict__ h2h, ushort* __restrict__ h2l)
{
  __shared__ __align__(16) ushort As[64*40], Bs[64*40];
  floatx4 acc[4];
  const int bM = blockIdx.x*64, bN = blockIdx.y*64;
  gemm_core<512>(hidden, Wg2t, bM, bN, acc, As, Bs);
  const int lane = threadIdx.x & 63, wave = threadIdx.x >> 6;
  const int quad = lane >> 4, m = lane & 15;
  #pragma unroll
  for (int ct = 0; ct < 4; ++ct) {
    const int c = bN + ct*16 + m;
    #pragma unroll
    for (int r = 0; r < 4; ++r) {
      const int i = bM + wave*16 + quad*4 + r;
      const float s = acc[ct][r] + b_g2[c];
      const ushort hi = f2bf(s);
      h2h[(size_t)i*512 + c] = hi;
      h2l[(size_t)i*512 + c] = f2bf(s - bf2f(hi));
    }
  }
}

// G3+G4 fused: qkv projection (hi/lo) and vg projection
__global__ __launch_bounds__(256) void k_g34(
    const ushort* __restrict__ h2h, const ushort* __restrict__ h2l,
    const ushort* __restrict__ Wth, const ushort* __restrict__ Wtl,
    const float* __restrict__ b_q, const float* __restrict__ b_k,
    const float* __restrict__ b_v,
    const ushort* __restrict__ g_src_b, const ushort* __restrict__ Wvgt,
    float* __restrict__ q_ws, ushort* __restrict__ kh, ushort* __restrict__ kl,
    ushort* __restrict__ vt)
{
  __shared__ __align__(16) ushort S0[64*40], S1[64*40], S2[64*40], S3[64*40];
  const int lb = blockIdx.y*192 + blockIdx.x;     // grid (192,8) = 1536
  const int lane = threadIdx.x & 63, wave = threadIdx.x >> 6;
  const int quad = lane >> 4, m = lane & 15;
  floatx4 acc[4];
  if (lb < 768) {
    // ---- G3 ----
    const int bM = (lb & 63)*64, bN = (lb >> 6)*64;
    gemm_core3<512>(h2h, h2l, Wth, Wtl, bM, bN, acc, S0, S1, S2, S3);
    #pragma unroll
    for (int ct = 0; ct < 4; ++ct) {
      const int c = bN + ct*16 + m;
      #pragma unroll
      for (int r = 0; r < 4; ++r) {
        const int i = bM + wave*16 + quad*4 + r;
        if (c < 256) {
          const float s = acc[ct][r] + b_q[c];
          q_ws[((size_t)(c >> 5)*N_ + i)*32 + (c & 31)] = s * QSCALE;
        } else if (c < 512) {
          const int cc = c - 256;
          const float s = acc[ct][r] + b_k[cc];
          const ushort hi = f2bf(s);
          kh[((size_t)(cc >> 5)*N_ + i)*32 + (cc & 31)] = hi;
          kl[((size_t)(cc >> 5)*N_ + i)*32 + (cc & 31)] = f2bf(s - bf2f(hi));
        } else {
          const int cc = c - 512;
          const float s = acc[ct][r] + b_v[cc];
          vt[((size_t)(cc >> 5)*144 + (cc & 31))*N_ + i] = f2bf(s);
        }
      }
    }
  } else {
    // ---- G4 ----
    const int lb2 = lb - 768;
    const int bM = (lb2 >> 2)*64, bN = (lb2 & 3)*64;
    gemm_core<256>(g_src_b, Wvgt, bM, bN, acc, S0, S1);
    #pragma unroll
    for (int ct = 0; ct < 4; ++ct) {
      const int c = bN + ct*16 + m;
      const int hh = c >> 5, d = c & 31;
      #pragma unroll
      for (int r = 0; r < 4; ++r) {
        const int i3 = bM + wave*16 + quad*4 + r;
        const int i = i3 / 3, j = i3 - 3*i;
        vt[((size_t)hh*144 + 32 + j*32 + d)*N_ + i] = f2bf(acc[ct][r]);
      }
    }
  }
}

// ---------------- K3: MFMA flash attention v5 -----------------------------------
// Split-K x2, register-prefetch (pointer-bumped), ones-col denominator,
// deferred rescale (exp2 domain, threshold 20), DPP max, truncated-bf16 P.
__global__ __launch_bounds__(256, 4) void k3_attn(
    const float* __restrict__ q_ws, const ushort* __restrict__ kh,
    const ushort* __restrict__ kl, const ushort* __restrict__ vt,
    ushort* __restrict__ Po0, ushort* __restrict__ Po1,
    float* __restrict__ Pml)
{
  __shared__ __align__(16) ushort Khs[64*40], Kls[64*40];  // 5 KiB each
  __shared__ __align__(16) ushort Vs[144*64];              // 18 KiB swizzled
  __shared__ __align__(16) ushort Pl[4*16*72];             // 9 KiB
  __shared__ float li_s[64];

  const int t    = threadIdx.x;
  const int wave = t >> 6;
  const int lane = t & 63;
  const int quad = lane >> 4;
  const int m    = lane & 15;
  const int h    = blockIdx.y;
  const int s    = blockIdx.z;
  const int n0q  = blockIdx.x * 64;

  // Q fragments: direct global load + hi/lo split in registers
  union { short8 v; ushort u[8]; } Aqh, Aql;
  {
    const float* qp = q_ws + ((size_t)h*N_ + n0q + wave*16 + m)*32 + quad*8;
    #pragma unroll
    for (int jj = 0; jj < 8; ++jj) {
      const float x = qp[jj];
      const ushort hi = f2bf(x);
      Aqh.u[jj] = hi;
      Aql.u[jj] = f2bf(x - bf2f(hi));
    }
  }

  floatx4 Of[9];                     // nt 0..7 = values, nt 8 = denominator col
  #pragma unroll
  for (int nt = 0; nt < 9; ++nt) Of[nt] = {0.f, 0.f, 0.f, 0.f};
  float mi[4];
  #pragma unroll
  for (int r = 0; r < 4; ++r) mi[r] = -3.0e38f;

  const int krow = t >> 2, kch = (t & 3) * 8;
  const int kt0 = s * 32;

  // pointer-bumped staging addresses (strength-reduced)
  const ushort* pKh = kh + ((size_t)h*N_ + kt0*64 + krow)*32 + kch;
  const ushort* pKl = kl + ((size_t)h*N_ + kt0*64 + krow)*32 + kch;
  const ushort* pV[4];
  int wV[4];                          // precomputed swizzled LDS write offsets
  #pragma unroll
  for (int p = 0; p < 4; ++p) {
    const int idx = p*256 + t, row = idx >> 3, g = idx & 7;
    pV[p] = vt + ((size_t)h*144 + row)*N_ + kt0*64 + g*8;
    wV[p] = (row*8 + (g ^ (row & 7)))*8;
  }
  const ushort* pV4 = nullptr;
  int wV4 = 0;
  if (t < 128) {
    const int idx = 1024 + t, row = idx >> 3, g = idx & 7;
    pV4 = vt + ((size_t)h*144 + row)*N_ + kt0*64 + g*8;
    wV4 = (row*8 + (g ^ (row & 7)))*8;
  }

  // fetch tile 0
  short8 rK0 = *(const short8*)pKh;
  short8 rK1 = *(const short8*)pKl;
  short8 rV[4], rV4e;
  #pragma unroll
  for (int p = 0; p < 4; ++p) rV[p] = *(const short8*)pV[p];
  if (t < 128) rV4e = *(const short8*)pV4;

  for (int i = 0; i < 32; ++i) {
    __syncthreads();   // prior tile's LDS reads complete
    *(short8*)&Khs[krow*40 + kch] = rK0;
    *(short8*)&Kls[krow*40 + kch] = rK1;
    #pragma unroll
    for (int p = 0; p < 4; ++p) *(short8*)&Vs[wV[p]] = rV[p];
    if (t < 128) *(short8*)&Vs[wV4] = rV4e;
    if (i + 1 < 32) {
      pKh += 2048; pKl += 2048;
      rK0 = *(const short8*)pKh;
      rK1 = *(const short8*)pKl;
      #pragma unroll
      for (int p = 0; p < 4; ++p) { pV[p] += 64; rV[p] = *(const short8*)pV[p]; }
      if (t < 128) { pV4 += 64; rV4e = *(const short8*)pV4; }
    }
    __syncthreads();   // LDS writes visible

    // S = Q K^T (3-term hi/lo MFMA), exp2-domain logits
    floatx4 sf[4];
    #pragma unroll
    for (int kb = 0; kb < 4; ++kb) {
      const short8 bkh = *(const short8*)&Khs[(kb*16 + m)*40 + quad*8];
      const short8 bkl = *(const short8*)&Kls[(kb*16 + m)*40 + quad*8];
      floatx4 sv = {0.f, 0.f, 0.f, 0.f};
      sv = __builtin_amdgcn_mfma_f32_16x16x32_bf16(Aqh.v, bkl, sv, 0, 0, 0);
      sv = __builtin_amdgcn_mfma_f32_16x16x32_bf16(Aql.v, bkh, sv, 0, 0, 0);
      sv = __builtin_amdgcn_mfma_f32_16x16x32_bf16(Aqh.v, bkh, sv, 0, 0, 0);
      sf[kb] = sv;
    }

    // deferred rescale: only rescale O when tile max exceeds applied max by >20
    float tm[4];
    bool need = false;
    #pragma unroll
    for (int r = 0; r < 4; ++r) {
      float nm = fmaxf(fmaxf(sf[0][r], sf[1][r]), fmaxf(sf[2][r], sf[3][r]));
      tm[r] = dpp_max16(nm);
      need |= (tm[r] > mi[r] + 20.f);
    }
    if (__any(need)) {
      #pragma unroll
      for (int r = 0; r < 4; ++r) {
        const float mn = fmaxf(mi[r], tm[r]);
        const float al = exp2f(mi[r] - mn);
        mi[r] = mn;
        #pragma unroll
        for (int nt = 0; nt < 9; ++nt) Of[nt][r] *= al;
      }
    }
    // P = exp2(S - mi_applied), truncated to bf16 (may exceed 1, bounded by 2^20)
    #pragma unroll
    for (int kb = 0; kb < 4; ++kb)
      #pragma unroll
      for (int r = 0; r < 4; ++r) {
        const float pv = exp2f(sf[kb][r] - mi[r]);
        Pl[wave*1152 + (quad*4 + r)*72 + kb*16 + m] =
            (ushort)(__float_as_uint(pv) >> 16);
      }

    // O += P @ V (9 n-tiles; nt 8 accumulates the denominator)
    #pragma unroll
    for (int ks = 0; ks < 2; ++ks) {
      const short8 ap = *(const short8*)&Pl[wave*1152 + m*72 + ks*32 + quad*8];
      #pragma unroll
      for (int nt = 0; nt < 9; ++nt) {
        const int row = nt*16 + m;
        const int pos = (ks*4 + quad) ^ (row & 7);
        const short8 bv = *(const short8*)&Vs[(row*8 + pos)*8];
        Of[nt] = __builtin_amdgcn_mfma_f32_16x16x32_bf16(ap, bv, Of[nt], 0, 0, 0);
      }
    }
  }

  // denominator lives at col 128 -> lanes m==0 of n-tile 8
  if (m == 0) {
    #pragma unroll
    for (int r = 0; r < 4; ++r) li_s[wave*16 + quad*4 + r] = Of[8][r];
  }
  __syncthreads();
  const floatx4 liv = *(const floatx4*)&li_s[wave*16 + quad*4];
  float linv[4];
  #pragma unroll
  for (int r = 0; r < 4; ++r) linv[r] = 1.0f / liv[r];

  ushort* Po = s ? Po1 : Po0;
  #pragma unroll
  for (int nt = 0; nt < 8; ++nt) {
    #pragma unroll
    for (int r = 0; r < 4; ++r) {
      const int n = n0q + wave*16 + quad*4 + r;
      Po[((size_t)h*N_ + n)*128 + nt*16 + m] = f2bf(Of[nt][r] * linv[r]);
    }
  }
  if (m == 0) {
    #pragma unroll
    for (int r = 0; r < 4; ++r) {
      const int n = n0q + wave*16 + quad*4 + r;
      Pml[(((size_t)s*8 + h)*N_ + n)*2 + 0] = mi[r];
      Pml[(((size_t)s*8 + h)*N_ + n)*2 + 1] = Of[8][r];
    }
  }
}

// ---------------- merge: combine 2 split-K partials (8 elems/thread) ------------
__global__ __launch_bounds__(256) void k_merge(
    const ushort* __restrict__ Po0, const ushort* __restrict__ Po1,
    const float* __restrict__ Pml,
    ushort* __restrict__ out_v_b, ushort* __restrict__ out_g_b)
{
  const int idx = blockIdx.x*256 + threadIdx.x;   // 524288 = 8 h * 4096 n * 16 chunks
  const int c0 = (idx & 15) * 8;
  const int n  = (idx >> 4) & 4095;
  const int h  = idx >> 16;
  const float m1 = Pml[(((size_t)0*8 + h)*N_ + n)*2 + 0];
  const float l1 = Pml[(((size_t)0*8 + h)*N_ + n)*2 + 1];
  const float m2 = Pml[(((size_t)1*8 + h)*N_ + n)*2 + 0];
  const float l2 = Pml[(((size_t)1*8 + h)*N_ + n)*2 + 1];
  const float M = fmaxf(m1, m2);
  const float w1 = exp2f(m1 - M) * l1;
  const float w2 = exp2f(m2 - M) * l2;
  const float inv = 1.0f / (w1 + w2);
  union { short8 v; ushort u[8]; } a, b, res;
  a.v = *(const short8*)&Po0[((size_t)h*N_ + n)*128 + c0];
  b.v = *(const short8*)&Po1[((size_t)h*N_ + n)*128 + c0];
  #pragma unroll
  for (int j = 0; j < 8; ++j)
    res.u[j] = f2bf((w1*bf2f(a.u[j]) + w2*bf2f(b.u[j])) * inv);
  if (c0 < 32) {
    *(short8*)&out_v_b[(size_t)n*256 + h*32 + c0] = res.v;
  } else {
    const int j = (c0 - 32) >> 5, cc = (c0 - 32) & 31;
    *(short8*)&out_g_b[((size_t)n*3 + j)*256 + h*32 + cc] = res.v;
  }
}

// ---------------- k5a+k5b fused ----------------
__global__ __launch_bounds__(256) void k56ab(
    const ushort* __restrict__ out_v_b, const ushort* __restrict__ Wngt,
    const float* __restrict__ b_ng, const float* __restrict__ h,
    ushort* __restrict__ tmp_b,
    const ushort* __restrict__ out_g_b, const ushort* __restrict__ Wgoutt,
    const ushort* __restrict__ g_src_b, ushort* __restrict__ gsum_b)
{
  __shared__ __align__(16) ushort As[64*40], Bs[64*40];
  floatx4 acc[4];
  const int lane = threadIdx.x & 63, wave = threadIdx.x >> 6;
  const int quad = lane >> 4, m = lane & 15;
  const int bN = blockIdx.y*64;
  if (blockIdx.x < 64) {
    const int bM = blockIdx.x*64;
    gemm_core<256>(out_v_b, Wngt, bM, bN, acc, As, Bs);
    #pragma unroll
    for (int ct = 0; ct < 4; ++ct) {
      const int c = bN + ct*16 + m;
      #pragma unroll
      for (int r = 0; r < 4; ++r) {
        const int i = bM + wave*16 + quad*4 + r;
        tmp_b[(size_t)i*256 + c] =
            f2bf(acc[ct][r] + b_ng[c] + h[(size_t)i*256 + c] * SQRT_E);
      }
    }
  } else {
    const int bM = (blockIdx.x - 64)*64;
    gemm_core<256>(out_g_b, Wgoutt, bM, bN, acc, As, Bs);
    #pragma unroll
    for (int ct = 0; ct < 4; ++ct) {
      const int c = bN + ct*16 + m;
      #pragma unroll
      for (int r = 0; r < 4; ++r) {
        const int i = bM + wave*16 + quad*4 + r;
        gsum_b[(size_t)i*256 + c] =
            f2bf(acc[ct][r] + bf2f(g_src_b[(size_t)i*256 + c]));
      }
    }
  }
}

// ---------------- k5c+k5d fused ----------------
__global__ __launch_bounds__(256) void k56cd(
    const ushort* __restrict__ tmp_b, const ushort* __restrict__ Whdect,
    const float* __restrict__ b_hdec,
    const ushort* __restrict__ gsum_b, const ushort* __restrict__ Wgdect,
    float* __restrict__ out)
{
  __shared__ __align__(16) ushort As[64*40], Bs[64*40];
  const int t = threadIdx.x;
  const int lane = t & 63, wave = t >> 6;
  const int quad = lane >> 4, m = lane & 15;
  if (blockIdx.x < 64) {
    floatx4 acc[4];
    const int bM = blockIdx.x*64, bN = blockIdx.y*64;
    gemm_core<256>(tmp_b, Whdect, bM, bN, acc, As, Bs);
    #pragma unroll
    for (int ct = 0; ct < 4; ++ct) {
      const int c = bN + ct*16 + m;
      #pragma unroll
      for (int r = 0; r < 4; ++r) {
        const int i = bM + wave*16 + quad*4 + r;
        out[196608 + (size_t)i*256 + c] = acc[ct][r] + b_hdec[c];
      }
    }
  } else if (blockIdx.y == 0) {
    const int bM = (blockIdx.x - 64)*64;
    floatx4 acc = {0.f, 0.f, 0.f, 0.f};
    const int row = t >> 2, kq = (t & 3) * 8;
    for (int k0 = 0; k0 < 256; k0 += 32) {
      __syncthreads();
      *(short8*)&As[row*40 + kq] = *(const short8*)&gsum_b[(size_t)(bM+row)*256 + k0 + kq];
      if (t < 64)
        *(short8*)&Bs[(t>>2)*40 + kq] = *(const short8*)&Wgdect[(size_t)(t>>2)*256 + k0 + kq];
      __syncthreads();
      const short8 af = *(const short8*)&As[(wave*16 + m)*40 + quad*8];
      const short8 bf = *(const short8*)&Bs[m*40 + quad*8];
      acc = __builtin_amdgcn_mfma_f32_16x16x32_bf16(af, bf, acc, 0, 0, 0);
    }
    #pragma unroll
    for (int r = 0; r < 4; ++r)
      out[(size_t)(bM + wave*16 + quad*4 + r)*16 + m] = acc[r];
  }
}

extern "C" void kernel_launch(void* const* d_in, const int* in_sizes, int n_in,
                              void* d_out, int out_size, void* d_ws, size_t ws_size,
                              hipStream_t stream) {
  const float* equ    = (const float*)d_in[0];
  const float* h      = (const float*)d_in[1];
  const float* W_equ  = (const float*)d_in[4];
  const float* W_gproj= (const float*)d_in[5];
  const float* W_vg   = (const float*)d_in[6];
  const float* W_g1   = (const float*)d_in[7];
  const float* b_g1   = (const float*)d_in[8];
  const float* W_g2   = (const float*)d_in[9];
  const float* b_g2   = (const float*)d_in[10];
  const float* W_q    = (const float*)d_in[11];
  const float* b_q    = (const float*)d_in[12];
  const float* W_k    = (const float*)d_in[13];
  const float* b_k    = (const float*)d_in[14];
  const float* W_v    = (const float*)d_in[15];
  const float* b_v    = (const float*)d_in[16];
  const float* W_ng   = (const float*)d_in[17];
  const float* b_ng   = (const float*)d_in[18];
  const float* W_gout = (const float*)d_in[19];
  const float* W_gdec = (const float*)d_in[20];
  const float* W_hdec = (const float*)d_in[21];
  const float* b_hdec = (const float*)d_in[22];
  float* out = (float*)d_out;

  // ---- workspace layout (lifetimes annotated), peak 47.5 MiB ----
  char* wsb = (char*)d_ws;
  constexpr size_t MiB = 1048576;
  float*  q_ws    = (float*) (wsb +  0*MiB);            // 4 MiB [G3 -> k3]
  ushort* kh      = (ushort*)(wsb +  4*MiB);            // 2 MiB [G3 -> k3]
  ushort* kl      = (ushort*)(wsb +  6*MiB);            // 2 MiB [G3 -> k3]
  ushort* vt      = (ushort*)(wsb +  8*MiB);            // 9 MiB [prep/G3/G4 -> k3]
  ushort* h2h     = (ushort*)(wsb + 17*MiB);            // 4 MiB [prep/G2 -> G3]
  ushort* h2l     = (ushort*)(wsb + 21*MiB);            // 4 MiB
  ushort* g_src_b = (ushort*)(wsb + 25*MiB);            // 6 MiB [prep -> G4,k5b]
  ushort* wbase   = (ushort*)(wsb + 31*MiB);            // 2.875 MiB [prep -> G4]
  ushort* Wg1t = wbase;                                 // 512x1024
  ushort* Wg2t = wbase + 524288;                        // 256x512
  ushort* Wth  = wbase + 655360;                        // 768x512 hi
  ushort* Wtl  = wbase + 1048576;                       // 768x512 lo
  ushort* Wvgt = wbase + 1441792;                       // 256x256
  ushort* wbase2  = (ushort*)(wsb + 34*MiB);            // 0.4 MiB [prep -> k5*]
  ushort* Wngt   = wbase2;                              // 256x256
  ushort* Wgoutt = wbase2 + 65536;                      // 256x256
  ushort* Whdect = wbase2 + 131072;                     // 256x256
  ushort* Wgdect = wbase2 + 196608;                     // 16x256
  ushort* gram_b  = (ushort*)(wsb + 34*MiB + 524288);   // 8 MiB [prep -> G1]
  ushort* hidden  = (ushort*)(wsb + 42*MiB + 524288);   // 4 MiB [G1 -> G2]
  // split-K attention partials:
  ushort* Po0     = (ushort*)(wsb + 17*MiB);            // 8 MiB [k3 -> merge] alias h2h/h2l
  ushort* Po1     = (ushort*)(wsb + 34*MiB + 524288);   // 8 MiB [k3 -> merge] alias gram_b
  float*  Pml     = (float*) (wsb + 47*MiB);            // 0.5 MiB [k3 -> merge]
  ushort* out_v_b = (ushort*)(wsb +  4*MiB);            // 2 MiB [merge -> k5a] alias kh/kl
  ushort* out_g_b = (ushort*)(wsb +  8*MiB);            // 6 MiB [merge -> k5b] alias vt
  ushort* tmp_b   = (ushort*)(wsb + 42*MiB + 524288);   // 2 MiB [k5a -> k5c] alias hidden
  ushort* gsum_b  = (ushort*)(wsb + 34*MiB + 524288);   // 6 MiB [k5b -> k5d] alias Po1

  // ---- 1 mega-prep launch (10 transposes + hsplit + vinit + k1) ----
  k_prep<<<11528, 256, 0, stream>>>(
      equ, h, W_equ, W_gproj, W_g1, W_g2, W_q, W_k, W_v,
      W_vg, W_ng, W_gout, W_hdec, W_gdec,
      Wg1t, Wg2t, Wth, Wtl, Wvgt, Wngt, Wgoutt, Whdect, Wgdect,
      h2h, h2l, vt, g_src_b, gram_b);

  // ---- GEMM chain ----
  k_g1<<<dim3(64, 8), 256, 0, stream>>>(gram_b, Wg1t, b_g1, hidden);
  k_g2<<<dim3(64, 4), 256, 0, stream>>>(hidden, Wg2t, b_g2, h2h, h2l);
  k_g34<<<dim3(192, 8), 256, 0, stream>>>(h2h, h2l, Wth, Wtl, b_q, b_k, b_v,
                                          g_src_b, Wvgt, q_ws, kh, kl, vt);

  // ---- attention (split-K x2) + merge ----
  dim3 g3(64, 8, 2);
  k3_attn<<<g3, 256, 0, stream>>>(q_ws, kh, kl, vt, Po0, Po1, Pml);
  k_merge<<<2048, 256, 0, stream>>>(Po0, Po1, Pml, out_v_b, out_g_b);

  // ---- epilogue GEMMs (fused pairs) ----
  k56ab<<<dim3(256, 4), 256, 0, stream>>>(out_v_b, Wngt, b_ng, h, tmp_b,
                                          out_g_b, Wgoutt, g_src_b, gsum_b);
  k56cd<<<dim3(256, 4), 256, 0, stream>>>(tmp_b, Whdect, b_hdec,
                                          gsum_b, Wgdect, out);
}

// Round 9
// 311.427 us; speedup vs baseline: 6.2607x; 1.0175x over previous
//
#include <hip/hip_runtime.h>
#include <hip/hip_bf16.h>

typedef __attribute__((ext_vector_type(8))) short short8;
typedef __attribute__((ext_vector_type(4))) float floatx4;

constexpr int N_ = 4096;
constexpr float SQRT_E = 16.0f;
// q scale folded with log2(e): softmax computed in exp2 domain
constexpr float QSCALE = 0.17677669529663687f * 1.4426950408889634f;

__device__ __forceinline__ ushort f2bf(float x) {
  __hip_bfloat16 h = __float2bfloat16(x);
  return *reinterpret_cast<ushort*>(&h);
}
__device__ __forceinline__ float bf2f(ushort b) {
  unsigned int u = ((unsigned int)b) << 16;
  return __uint_as_float(u);
}

// all 16 lanes of each aligned 16-lane group get the group max (VALU DPP, not LDS)
__device__ __forceinline__ float dpp_max16(float x) {
  int v = __float_as_int(x);
  int y;
  y = __builtin_amdgcn_update_dpp(v, v, 0x128, 0xf, 0xf, false); // row_ror:8
  v = __float_as_int(fmaxf(__int_as_float(v), __int_as_float(y)));
  y = __builtin_amdgcn_update_dpp(v, v, 0x124, 0xf, 0xf, false); // row_ror:4
  v = __float_as_int(fmaxf(__int_as_float(v), __int_as_float(y)));
  y = __builtin_amdgcn_update_dpp(v, v, 0x122, 0xf, 0xf, false); // row_ror:2
  v = __float_as_int(fmaxf(__int_as_float(v), __int_as_float(y)));
  y = __builtin_amdgcn_update_dpp(v, v, 0x121, 0xf, 0xf, false); // row_ror:1
  v = __float_as_int(fmaxf(__int_as_float(v), __int_as_float(y)));
  return __int_as_float(v);
}

// ---------------- transpose helper (device side of mega-prep) ----------------
__device__ __forceinline__ void do_transpose(
    const float* __restrict__ src, ushort* __restrict__ dsth,
    ushort* __restrict__ dstl, int R, int C, int lb, int cb_shift,
    float* smem, int hasLo)
{
  float (*tile)[33] = (float(*)[33])smem;
  const int r0 = (lb >> cb_shift) * 32;
  const int c0 = (lb & ((1 << cb_shift) - 1)) * 32;
  const int tx = threadIdx.x & 31, ty = threadIdx.x >> 5;
  #pragma unroll
  for (int p = 0; p < 4; ++p) {
    const int lr = p*8 + ty;
    tile[lr][tx] = (r0+lr < R && c0+tx < C) ? src[(size_t)(r0+lr)*C + c0 + tx] : 0.f;
  }
  __syncthreads();
  #pragma unroll
  for (int p = 0; p < 4; ++p) {
    const int dc = p*8 + ty;
    if (c0+dc < C && r0+tx < R) {
      const float v = tile[tx][dc];
      const ushort hi = f2bf(v);
      dsth[(size_t)(c0+dc)*R + r0 + tx] = hi;
      if (hasLo) dstl[(size_t)(c0+dc)*R + r0 + tx] = f2bf(v - bf2f(hi));
    }
  }
}

// ---------------- mega-prep: all transposes + hsplit + vinit + k1 in ONE launch --
__global__ __launch_bounds__(256) void k_prep(
    const float* __restrict__ equ, const float* __restrict__ h,
    const float* __restrict__ W_equ, const float* __restrict__ W_gproj,
    const float* __restrict__ W_g1, const float* __restrict__ W_g2,
    const float* __restrict__ W_q, const float* __restrict__ W_k,
    const float* __restrict__ W_v, const float* __restrict__ W_vg,
    const float* __restrict__ W_ng, const float* __restrict__ W_gout,
    const float* __restrict__ W_hdec, const float* __restrict__ W_gdec,
    ushort* __restrict__ Wg1t, ushort* __restrict__ Wg2t,
    ushort* __restrict__ Wth, ushort* __restrict__ Wtl,
    ushort* __restrict__ Wvgt, ushort* __restrict__ Wngt,
    ushort* __restrict__ Wgoutt, ushort* __restrict__ Whdect,
    ushort* __restrict__ Wgdect,
    ushort* __restrict__ h2h, ushort* __restrict__ h2l,
    ushort* __restrict__ vt,
    ushort* __restrict__ g_src_b, ushort* __restrict__ gram_b)
{
  __shared__ __align__(16) float smem[1056];
  const int b = blockIdx.x;
  const int t = threadIdx.x;

  if (b < 512) {            // W_g1 [1024,512] -> Wg1t
    do_transpose(W_g1, Wg1t, nullptr, 1024, 512, b, 4, smem, 0);
  } else if (b < 640) {     // W_g2 [512,256]
    do_transpose(W_g2, Wg2t, nullptr, 512, 256, b-512, 3, smem, 0);
  } else if (b < 768) {     // W_q hi/lo
    do_transpose(W_q, Wth, Wtl, 512, 256, b-640, 3, smem, 1);
  } else if (b < 896) {     // W_k hi/lo
    do_transpose(W_k, Wth + 256*512, Wtl + 256*512, 512, 256, b-768, 3, smem, 1);
  } else if (b < 1024) {    // W_v hi/lo
    do_transpose(W_v, Wth + 512*512, Wtl + 512*512, 512, 256, b-896, 3, smem, 1);
  } else if (b < 1088) {    // W_vg
    do_transpose(W_vg, Wvgt, nullptr, 256, 256, b-1024, 3, smem, 0);
  } else if (b < 1152) {    // W_ng
    do_transpose(W_ng, Wngt, nullptr, 256, 256, b-1088, 3, smem, 0);
  } else if (b < 1216) {    // W_gout
    do_transpose(W_gout, Wgoutt, nullptr, 256, 256, b-1152, 3, smem, 0);
  } else if (b < 1280) {    // W_hdec
    do_transpose(W_hdec, Whdect, nullptr, 256, 256, b-1216, 3, smem, 0);
  } else if (b < 1288) {    // W_gdec [256,16]
    do_transpose(W_gdec, Wgdect, nullptr, 256, 16, b-1280, 0, smem, 0);
  } else if (b < 5384) {    // hsplit: h_src half of h2 (hi/lo)
    const int i = b - 1288;
    const float v = h[(size_t)i*256 + t] * SQRT_E;
    const ushort hi = f2bf(v);
    h2h[(size_t)i*512 + 256 + t] = hi;
    h2l[(size_t)i*512 + 256 + t] = f2bf(v - bf2f(hi));
  } else if (b < 7432) {    // vinit: ones-col + zero ext
    const int idx = (b - 5384)*256 + t;
    const int n = idx & 4095;
    const int c16 = (idx >> 12) & 15;
    const int hh = idx >> 16;
    vt[((size_t)hh*144 + 128 + c16)*N_ + n] = (c16 == 0) ? (ushort)0x3F80 : (ushort)0;
  } else {                  // k1: g_src_b + gram_b
    float* eq  = smem;        // 48
    float* gs  = smem + 48;   // 768
    float* g2p = smem + 816;  // 96
    const int i = b - 7432;
    if (t < 48) eq[t] = equ[(size_t)i*48 + t];
    __syncthreads();
    #pragma unroll
    for (int j = 0; j < 3; ++j) {
      float s = 0.f;
      #pragma unroll
      for (int m = 0; m < 16; ++m) s += eq[j*16+m] * W_equ[m*256 + t];
      s *= SQRT_E;
      gs[j*256 + t] = s;
      g_src_b[((size_t)i*3 + j)*256 + t] = f2bf(s);
    }
    __syncthreads();
    if (t < 96) {
      const int j = t >> 5, a = t & 31;
      float s = 0.f;
      for (int e = 0; e < 256; ++e) s += gs[j*256+e] * W_gproj[e*32 + a];
      g2p[t] = s;
    }
    __syncthreads();
    #pragma unroll
    for (int r = 0; r < 4; ++r) {
      const int idx = r*256 + t;
      const int a = idx >> 5, bb = idx & 31;
      const float s = g2p[a]*g2p[bb] + g2p[32+a]*g2p[32+bb] + g2p[64+a]*g2p[64+bb];
      gram_b[(size_t)i*1024 + idx] = f2bf(s);
    }
  }
}

// ---------------- shared GEMM cores ----------------
template<int KTOT>
__device__ __forceinline__ void gemm_core(
    const ushort* __restrict__ A, const ushort* __restrict__ Bt,
    int bM, int bN, floatx4 acc[4], ushort* As, ushort* Bs)
{
  const int t = threadIdx.x;
  const int wave = t >> 6, lane = t & 63, quad = lane >> 4, m = lane & 15;
  #pragma unroll
  for (int ct = 0; ct < 4; ++ct) acc[ct] = {0.f, 0.f, 0.f, 0.f};
  const int row = t >> 2, kq = (t & 3) * 8;
  for (int k0 = 0; k0 < KTOT; k0 += 32) {
    __syncthreads();
    *(short8*)&As[row*40 + kq] = *(const short8*)&A[(size_t)(bM+row)*KTOT + k0 + kq];
    *(short8*)&Bs[row*40 + kq] = *(const short8*)&Bt[(size_t)(bN+row)*KTOT + k0 + kq];
    __syncthreads();
    const short8 af = *(const short8*)&As[(wave*16 + m)*40 + quad*8];
    #pragma unroll
    for (int ct = 0; ct < 4; ++ct) {
      const short8 bf = *(const short8*)&Bs[(ct*16 + m)*40 + quad*8];
      acc[ct] = __builtin_amdgcn_mfma_f32_16x16x32_bf16(af, bf, acc[ct], 0, 0, 0);
    }
  }
}

template<int KTOT>
__device__ __forceinline__ void gemm_core3(
    const ushort* __restrict__ Ah, const ushort* __restrict__ Al,
    const ushort* __restrict__ Bth, const ushort* __restrict__ Btl,
    int bM, int bN, floatx4 acc[4],
    ushort* Ash, ushort* Asl, ushort* Bsh, ushort* Bsl)
{
  const int t = threadIdx.x;
  const int wave = t >> 6, lane = t & 63, quad = lane >> 4, m = lane & 15;
  #pragma unroll
  for (int ct = 0; ct < 4; ++ct) acc[ct] = {0.f, 0.f, 0.f, 0.f};
  const int row = t >> 2, kq = (t & 3) * 8;
  for (int k0 = 0; k0 < KTOT; k0 += 32) {
    __syncthreads();
    *(short8*)&Ash[row*40 + kq] = *(const short8*)&Ah[(size_t)(bM+row)*KTOT + k0 + kq];
    *(short8*)&Asl[row*40 + kq] = *(const short8*)&Al[(size_t)(bM+row)*KTOT + k0 + kq];
    *(short8*)&Bsh[row*40 + kq] = *(const short8*)&Bth[(size_t)(bN+row)*KTOT + k0 + kq];
    *(short8*)&Bsl[row*40 + kq] = *(const short8*)&Btl[(size_t)(bN+row)*KTOT + k0 + kq];
    __syncthreads();
    const short8 ah = *(const short8*)&Ash[(wave*16 + m)*40 + quad*8];
    const short8 al = *(const short8*)&Asl[(wave*16 + m)*40 + quad*8];
    #pragma unroll
    for (int ct = 0; ct < 4; ++ct) {
      const short8 bh = *(const short8*)&Bsh[(ct*16 + m)*40 + quad*8];
      const short8 bl = *(const short8*)&Bsl[(ct*16 + m)*40 + quad*8];
      acc[ct] = __builtin_amdgcn_mfma_f32_16x16x32_bf16(ah, bl, acc[ct], 0, 0, 0);
      acc[ct] = __builtin_amdgcn_mfma_f32_16x16x32_bf16(al, bh, acc[ct], 0, 0, 0);
      acc[ct] = __builtin_amdgcn_mfma_f32_16x16x32_bf16(ah, bh, acc[ct], 0, 0, 0);
    }
  }
}

// G1: hidden = relu(gram @ W_g1 + b_g1)
__global__ __launch_bounds__(256) void k_g1(
    const ushort* __restrict__ gram_b, const ushort* __restrict__ Wg1t,
    const float* __restrict__ b_g1, ushort* __restrict__ hidden)
{
  __shared__ __align__(16) ushort As[64*40], Bs[64*40];
  floatx4 acc[4];
  const int bM = blockIdx.x*64, bN = blockIdx.y*64;
  gemm_core<1024>(gram_b, Wg1t, bM, bN, acc, As, Bs);
  const int lane = threadIdx.x & 63, wave = threadIdx.x >> 6;
  const int quad = lane >> 4, m = lane & 15;
  #pragma unroll
  for (int ct = 0; ct < 4; ++ct) {
    const int c = bN + ct*16 + m;
    #pragma unroll
    for (int r = 0; r < 4; ++r) {
      const int i = bM + wave*16 + quad*4 + r;
      hidden[(size_t)i*512 + c] = f2bf(fmaxf(acc[ct][r] + b_g1[c], 0.f));
    }
  }
}

// G2: g2 = hidden @ W_g2 + b_g2 -> hi/lo into h2 cols 0..255
__global__ __launch_bounds__(256) void k_g2(
    const ushort* __restrict__ hidden, const ushort* __restrict__ Wg2t,
    const float* __restrict__ b_g2, ushort* __restrict__ h2h, ushort* __restrict__ h2l)
{
  __shared__ __align__(16) ushort As[64*40], Bs[64*40];
  floatx4 acc[4];
  const int bM = blockIdx.x*64, bN = blockIdx.y*64;
  gemm_core<512>(hidden, Wg2t, bM, bN, acc, As, Bs);
  const int lane = threadIdx.x & 63, wave = threadIdx.x >> 6;
  const int quad = lane >> 4, m = lane & 15;
  #pragma unroll
  for (int ct = 0; ct < 4; ++ct) {
    const int c = bN + ct*16 + m;
    #pragma unroll
    for (int r = 0; r < 4; ++r) {
      const int i = bM + wave*16 + quad*4 + r;
      const float s = acc[ct][r] + b_g2[c];
      const ushort hi = f2bf(s);
      h2h[(size_t)i*512 + c] = hi;
      h2l[(size_t)i*512 + c] = f2bf(s - bf2f(hi));
    }
  }
}

// G3+G4 fused: q/k hi/lo 3-term; v 1-term (bf16-rounded at output anyway); vg 1-term
__global__ __launch_bounds__(256) void k_g34(
    const ushort* __restrict__ h2h, const ushort* __restrict__ h2l,
    const ushort* __restrict__ Wth, const ushort* __restrict__ Wtl,
    const float* __restrict__ b_q, const float* __restrict__ b_k,
    const float* __restrict__ b_v,
    const ushort* __restrict__ g_src_b, const ushort* __restrict__ Wvgt,
    float* __restrict__ q_ws, ushort* __restrict__ kh, ushort* __restrict__ kl,
    ushort* __restrict__ vt)
{
  __shared__ __align__(16) ushort S0[64*40], S1[64*40], S2[64*40], S3[64*40];
  const int lb = blockIdx.y*192 + blockIdx.x;     // grid (192,8) = 1536
  const int lane = threadIdx.x & 63, wave = threadIdx.x >> 6;
  const int quad = lane >> 4, m = lane & 15;
  floatx4 acc[4];
  if (lb < 768) {
    const int bM = (lb & 63)*64, bN = (lb >> 6)*64;
    if (bN < 512) {
      // ---- q/k: 3-term hi/lo ----
      gemm_core3<512>(h2h, h2l, Wth, Wtl, bM, bN, acc, S0, S1, S2, S3);
      #pragma unroll
      for (int ct = 0; ct < 4; ++ct) {
        const int c = bN + ct*16 + m;
        #pragma unroll
        for (int r = 0; r < 4; ++r) {
          const int i = bM + wave*16 + quad*4 + r;
          if (c < 256) {
            const float s = acc[ct][r] + b_q[c];
            q_ws[((size_t)(c >> 5)*N_ + i)*32 + (c & 31)] = s * QSCALE;
          } else {
            const int cc = c - 256;
            const float s = acc[ct][r] + b_k[cc];
            const ushort hi = f2bf(s);
            kh[((size_t)(cc >> 5)*N_ + i)*32 + (cc & 31)] = hi;
            kl[((size_t)(cc >> 5)*N_ + i)*32 + (cc & 31)] = f2bf(s - bf2f(hi));
          }
        }
      }
    } else {
      // ---- v: 1-term bf16 (output is bf16 anyway) ----
      gemm_core<512>(h2h, Wth, bM, bN, acc, S0, S1);
      #pragma unroll
      for (int ct = 0; ct < 4; ++ct) {
        const int cc = bN + ct*16 + m - 512;
        #pragma unroll
        for (int r = 0; r < 4; ++r) {
          const int i = bM + wave*16 + quad*4 + r;
          const float s = acc[ct][r] + b_v[cc];
          vt[((size_t)(cc >> 5)*144 + (cc & 31))*N_ + i] = f2bf(s);
        }
      }
    }
  } else {
    // ---- G4: vg ----
    const int lb2 = lb - 768;
    const int bM = (lb2 >> 2)*64, bN = (lb2 & 3)*64;
    gemm_core<256>(g_src_b, Wvgt, bM, bN, acc, S0, S1);
    #pragma unroll
    for (int ct = 0; ct < 4; ++ct) {
      const int c = bN + ct*16 + m;
      const int hh = c >> 5, d = c & 31;
      #pragma unroll
      for (int r = 0; r < 4; ++r) {
        const int i3 = bM + wave*16 + quad*4 + r;
        const int i = i3 / 3, j = i3 - 3*i;
        vt[((size_t)hh*144 + 32 + j*32 + d)*N_ + i] = f2bf(acc[ct][r]);
      }
    }
  }
}

// ---------------- K3: MFMA flash attention v6 -----------------------------------
// Split-K x3 (tiles 22/21/21), register-prefetch, ones-col denominator,
// deferred rescale, DPP max, truncated-bf16 P.
__global__ __launch_bounds__(256, 4) void k3_attn(
    const float* __restrict__ q_ws, const ushort* __restrict__ kh,
    const ushort* __restrict__ kl, const ushort* __restrict__ vt,
    ushort* __restrict__ Po0, ushort* __restrict__ Po1, ushort* __restrict__ Po2,
    float* __restrict__ Pml)
{
  __shared__ __align__(16) ushort Khs[64*40], Kls[64*40];  // 5 KiB each
  __shared__ __align__(16) ushort Vs[144*64];              // 18 KiB swizzled
  __shared__ __align__(16) ushort Pl[4*16*72];             // 9 KiB
  __shared__ float li_s[64];

  const int t    = threadIdx.x;
  const int wave = t >> 6;
  const int lane = t & 63;
  const int quad = lane >> 4;
  const int m    = lane & 15;
  const int h    = blockIdx.y;
  const int s    = blockIdx.z;
  const int n0q  = blockIdx.x * 64;

  const int ktb = (s == 0) ? 0  : (s == 1 ? 22 : 43);
  const int kte = (s == 0) ? 22 : (s == 1 ? 43 : 64);

  // Q fragments: direct global load + hi/lo split in registers
  union { short8 v; ushort u[8]; } Aqh, Aql;
  {
    const float* qp = q_ws + ((size_t)h*N_ + n0q + wave*16 + m)*32 + quad*8;
    #pragma unroll
    for (int jj = 0; jj < 8; ++jj) {
      const float x = qp[jj];
      const ushort hi = f2bf(x);
      Aqh.u[jj] = hi;
      Aql.u[jj] = f2bf(x - bf2f(hi));
    }
  }

  floatx4 Of[9];                     // nt 0..7 = values, nt 8 = denominator col
  #pragma unroll
  for (int nt = 0; nt < 9; ++nt) Of[nt] = {0.f, 0.f, 0.f, 0.f};
  float mi[4];
  #pragma unroll
  for (int r = 0; r < 4; ++r) mi[r] = -3.0e38f;

  const int krow = t >> 2, kch = (t & 3) * 8;

  // pointer-bumped staging addresses
  const ushort* pKh = kh + ((size_t)h*N_ + ktb*64 + krow)*32 + kch;
  const ushort* pKl = kl + ((size_t)h*N_ + ktb*64 + krow)*32 + kch;
  const ushort* pV[4];
  int wV[4];
  #pragma unroll
  for (int p = 0; p < 4; ++p) {
    const int idx = p*256 + t, row = idx >> 3, g = idx & 7;
    pV[p] = vt + ((size_t)h*144 + row)*N_ + ktb*64 + g*8;
    wV[p] = (row*8 + (g ^ (row & 7)))*8;
  }
  const ushort* pV4 = nullptr;
  int wV4 = 0;
  if (t < 128) {
    const int idx = 1024 + t, row = idx >> 3, g = idx & 7;
    pV4 = vt + ((size_t)h*144 + row)*N_ + ktb*64 + g*8;
    wV4 = (row*8 + (g ^ (row & 7)))*8;
  }

  // fetch first tile
  short8 rK0 = *(const short8*)pKh;
  short8 rK1 = *(const short8*)pKl;
  short8 rV[4], rV4e;
  #pragma unroll
  for (int p = 0; p < 4; ++p) rV[p] = *(const short8*)pV[p];
  if (t < 128) rV4e = *(const short8*)pV4;

  for (int kt = ktb; kt < kte; ++kt) {
    __syncthreads();   // prior tile's LDS reads complete
    *(short8*)&Khs[krow*40 + kch] = rK0;
    *(short8*)&Kls[krow*40 + kch] = rK1;
    #pragma unroll
    for (int p = 0; p < 4; ++p) *(short8*)&Vs[wV[p]] = rV[p];
    if (t < 128) *(short8*)&Vs[wV4] = rV4e;
    if (kt + 1 < kte) {
      pKh += 2048; pKl += 2048;
      rK0 = *(const short8*)pKh;
      rK1 = *(const short8*)pKl;
      #pragma unroll
      for (int p = 0; p < 4; ++p) { pV[p] += 64; rV[p] = *(const short8*)pV[p]; }
      if (t < 128) { pV4 += 64; rV4e = *(const short8*)pV4; }
    }
    __syncthreads();   // LDS writes visible

    // S = Q K^T (3-term hi/lo MFMA), exp2-domain logits
    floatx4 sf[4];
    #pragma unroll
    for (int kb = 0; kb < 4; ++kb) {
      const short8 bkh = *(const short8*)&Khs[(kb*16 + m)*40 + quad*8];
      const short8 bkl = *(const short8*)&Kls[(kb*16 + m)*40 + quad*8];
      floatx4 sv = {0.f, 0.f, 0.f, 0.f};
      sv = __builtin_amdgcn_mfma_f32_16x16x32_bf16(Aqh.v, bkl, sv, 0, 0, 0);
      sv = __builtin_amdgcn_mfma_f32_16x16x32_bf16(Aql.v, bkh, sv, 0, 0, 0);
      sv = __builtin_amdgcn_mfma_f32_16x16x32_bf16(Aqh.v, bkh, sv, 0, 0, 0);
      sf[kb] = sv;
    }

    // deferred rescale: only rescale O when tile max exceeds applied max by >20
    float tm[4];
    bool need = false;
    #pragma unroll
    for (int r = 0; r < 4; ++r) {
      float nm = fmaxf(fmaxf(sf[0][r], sf[1][r]), fmaxf(sf[2][r], sf[3][r]));
      tm[r] = dpp_max16(nm);
      need |= (tm[r] > mi[r] + 20.f);
    }
    if (__any(need)) {
      #pragma unroll
      for (int r = 0; r < 4; ++r) {
        const float mn = fmaxf(mi[r], tm[r]);
        const float al = exp2f(mi[r] - mn);
        mi[r] = mn;
        #pragma unroll
        for (int nt = 0; nt < 9; ++nt) Of[nt][r] *= al;
      }
    }
    // P = exp2(S - mi_applied), truncated to bf16 (may exceed 1, bounded by 2^20)
    #pragma unroll
    for (int kb = 0; kb < 4; ++kb)
      #pragma unroll
      for (int r = 0; r < 4; ++r) {
        const float pv = exp2f(sf[kb][r] - mi[r]);
        Pl[wave*1152 + (quad*4 + r)*72 + kb*16 + m] =
            (ushort)(__float_as_uint(pv) >> 16);
      }

    // O += P @ V (9 n-tiles; nt 8 accumulates the denominator)
    #pragma unroll
    for (int ks = 0; ks < 2; ++ks) {
      const short8 ap = *(const short8*)&Pl[wave*1152 + m*72 + ks*32 + quad*8];
      #pragma unroll
      for (int nt = 0; nt < 9; ++nt) {
        const int row = nt*16 + m;
        const int pos = (ks*4 + quad) ^ (row & 7);
        const short8 bv = *(const short8*)&Vs[(row*8 + pos)*8];
        Of[nt] = __builtin_amdgcn_mfma_f32_16x16x32_bf16(ap, bv, Of[nt], 0, 0, 0);
      }
    }
  }

  // denominator lives at col 128 -> lanes m==0 of n-tile 8
  if (m == 0) {
    #pragma unroll
    for (int r = 0; r < 4; ++r) li_s[wave*16 + quad*4 + r] = Of[8][r];
  }
  __syncthreads();
  const floatx4 liv = *(const floatx4*)&li_s[wave*16 + quad*4];
  float linv[4];
  #pragma unroll
  for (int r = 0; r < 4; ++r) linv[r] = 1.0f / liv[r];

  ushort* Po = (s == 0) ? Po0 : ((s == 1) ? Po1 : Po2);
  #pragma unroll
  for (int nt = 0; nt < 8; ++nt) {
    #pragma unroll
    for (int r = 0; r < 4; ++r) {
      const int n = n0q + wave*16 + quad*4 + r;
      Po[((size_t)h*N_ + n)*128 + nt*16 + m] = f2bf(Of[nt][r] * linv[r]);
    }
  }
  if (m == 0) {
    #pragma unroll
    for (int r = 0; r < 4; ++r) {
      const int n = n0q + wave*16 + quad*4 + r;
      Pml[(((size_t)s*8 + h)*N_ + n)*2 + 0] = mi[r];
      Pml[(((size_t)s*8 + h)*N_ + n)*2 + 1] = Of[8][r];
    }
  }
}

// ---------------- merge: combine 3 split-K partials (8 elems/thread) ------------
__global__ __launch_bounds__(256) void k_merge(
    const ushort* __restrict__ Po0, const ushort* __restrict__ Po1,
    const ushort* __restrict__ Po2, const float* __restrict__ Pml,
    ushort* __restrict__ out_v_b, ushort* __restrict__ out_g_b)
{
  const int idx = blockIdx.x*256 + threadIdx.x;   // 524288 = 8 h * 4096 n * 16 chunks
  const int c0 = (idx & 15) * 8;
  const int n  = (idx >> 4) & 4095;
  const int h  = idx >> 16;
  const float m1 = Pml[(((size_t)0*8 + h)*N_ + n)*2 + 0];
  const float l1 = Pml[(((size_t)0*8 + h)*N_ + n)*2 + 1];
  const float m2 = Pml[(((size_t)1*8 + h)*N_ + n)*2 + 0];
  const float l2 = Pml[(((size_t)1*8 + h)*N_ + n)*2 + 1];
  const float m3 = Pml[(((size_t)2*8 + h)*N_ + n)*2 + 0];
  const float l3 = Pml[(((size_t)2*8 + h)*N_ + n)*2 + 1];
  const float M = fmaxf(fmaxf(m1, m2), m3);
  const float w1 = exp2f(m1 - M) * l1;
  const float w2 = exp2f(m2 - M) * l2;
  const float w3 = exp2f(m3 - M) * l3;
  const float inv = 1.0f / (w1 + w2 + w3);
  union { short8 v; ushort u[8]; } a, b, c, res;
  a.v = *(const short8*)&Po0[((size_t)h*N_ + n)*128 + c0];
  b.v = *(const short8*)&Po1[((size_t)h*N_ + n)*128 + c0];
  c.v = *(const short8*)&Po2[((size_t)h*N_ + n)*128 + c0];
  #pragma unroll
  for (int j = 0; j < 8; ++j)
    res.u[j] = f2bf((w1*bf2f(a.u[j]) + w2*bf2f(b.u[j]) + w3*bf2f(c.u[j])) * inv);
  if (c0 < 32) {
    *(short8*)&out_v_b[(size_t)n*256 + h*32 + c0] = res.v;
  } else {
    const int j = (c0 - 32) >> 5, cc = (c0 - 32) & 31;
    *(short8*)&out_g_b[((size_t)n*3 + j)*256 + h*32 + cc] = res.v;
  }
}

// ---------------- k5a+k5b fused ----------------
__global__ __launch_bounds__(256) void k56ab(
    const ushort* __restrict__ out_v_b, const ushort* __restrict__ Wngt,
    const float* __restrict__ b_ng, const float* __restrict__ h,
    ushort* __restrict__ tmp_b,
    const ushort* __restrict__ out_g_b, const ushort* __restrict__ Wgoutt,
    const ushort* __restrict__ g_src_b, ushort* __restrict__ gsum_b)
{
  __shared__ __align__(16) ushort As[64*40], Bs[64*40];
  floatx4 acc[4];
  const int lane = threadIdx.x & 63, wave = threadIdx.x >> 6;
  const int quad = lane >> 4, m = lane & 15;
  const int bN = blockIdx.y*64;
  if (blockIdx.x < 64) {
    const int bM = blockIdx.x*64;
    gemm_core<256>(out_v_b, Wngt, bM, bN, acc, As, Bs);
    #pragma unroll
    for (int ct = 0; ct < 4; ++ct) {
      const int c = bN + ct*16 + m;
      #pragma unroll
      for (int r = 0; r < 4; ++r) {
        const int i = bM + wave*16 + quad*4 + r;
        tmp_b[(size_t)i*256 + c] =
            f2bf(acc[ct][r] + b_ng[c] + h[(size_t)i*256 + c] * SQRT_E);
      }
    }
  } else {
    const int bM = (blockIdx.x - 64)*64;
    gemm_core<256>(out_g_b, Wgoutt, bM, bN, acc, As, Bs);
    #pragma unroll
    for (int ct = 0; ct < 4; ++ct) {
      const int c = bN + ct*16 + m;
      #pragma unroll
      for (int r = 0; r < 4; ++r) {
        const int i = bM + wave*16 + quad*4 + r;
        gsum_b[(size_t)i*256 + c] =
            f2bf(acc[ct][r] + bf2f(g_src_b[(size_t)i*256 + c]));
      }
    }
  }
}

// ---------------- k5c+k5d fused ----------------
__global__ __launch_bounds__(256) void k56cd(
    const ushort* __restrict__ tmp_b, const ushort* __restrict__ Whdect,
    const float* __restrict__ b_hdec,
    const ushort* __restrict__ gsum_b, const ushort* __restrict__ Wgdect,
    float* __restrict__ out)
{
  __shared__ __align__(16) ushort As[64*40], Bs[64*40];
  const int t = threadIdx.x;
  const int lane = t & 63, wave = t >> 6;
  const int quad = lane >> 4, m = lane & 15;
  if (blockIdx.x < 64) {
    floatx4 acc[4];
    const int bM = blockIdx.x*64, bN = blockIdx.y*64;
    gemm_core<256>(tmp_b, Whdect, bM, bN, acc, As, Bs);
    #pragma unroll
    for (int ct = 0; ct < 4; ++ct) {
      const int c = bN + ct*16 + m;
      #pragma unroll
      for (int r = 0; r < 4; ++r) {
        const int i = bM + wave*16 + quad*4 + r;
        out[196608 + (size_t)i*256 + c] = acc[ct][r] + b_hdec[c];
      }
    }
  } else if (blockIdx.y == 0) {
    const int bM = (blockIdx.x - 64)*64;
    floatx4 acc = {0.f, 0.f, 0.f, 0.f};
    const int row = t >> 2, kq = (t & 3) * 8;
    for (int k0 = 0; k0 < 256; k0 += 32) {
      __syncthreads();
      *(short8*)&As[row*40 + kq] = *(const short8*)&gsum_b[(size_t)(bM+row)*256 + k0 + kq];
      if (t < 64)
        *(short8*)&Bs[(t>>2)*40 + kq] = *(const short8*)&Wgdect[(size_t)(t>>2)*256 + k0 + kq];
      __syncthreads();
      const short8 af = *(const short8*)&As[(wave*16 + m)*40 + quad*8];
      const short8 bf = *(const short8*)&Bs[m*40 + quad*8];
      acc = __builtin_amdgcn_mfma_f32_16x16x32_bf16(af, bf, acc, 0, 0, 0);
    }
    #pragma unroll
    for (int r = 0; r < 4; ++r)
      out[(size_t)(bM + wave*16 + quad*4 + r)*16 + m] = acc[r];
  }
}

extern "C" void kernel_launch(void* const* d_in, const int* in_sizes, int n_in,
                              void* d_out, int out_size, void* d_ws, size_t ws_size,
                              hipStream_t stream) {
  const float* equ    = (const float*)d_in[0];
  const float* h      = (const float*)d_in[1];
  const float* W_equ  = (const float*)d_in[4];
  const float* W_gproj= (const float*)d_in[5];
  const float* W_vg   = (const float*)d_in[6];
  const float* W_g1   = (const float*)d_in[7];
  const float* b_g1   = (const float*)d_in[8];
  const float* W_g2   = (const float*)d_in[9];
  const float* b_g2   = (const float*)d_in[10];
  const float* W_q    = (const float*)d_in[11];
  const float* b_q    = (const float*)d_in[12];
  const float* W_k    = (const float*)d_in[13];
  const float* b_k    = (const float*)d_in[14];
  const float* W_v    = (const float*)d_in[15];
  const float* b_v    = (const float*)d_in[16];
  const float* W_ng   = (const float*)d_in[17];
  const float* b_ng   = (const float*)d_in[18];
  const float* W_gout = (const float*)d_in[19];
  const float* W_gdec = (const float*)d_in[20];
  const float* W_hdec = (const float*)d_in[21];
  const float* b_hdec = (const float*)d_in[22];
  float* out = (float*)d_out;

  // ---- workspace layout (lifetimes annotated), peak 51.25 MiB (52 proven) ----
  char* wsb = (char*)d_ws;
  constexpr size_t MiB = 1048576;
  float*  q_ws    = (float*) (wsb +  0*MiB);            // 4 MiB [g34 -> k3]
  ushort* kh      = (ushort*)(wsb +  4*MiB);            // 2 MiB [g34 -> k3]
  ushort* kl      = (ushort*)(wsb +  6*MiB);            // 2 MiB [g34 -> k3]
  ushort* vt      = (ushort*)(wsb +  8*MiB);            // 9 MiB [prep/g34 -> k3]
  ushort* h2h     = (ushort*)(wsb + 17*MiB);            // 4 MiB [prep/g2 -> g34]
  ushort* h2l     = (ushort*)(wsb + 21*MiB);            // 4 MiB
  ushort* g_src_b = (ushort*)(wsb + 25*MiB);            // 6 MiB [prep -> g34,k56ab]
  ushort* wbase   = (ushort*)(wsb + 31*MiB);            // 2.875 MiB [prep -> g34]
  ushort* Wg1t = wbase;                                 // 512x1024
  ushort* Wg2t = wbase + 524288;                        // 256x512
  ushort* Wth  = wbase + 655360;                        // 768x512 hi
  ushort* Wtl  = wbase + 1048576;                       // 768x512 lo
  ushort* Wvgt = wbase + 1441792;                       // 256x256
  ushort* wbase2  = (ushort*)(wsb + 34*MiB);            // 0.4 MiB [prep -> k56*]
  ushort* Wngt   = wbase2;                              // 256x256
  ushort* Wgoutt = wbase2 + 65536;                      // 256x256
  ushort* Whdect = wbase2 + 131072;                     // 256x256
  ushort* Wgdect = wbase2 + 196608;                     // 16x256
  ushort* gram_b  = (ushort*)(wsb + 34*MiB + 524288);   // 8 MiB [prep -> g1]
  ushort* hidden  = (ushort*)(wsb + 42*MiB + 524288);   // 4 MiB [g1 -> g2]
  // split-K x3 attention partials (all alias dead regions):
  ushort* Po0     = (ushort*)(wsb + 17*MiB);            // 8 MiB [k3 -> merge] alias h2h/h2l
  ushort* Po1     = (ushort*)(wsb + 34*MiB + 524288);   // 8 MiB [k3 -> merge] alias gram_b
  ushort* Po2     = (ushort*)(wsb + 42*MiB + 524288);   // 8 MiB [k3 -> merge] alias hidden+
  float*  Pml     = (float*) (wsb + 50*MiB + 524288);   // 0.75 MiB [k3 -> merge]
  ushort* out_v_b = (ushort*)(wsb +  4*MiB);            // 2 MiB [merge -> k56ab] alias kh/kl
  ushort* out_g_b = (ushort*)(wsb +  8*MiB);            // 6 MiB [merge -> k56ab] alias vt
  ushort* tmp_b   = (ushort*)(wsb + 42*MiB + 524288);   // 2 MiB [k56ab -> k56cd] alias Po2
  ushort* gsum_b  = (ushort*)(wsb + 34*MiB + 524288);   // 6 MiB [k56ab -> k56cd] alias Po1

  // ---- 1 mega-prep launch (10 transposes + hsplit + vinit + k1) ----
  k_prep<<<11528, 256, 0, stream>>>(
      equ, h, W_equ, W_gproj, W_g1, W_g2, W_q, W_k, W_v,
      W_vg, W_ng, W_gout, W_hdec, W_gdec,
      Wg1t, Wg2t, Wth, Wtl, Wvgt, Wngt, Wgoutt, Whdect, Wgdect,
      h2h, h2l, vt, g_src_b, gram_b);

  // ---- GEMM chain ----
  k_g1<<<dim3(64, 8), 256, 0, stream>>>(gram_b, Wg1t, b_g1, hidden);
  k_g2<<<dim3(64, 4), 256, 0, stream>>>(hidden, Wg2t, b_g2, h2h, h2l);
  k_g34<<<dim3(192, 8), 256, 0, stream>>>(h2h, h2l, Wth, Wtl, b_q, b_k, b_v,
                                          g_src_b, Wvgt, q_ws, kh, kl, vt);

  // ---- attention (split-K x3) + merge ----
  dim3 g3(64, 8, 3);
  k3_attn<<<g3, 256, 0, stream>>>(q_ws, kh, kl, vt, Po0, Po1, Po2, Pml);
  k_merge<<<2048, 256, 0, stream>>>(Po0, Po1, Po2, Pml, out_v_b, out_g_b);

  // ---- epilogue GEMMs (fused pairs) ----
  k56ab<<<dim3(256, 4), 256, 0, stream>>>(out_v_b, Wngt, b_ng, h, tmp_b,
                                          out_g_b, Wgoutt, g_src_b, gsum_b);
  k56cd<<<dim3(256, 4), 256, 0, stream>>>(tmp_b, Whdect, b_hdec,
                                          gsum_b, Wgdect, out);
}

// Round 10
// 299.703 us; speedup vs baseline: 6.5056x; 1.0391x over previous
//
#include <hip/hip_runtime.h>
#include <hip/hip_bf16.h>

typedef __attribute__((ext_vector_type(8))) short short8;
typedef __attribute__((ext_vector_type(4))) float floatx4;

constexpr int N_ = 4096;
constexpr float SQRT_E = 16.0f;
// q scale folded with log2(e): softmax computed in exp2 domain
constexpr float QSCALE = 0.17677669529663687f * 1.4426950408889634f;

__device__ __forceinline__ ushort f2bf(float x) {
  __hip_bfloat16 h = __float2bfloat16(x);
  return *reinterpret_cast<ushort*>(&h);
}
__device__ __forceinline__ float bf2f(ushort b) {
  unsigned int u = ((unsigned int)b) << 16;
  return __uint_as_float(u);
}

// all 16 lanes of each aligned 16-lane group get the group max (VALU DPP, not LDS)
__device__ __forceinline__ float dpp_max16(float x) {
  int v = __float_as_int(x);
  int y;
  y = __builtin_amdgcn_update_dpp(v, v, 0x128, 0xf, 0xf, false); // row_ror:8
  v = __float_as_int(fmaxf(__int_as_float(v), __int_as_float(y)));
  y = __builtin_amdgcn_update_dpp(v, v, 0x124, 0xf, 0xf, false); // row_ror:4
  v = __float_as_int(fmaxf(__int_as_float(v), __int_as_float(y)));
  y = __builtin_amdgcn_update_dpp(v, v, 0x122, 0xf, 0xf, false); // row_ror:2
  v = __float_as_int(fmaxf(__int_as_float(v), __int_as_float(y)));
  y = __builtin_amdgcn_update_dpp(v, v, 0x121, 0xf, 0xf, false); // row_ror:1
  v = __float_as_int(fmaxf(__int_as_float(v), __int_as_float(y)));
  return __int_as_float(v);
}

// ---------------- transpose helper (device side of mega-prep) ----------------
__device__ __forceinline__ void do_transpose(
    const float* __restrict__ src, ushort* __restrict__ dsth,
    ushort* __restrict__ dstl, int R, int C, int lb, int cb_shift,
    float* smem, int hasLo)
{
  float (*tile)[33] = (float(*)[33])smem;
  const int r0 = (lb >> cb_shift) * 32;
  const int c0 = (lb & ((1 << cb_shift) - 1)) * 32;
  const int tx = threadIdx.x & 31, ty = threadIdx.x >> 5;
  #pragma unroll
  for (int p = 0; p < 4; ++p) {
    const int lr = p*8 + ty;
    tile[lr][tx] = (r0+lr < R && c0+tx < C) ? src[(size_t)(r0+lr)*C + c0 + tx] : 0.f;
  }
  __syncthreads();
  #pragma unroll
  for (int p = 0; p < 4; ++p) {
    const int dc = p*8 + ty;
    if (c0+dc < C && r0+tx < R) {
      const float v = tile[tx][dc];
      const ushort hi = f2bf(v);
      dsth[(size_t)(c0+dc)*R + r0 + tx] = hi;
      if (hasLo) dstl[(size_t)(c0+dc)*R + r0 + tx] = f2bf(v - bf2f(hi));
    }
  }
}

// ---------------- mega-prep: all transposes + hsplit + vinit + k1 in ONE launch --
__global__ __launch_bounds__(256) void k_prep(
    const float* __restrict__ equ, const float* __restrict__ h,
    const float* __restrict__ W_equ, const float* __restrict__ W_gproj,
    const float* __restrict__ W_g1, const float* __restrict__ W_g2,
    const float* __restrict__ W_q, const float* __restrict__ W_k,
    const float* __restrict__ W_v, const float* __restrict__ W_vg,
    const float* __restrict__ W_ng, const float* __restrict__ W_gout,
    const float* __restrict__ W_hdec, const float* __restrict__ W_gdec,
    ushort* __restrict__ Wg1t, ushort* __restrict__ Wg2t,
    ushort* __restrict__ Wth, ushort* __restrict__ Wtl,
    ushort* __restrict__ Wvgt, ushort* __restrict__ Wngt,
    ushort* __restrict__ Wgoutt, ushort* __restrict__ Whdect,
    ushort* __restrict__ Wgdect,
    ushort* __restrict__ h2h, ushort* __restrict__ h2l,
    ushort* __restrict__ vt,
    ushort* __restrict__ g_src_b, ushort* __restrict__ gram_b)
{
  __shared__ __align__(16) float smem[1056];
  const int b = blockIdx.x;
  const int t = threadIdx.x;

  if (b < 512) {            // W_g1 [1024,512] -> Wg1t
    do_transpose(W_g1, Wg1t, nullptr, 1024, 512, b, 4, smem, 0);
  } else if (b < 640) {     // W_g2 [512,256]
    do_transpose(W_g2, Wg2t, nullptr, 512, 256, b-512, 3, smem, 0);
  } else if (b < 768) {     // W_q hi/lo
    do_transpose(W_q, Wth, Wtl, 512, 256, b-640, 3, smem, 1);
  } else if (b < 896) {     // W_k hi/lo
    do_transpose(W_k, Wth + 256*512, Wtl + 256*512, 512, 256, b-768, 3, smem, 1);
  } else if (b < 1024) {    // W_v hi/lo
    do_transpose(W_v, Wth + 512*512, Wtl + 512*512, 512, 256, b-896, 3, smem, 1);
  } else if (b < 1088) {    // W_vg
    do_transpose(W_vg, Wvgt, nullptr, 256, 256, b-1024, 3, smem, 0);
  } else if (b < 1152) {    // W_ng
    do_transpose(W_ng, Wngt, nullptr, 256, 256, b-1088, 3, smem, 0);
  } else if (b < 1216) {    // W_gout
    do_transpose(W_gout, Wgoutt, nullptr, 256, 256, b-1152, 3, smem, 0);
  } else if (b < 1280) {    // W_hdec
    do_transpose(W_hdec, Whdect, nullptr, 256, 256, b-1216, 3, smem, 0);
  } else if (b < 1288) {    // W_gdec [256,16]
    do_transpose(W_gdec, Wgdect, nullptr, 256, 16, b-1280, 0, smem, 0);
  } else if (b < 5384) {    // hsplit: h_src half of h2 (hi/lo)
    const int i = b - 1288;
    const float v = h[(size_t)i*256 + t] * SQRT_E;
    const ushort hi = f2bf(v);
    h2h[(size_t)i*512 + 256 + t] = hi;
    h2l[(size_t)i*512 + 256 + t] = f2bf(v - bf2f(hi));
  } else if (b < 7432) {    // vinit: ones-col + zero ext
    const int idx = (b - 5384)*256 + t;
    const int n = idx & 4095;
    const int c16 = (idx >> 12) & 15;
    const int hh = idx >> 16;
    vt[((size_t)hh*144 + 128 + c16)*N_ + n] = (c16 == 0) ? (ushort)0x3F80 : (ushort)0;
  } else {                  // k1: g_src_b + gram_b
    float* eq  = smem;        // 48
    float* gs  = smem + 48;   // 768
    float* g2p = smem + 816;  // 96
    const int i = b - 7432;
    if (t < 48) eq[t] = equ[(size_t)i*48 + t];
    __syncthreads();
    #pragma unroll
    for (int j = 0; j < 3; ++j) {
      float s = 0.f;
      #pragma unroll
      for (int m = 0; m < 16; ++m) s += eq[j*16+m] * W_equ[m*256 + t];
      s *= SQRT_E;
      gs[j*256 + t] = s;
      g_src_b[((size_t)i*3 + j)*256 + t] = f2bf(s);
    }
    __syncthreads();
    if (t < 96) {
      const int j = t >> 5, a = t & 31;
      float s = 0.f;
      for (int e = 0; e < 256; ++e) s += gs[j*256+e] * W_gproj[e*32 + a];
      g2p[t] = s;
    }
    __syncthreads();
    #pragma unroll
    for (int r = 0; r < 4; ++r) {
      const int idx = r*256 + t;
      const int a = idx >> 5, bb = idx & 31;
      const float s = g2p[a]*g2p[bb] + g2p[32+a]*g2p[32+bb] + g2p[64+a]*g2p[64+bb];
      gram_b[(size_t)i*1024 + idx] = f2bf(s);
    }
  }
}

// ---------------- GEMM cores v2: BK=64, double-pumped, register prefetch --------
// C[64x64] = A[64xK] * Bt[64xK]^T.  As/Bs: 64 rows x stride 72 shorts (16B-align).
template<int KTOT>
__device__ __forceinline__ void gemm_core(
    const ushort* __restrict__ A, const ushort* __restrict__ Bt,
    int bM, int bN, floatx4 acc[4], ushort* As, ushort* Bs)
{
  const int t = threadIdx.x;
  const int wave = t >> 6, lane = t & 63, quad = lane >> 4, m = lane & 15;
  #pragma unroll
  for (int ct = 0; ct < 4; ++ct) acc[ct] = {0.f, 0.f, 0.f, 0.f};
  // 2 chunks (8 shorts each) per thread per matrix: chunk c -> row c>>3, pos c&7
  const int ca = t*2, cb = t*2 + 1;
  const int ra = ca >> 3, pa = ca & 7;
  const int rb = cb >> 3, pb = cb & 7;
  const ushort* pA0 = A  + (size_t)(bM+ra)*KTOT + pa*8;
  const ushort* pA1 = A  + (size_t)(bM+rb)*KTOT + pb*8;
  const ushort* pB0 = Bt + (size_t)(bN+ra)*KTOT + pa*8;
  const ushort* pB1 = Bt + (size_t)(bN+rb)*KTOT + pb*8;
  short8 rA0 = *(const short8*)pA0, rA1 = *(const short8*)pA1;
  short8 rB0 = *(const short8*)pB0, rB1 = *(const short8*)pB1;
  for (int k0 = 0; k0 < KTOT; k0 += 64) {
    __syncthreads();
    *(short8*)&As[ra*72 + pa*8] = rA0;
    *(short8*)&As[rb*72 + pb*8] = rA1;
    *(short8*)&Bs[ra*72 + pa*8] = rB0;
    *(short8*)&Bs[rb*72 + pb*8] = rB1;
    if (k0 + 64 < KTOT) {
      pA0 += 64; pA1 += 64; pB0 += 64; pB1 += 64;
      rA0 = *(const short8*)pA0; rA1 = *(const short8*)pA1;
      rB0 = *(const short8*)pB0; rB1 = *(const short8*)pB1;
    }
    __syncthreads();
    #pragma unroll
    for (int ks = 0; ks < 2; ++ks) {
      const short8 af = *(const short8*)&As[(wave*16 + m)*72 + ks*32 + quad*8];
      #pragma unroll
      for (int ct = 0; ct < 4; ++ct) {
        const short8 bf = *(const short8*)&Bs[(ct*16 + m)*72 + ks*32 + quad*8];
        acc[ct] = __builtin_amdgcn_mfma_f32_16x16x32_bf16(af, bf, acc[ct], 0, 0, 0);
      }
    }
  }
}

// 3-term hi/lo core (q/k precision), same BK=64 structure
template<int KTOT>
__device__ __forceinline__ void gemm_core3(
    const ushort* __restrict__ Ah, const ushort* __restrict__ Al,
    const ushort* __restrict__ Bth, const ushort* __restrict__ Btl,
    int bM, int bN, floatx4 acc[4],
    ushort* Ash, ushort* Asl, ushort* Bsh, ushort* Bsl)
{
  const int t = threadIdx.x;
  const int wave = t >> 6, lane = t & 63, quad = lane >> 4, m = lane & 15;
  #pragma unroll
  for (int ct = 0; ct < 4; ++ct) acc[ct] = {0.f, 0.f, 0.f, 0.f};
  const int ca = t*2, cb = t*2 + 1;
  const int ra = ca >> 3, pa = ca & 7;
  const int rb = cb >> 3, pb = cb & 7;
  const ushort* pAh0 = Ah  + (size_t)(bM+ra)*KTOT + pa*8;
  const ushort* pAh1 = Ah  + (size_t)(bM+rb)*KTOT + pb*8;
  const ushort* pAl0 = Al  + (size_t)(bM+ra)*KTOT + pa*8;
  const ushort* pAl1 = Al  + (size_t)(bM+rb)*KTOT + pb*8;
  const ushort* pBh0 = Bth + (size_t)(bN+ra)*KTOT + pa*8;
  const ushort* pBh1 = Bth + (size_t)(bN+rb)*KTOT + pb*8;
  const ushort* pBl0 = Btl + (size_t)(bN+ra)*KTOT + pa*8;
  const ushort* pBl1 = Btl + (size_t)(bN+rb)*KTOT + pb*8;
  short8 rAh0 = *(const short8*)pAh0, rAh1 = *(const short8*)pAh1;
  short8 rAl0 = *(const short8*)pAl0, rAl1 = *(const short8*)pAl1;
  short8 rBh0 = *(const short8*)pBh0, rBh1 = *(const short8*)pBh1;
  short8 rBl0 = *(const short8*)pBl0, rBl1 = *(const short8*)pBl1;
  for (int k0 = 0; k0 < KTOT; k0 += 64) {
    __syncthreads();
    *(short8*)&Ash[ra*72 + pa*8] = rAh0;
    *(short8*)&Ash[rb*72 + pb*8] = rAh1;
    *(short8*)&Asl[ra*72 + pa*8] = rAl0;
    *(short8*)&Asl[rb*72 + pb*8] = rAl1;
    *(short8*)&Bsh[ra*72 + pa*8] = rBh0;
    *(short8*)&Bsh[rb*72 + pb*8] = rBh1;
    *(short8*)&Bsl[ra*72 + pa*8] = rBl0;
    *(short8*)&Bsl[rb*72 + pb*8] = rBl1;
    if (k0 + 64 < KTOT) {
      pAh0 += 64; pAh1 += 64; pAl0 += 64; pAl1 += 64;
      pBh0 += 64; pBh1 += 64; pBl0 += 64; pBl1 += 64;
      rAh0 = *(const short8*)pAh0; rAh1 = *(const short8*)pAh1;
      rAl0 = *(const short8*)pAl0; rAl1 = *(const short8*)pAl1;
      rBh0 = *(const short8*)pBh0; rBh1 = *(const short8*)pBh1;
      rBl0 = *(const short8*)pBl0; rBl1 = *(const short8*)pBl1;
    }
    __syncthreads();
    #pragma unroll
    for (int ks = 0; ks < 2; ++ks) {
      const short8 ah = *(const short8*)&Ash[(wave*16 + m)*72 + ks*32 + quad*8];
      const short8 al = *(const short8*)&Asl[(wave*16 + m)*72 + ks*32 + quad*8];
      #pragma unroll
      for (int ct = 0; ct < 4; ++ct) {
        const short8 bh = *(const short8*)&Bsh[(ct*16 + m)*72 + ks*32 + quad*8];
        const short8 bl = *(const short8*)&Bsl[(ct*16 + m)*72 + ks*32 + quad*8];
        acc[ct] = __builtin_amdgcn_mfma_f32_16x16x32_bf16(ah, bl, acc[ct], 0, 0, 0);
        acc[ct] = __builtin_amdgcn_mfma_f32_16x16x32_bf16(al, bh, acc[ct], 0, 0, 0);
        acc[ct] = __builtin_amdgcn_mfma_f32_16x16x32_bf16(ah, bh, acc[ct], 0, 0, 0);
      }
    }
  }
}

// G1: hidden = relu(gram @ W_g1 + b_g1)
__global__ __launch_bounds__(256) void k_g1(
    const ushort* __restrict__ gram_b, const ushort* __restrict__ Wg1t,
    const float* __restrict__ b_g1, ushort* __restrict__ hidden)
{
  __shared__ __align__(16) ushort As[64*72], Bs[64*72];
  floatx4 acc[4];
  const int bM = blockIdx.x*64, bN = blockIdx.y*64;
  gemm_core<1024>(gram_b, Wg1t, bM, bN, acc, As, Bs);
  const int lane = threadIdx.x & 63, wave = threadIdx.x >> 6;
  const int quad = lane >> 4, m = lane & 15;
  #pragma unroll
  for (int ct = 0; ct < 4; ++ct) {
    const int c = bN + ct*16 + m;
    #pragma unroll
    for (int r = 0; r < 4; ++r) {
      const int i = bM + wave*16 + quad*4 + r;
      hidden[(size_t)i*512 + c] = f2bf(fmaxf(acc[ct][r] + b_g1[c], 0.f));
    }
  }
}

// G2: g2 = hidden @ W_g2 + b_g2 -> hi/lo into h2 cols 0..255
__global__ __launch_bounds__(256) void k_g2(
    const ushort* __restrict__ hidden, const ushort* __restrict__ Wg2t,
    const float* __restrict__ b_g2, ushort* __restrict__ h2h, ushort* __restrict__ h2l)
{
  __shared__ __align__(16) ushort As[64*72], Bs[64*72];
  floatx4 acc[4];
  const int bM = blockIdx.x*64, bN = blockIdx.y*64;
  gemm_core<512>(hidden, Wg2t, bM, bN, acc, As, Bs);
  const int lane = threadIdx.x & 63, wave = threadIdx.x >> 6;
  const int quad = lane >> 4, m = lane & 15;
  #pragma unroll
  for (int ct = 0; ct < 4; ++ct) {
    const int c = bN + ct*16 + m;
    #pragma unroll
    for (int r = 0; r < 4; ++r) {
      const int i = bM + wave*16 + quad*4 + r;
      const float s = acc[ct][r] + b_g2[c];
      const ushort hi = f2bf(s);
      h2h[(size_t)i*512 + c] = hi;
      h2l[(size_t)i*512 + c] = f2bf(s - bf2f(hi));
    }
  }
}

// G3+G4 fused: q/k hi/lo 3-term; v 1-term (bf16-rounded at output anyway); vg 1-term
__global__ __launch_bounds__(256) void k_g34(
    const ushort* __restrict__ h2h, const ushort* __restrict__ h2l,
    const ushort* __restrict__ Wth, const ushort* __restrict__ Wtl,
    const float* __restrict__ b_q, const float* __restrict__ b_k,
    const float* __restrict__ b_v,
    const ushort* __restrict__ g_src_b, const ushort* __restrict__ Wvgt,
    float* __restrict__ q_ws, ushort* __restrict__ kh, ushort* __restrict__ kl,
    ushort* __restrict__ vt)
{
  __shared__ __align__(16) ushort S0[64*72], S1[64*72], S2[64*72], S3[64*72];
  const int lb = blockIdx.y*192 + blockIdx.x;     // grid (192,8) = 1536
  const int lane = threadIdx.x & 63, wave = threadIdx.x >> 6;
  const int quad = lane >> 4, m = lane & 15;
  floatx4 acc[4];
  if (lb < 768) {
    const int bM = (lb & 63)*64, bN = (lb >> 6)*64;
    if (bN < 512) {
      // ---- q/k: 3-term hi/lo ----
      gemm_core3<512>(h2h, h2l, Wth, Wtl, bM, bN, acc, S0, S1, S2, S3);
      #pragma unroll
      for (int ct = 0; ct < 4; ++ct) {
        const int c = bN + ct*16 + m;
        #pragma unroll
        for (int r = 0; r < 4; ++r) {
          const int i = bM + wave*16 + quad*4 + r;
          if (c < 256) {
            const float s = acc[ct][r] + b_q[c];
            q_ws[((size_t)(c >> 5)*N_ + i)*32 + (c & 31)] = s * QSCALE;
          } else {
            const int cc = c - 256;
            const float s = acc[ct][r] + b_k[cc];
            const ushort hi = f2bf(s);
            kh[((size_t)(cc >> 5)*N_ + i)*32 + (cc & 31)] = hi;
            kl[((size_t)(cc >> 5)*N_ + i)*32 + (cc & 31)] = f2bf(s - bf2f(hi));
          }
        }
      }
    } else {
      // ---- v: 1-term bf16 (output is bf16 anyway) ----
      gemm_core<512>(h2h, Wth, bM, bN, acc, S0, S1);
      #pragma unroll
      for (int ct = 0; ct < 4; ++ct) {
        const int cc = bN + ct*16 + m - 512;
        #pragma unroll
        for (int r = 0; r < 4; ++r) {
          const int i = bM + wave*16 + quad*4 + r;
          const float s = acc[ct][r] + b_v[cc];
          vt[((size_t)(cc >> 5)*144 + (cc & 31))*N_ + i] = f2bf(s);
        }
      }
    }
  } else {
    // ---- G4: vg ----
    const int lb2 = lb - 768;
    const int bM = (lb2 >> 2)*64, bN = (lb2 & 3)*64;
    gemm_core<256>(g_src_b, Wvgt, bM, bN, acc, S0, S1);
    #pragma unroll
    for (int ct = 0; ct < 4; ++ct) {
      const int c = bN + ct*16 + m;
      const int hh = c >> 5, d = c & 31;
      #pragma unroll
      for (int r = 0; r < 4; ++r) {
        const int i3 = bM + wave*16 + quad*4 + r;
        const int i = i3 / 3, j = i3 - 3*i;
        vt[((size_t)hh*144 + 32 + j*32 + d)*N_ + i] = f2bf(acc[ct][r]);
      }
    }
  }
}

// ---------------- K3: MFMA flash attention v6 (unchanged from round 9) ----------
__global__ __launch_bounds__(256, 4) void k3_attn(
    const float* __restrict__ q_ws, const ushort* __restrict__ kh,
    const ushort* __restrict__ kl, const ushort* __restrict__ vt,
    ushort* __restrict__ Po0, ushort* __restrict__ Po1, ushort* __restrict__ Po2,
    float* __restrict__ Pml)
{
  __shared__ __align__(16) ushort Khs[64*40], Kls[64*40];
  __shared__ __align__(16) ushort Vs[144*64];
  __shared__ __align__(16) ushort Pl[4*16*72];
  __shared__ float li_s[64];

  const int t    = threadIdx.x;
  const int wave = t >> 6;
  const int lane = t & 63;
  const int quad = lane >> 4;
  const int m    = lane & 15;
  const int h    = blockIdx.y;
  const int s    = blockIdx.z;
  const int n0q  = blockIdx.x * 64;

  const int ktb = (s == 0) ? 0  : (s == 1 ? 22 : 43);
  const int kte = (s == 0) ? 22 : (s == 1 ? 43 : 64);

  union { short8 v; ushort u[8]; } Aqh, Aql;
  {
    const float* qp = q_ws + ((size_t)h*N_ + n0q + wave*16 + m)*32 + quad*8;
    #pragma unroll
    for (int jj = 0; jj < 8; ++jj) {
      const float x = qp[jj];
      const ushort hi = f2bf(x);
      Aqh.u[jj] = hi;
      Aql.u[jj] = f2bf(x - bf2f(hi));
    }
  }

  floatx4 Of[9];
  #pragma unroll
  for (int nt = 0; nt < 9; ++nt) Of[nt] = {0.f, 0.f, 0.f, 0.f};
  float mi[4];
  #pragma unroll
  for (int r = 0; r < 4; ++r) mi[r] = -3.0e38f;

  const int krow = t >> 2, kch = (t & 3) * 8;

  const ushort* pKh = kh + ((size_t)h*N_ + ktb*64 + krow)*32 + kch;
  const ushort* pKl = kl + ((size_t)h*N_ + ktb*64 + krow)*32 + kch;
  const ushort* pV[4];
  int wV[4];
  #pragma unroll
  for (int p = 0; p < 4; ++p) {
    const int idx = p*256 + t, row = idx >> 3, g = idx & 7;
    pV[p] = vt + ((size_t)h*144 + row)*N_ + ktb*64 + g*8;
    wV[p] = (row*8 + (g ^ (row & 7)))*8;
  }
  const ushort* pV4 = nullptr;
  int wV4 = 0;
  if (t < 128) {
    const int idx = 1024 + t, row = idx >> 3, g = idx & 7;
    pV4 = vt + ((size_t)h*144 + row)*N_ + ktb*64 + g*8;
    wV4 = (row*8 + (g ^ (row & 7)))*8;
  }

  short8 rK0 = *(const short8*)pKh;
  short8 rK1 = *(const short8*)pKl;
  short8 rV[4], rV4e;
  #pragma unroll
  for (int p = 0; p < 4; ++p) rV[p] = *(const short8*)pV[p];
  if (t < 128) rV4e = *(const short8*)pV4;

  for (int kt = ktb; kt < kte; ++kt) {
    __syncthreads();
    *(short8*)&Khs[krow*40 + kch] = rK0;
    *(short8*)&Kls[krow*40 + kch] = rK1;
    #pragma unroll
    for (int p = 0; p < 4; ++p) *(short8*)&Vs[wV[p]] = rV[p];
    if (t < 128) *(short8*)&Vs[wV4] = rV4e;
    if (kt + 1 < kte) {
      pKh += 2048; pKl += 2048;
      rK0 = *(const short8*)pKh;
      rK1 = *(const short8*)pKl;
      #pragma unroll
      for (int p = 0; p < 4; ++p) { pV[p] += 64; rV[p] = *(const short8*)pV[p]; }
      if (t < 128) { pV4 += 64; rV4e = *(const short8*)pV4; }
    }
    __syncthreads();

    floatx4 sf[4];
    #pragma unroll
    for (int kb = 0; kb < 4; ++kb) {
      const short8 bkh = *(const short8*)&Khs[(kb*16 + m)*40 + quad*8];
      const short8 bkl = *(const short8*)&Kls[(kb*16 + m)*40 + quad*8];
      floatx4 sv = {0.f, 0.f, 0.f, 0.f};
      sv = __builtin_amdgcn_mfma_f32_16x16x32_bf16(Aqh.v, bkl, sv, 0, 0, 0);
      sv = __builtin_amdgcn_mfma_f32_16x16x32_bf16(Aql.v, bkh, sv, 0, 0, 0);
      sv = __builtin_amdgcn_mfma_f32_16x16x32_bf16(Aqh.v, bkh, sv, 0, 0, 0);
      sf[kb] = sv;
    }

    float tm[4];
    bool need = false;
    #pragma unroll
    for (int r = 0; r < 4; ++r) {
      float nm = fmaxf(fmaxf(sf[0][r], sf[1][r]), fmaxf(sf[2][r], sf[3][r]));
      tm[r] = dpp_max16(nm);
      need |= (tm[r] > mi[r] + 20.f);
    }
    if (__any(need)) {
      #pragma unroll
      for (int r = 0; r < 4; ++r) {
        const float mn = fmaxf(mi[r], tm[r]);
        const float al = exp2f(mi[r] - mn);
        mi[r] = mn;
        #pragma unroll
        for (int nt = 0; nt < 9; ++nt) Of[nt][r] *= al;
      }
    }
    #pragma unroll
    for (int kb = 0; kb < 4; ++kb)
      #pragma unroll
      for (int r = 0; r < 4; ++r) {
        const float pv = exp2f(sf[kb][r] - mi[r]);
        Pl[wave*1152 + (quad*4 + r)*72 + kb*16 + m] =
            (ushort)(__float_as_uint(pv) >> 16);
      }

    #pragma unroll
    for (int ks = 0; ks < 2; ++ks) {
      const short8 ap = *(const short8*)&Pl[wave*1152 + m*72 + ks*32 + quad*8];
      #pragma unroll
      for (int nt = 0; nt < 9; ++nt) {
        const int row = nt*16 + m;
        const int pos = (ks*4 + quad) ^ (row & 7);
        const short8 bv = *(const short8*)&Vs[(row*8 + pos)*8];
        Of[nt] = __builtin_amdgcn_mfma_f32_16x16x32_bf16(ap, bv, Of[nt], 0, 0, 0);
      }
    }
  }

  if (m == 0) {
    #pragma unroll
    for (int r = 0; r < 4; ++r) li_s[wave*16 + quad*4 + r] = Of[8][r];
  }
  __syncthreads();
  const floatx4 liv = *(const floatx4*)&li_s[wave*16 + quad*4];
  float linv[4];
  #pragma unroll
  for (int r = 0; r < 4; ++r) linv[r] = 1.0f / liv[r];

  ushort* Po = (s == 0) ? Po0 : ((s == 1) ? Po1 : Po2);
  #pragma unroll
  for (int nt = 0; nt < 8; ++nt) {
    #pragma unroll
    for (int r = 0; r < 4; ++r) {
      const int n = n0q + wave*16 + quad*4 + r;
      Po[((size_t)h*N_ + n)*128 + nt*16 + m] = f2bf(Of[nt][r] * linv[r]);
    }
  }
  if (m == 0) {
    #pragma unroll
    for (int r = 0; r < 4; ++r) {
      const int n = n0q + wave*16 + quad*4 + r;
      Pml[(((size_t)s*8 + h)*N_ + n)*2 + 0] = mi[r];
      Pml[(((size_t)s*8 + h)*N_ + n)*2 + 1] = Of[8][r];
    }
  }
}

// ---------------- merge: combine 3 split-K partials (8 elems/thread) ------------
__global__ __launch_bounds__(256) void k_merge(
    const ushort* __restrict__ Po0, const ushort* __restrict__ Po1,
    const ushort* __restrict__ Po2, const float* __restrict__ Pml,
    ushort* __restrict__ out_v_b, ushort* __restrict__ out_g_b)
{
  const int idx = blockIdx.x*256 + threadIdx.x;
  const int c0 = (idx & 15) * 8;
  const int n  = (idx >> 4) & 4095;
  const int h  = idx >> 16;
  const float m1 = Pml[(((size_t)0*8 + h)*N_ + n)*2 + 0];
  const float l1 = Pml[(((size_t)0*8 + h)*N_ + n)*2 + 1];
  const float m2 = Pml[(((size_t)1*8 + h)*N_ + n)*2 + 0];
  const float l2 = Pml[(((size_t)1*8 + h)*N_ + n)*2 + 1];
  const float m3 = Pml[(((size_t)2*8 + h)*N_ + n)*2 + 0];
  const float l3 = Pml[(((size_t)2*8 + h)*N_ + n)*2 + 1];
  const float M = fmaxf(fmaxf(m1, m2), m3);
  const float w1 = exp2f(m1 - M) * l1;
  const float w2 = exp2f(m2 - M) * l2;
  const float w3 = exp2f(m3 - M) * l3;
  const float inv = 1.0f / (w1 + w2 + w3);
  union { short8 v; ushort u[8]; } a, b, c, res;
  a.v = *(const short8*)&Po0[((size_t)h*N_ + n)*128 + c0];
  b.v = *(const short8*)&Po1[((size_t)h*N_ + n)*128 + c0];
  c.v = *(const short8*)&Po2[((size_t)h*N_ + n)*128 + c0];
  #pragma unroll
  for (int j = 0; j < 8; ++j)
    res.u[j] = f2bf((w1*bf2f(a.u[j]) + w2*bf2f(b.u[j]) + w3*bf2f(c.u[j])) * inv);
  if (c0 < 32) {
    *(short8*)&out_v_b[(size_t)n*256 + h*32 + c0] = res.v;
  } else {
    const int j = (c0 - 32) >> 5, cc = (c0 - 32) & 31;
    *(short8*)&out_g_b[((size_t)n*3 + j)*256 + h*32 + cc] = res.v;
  }
}

// ---------------- k5a+k5b fused ----------------
__global__ __launch_bounds__(256) void k56ab(
    const ushort* __restrict__ out_v_b, const ushort* __restrict__ Wngt,
    const float* __restrict__ b_ng, const float* __restrict__ h,
    ushort* __restrict__ tmp_b,
    const ushort* __restrict__ out_g_b, const ushort* __restrict__ Wgoutt,
    const ushort* __restrict__ g_src_b, ushort* __restrict__ gsum_b)
{
  __shared__ __align__(16) ushort As[64*72], Bs[64*72];
  floatx4 acc[4];
  const int lane = threadIdx.x & 63, wave = threadIdx.x >> 6;
  const int quad = lane >> 4, m = lane & 15;
  const int bN = blockIdx.y*64;
  if (blockIdx.x < 64) {
    const int bM = blockIdx.x*64;
    gemm_core<256>(out_v_b, Wngt, bM, bN, acc, As, Bs);
    #pragma unroll
    for (int ct = 0; ct < 4; ++ct) {
      const int c = bN + ct*16 + m;
      #pragma unroll
      for (int r = 0; r < 4; ++r) {
        const int i = bM + wave*16 + quad*4 + r;
        tmp_b[(size_t)i*256 + c] =
            f2bf(acc[ct][r] + b_ng[c] + h[(size_t)i*256 + c] * SQRT_E);
      }
    }
  } else {
    const int bM = (blockIdx.x - 64)*64;
    gemm_core<256>(out_g_b, Wgoutt, bM, bN, acc, As, Bs);
    #pragma unroll
    for (int ct = 0; ct < 4; ++ct) {
      const int c = bN + ct*16 + m;
      #pragma unroll
      for (int r = 0; r < 4; ++r) {
        const int i = bM + wave*16 + quad*4 + r;
        gsum_b[(size_t)i*256 + c] =
            f2bf(acc[ct][r] + bf2f(g_src_b[(size_t)i*256 + c]));
      }
    }
  }
}

// ---------------- k5c+k5d fused ----------------
__global__ __launch_bounds__(256) void k56cd(
    const ushort* __restrict__ tmp_b, const ushort* __restrict__ Whdect,
    const float* __restrict__ b_hdec,
    const ushort* __restrict__ gsum_b, const ushort* __restrict__ Wgdect,
    float* __restrict__ out)
{
  __shared__ __align__(16) ushort As[64*72], Bs[64*72];
  const int t = threadIdx.x;
  const int lane = t & 63, wave = t >> 6;
  const int quad = lane >> 4, m = lane & 15;
  if (blockIdx.x < 64) {
    floatx4 acc[4];
    const int bM = blockIdx.x*64, bN = blockIdx.y*64;
    gemm_core<256>(tmp_b, Whdect, bM, bN, acc, As, Bs);
    #pragma unroll
    for (int ct = 0; ct < 4; ++ct) {
      const int c = bN + ct*16 + m;
      #pragma unroll
      for (int r = 0; r < 4; ++r) {
        const int i = bM + wave*16 + quad*4 + r;
        out[196608 + (size_t)i*256 + c] = acc[ct][r] + b_hdec[c];
      }
    }
  } else if (blockIdx.y == 0) {
    const int bM = (blockIdx.x - 64)*64;
    floatx4 acc = {0.f, 0.f, 0.f, 0.f};
    const int row = t >> 2, kq = (t & 3) * 8;
    for (int k0 = 0; k0 < 256; k0 += 32) {
      __syncthreads();
      *(short8*)&As[row*40 + kq] = *(const short8*)&gsum_b[(size_t)(bM+row)*256 + k0 + kq];
      if (t < 64)
        *(short8*)&Bs[(t>>2)*40 + kq] = *(const short8*)&Wgdect[(size_t)(t>>2)*256 + k0 + kq];
      __syncthreads();
      const short8 af = *(const short8*)&As[(wave*16 + m)*40 + quad*8];
      const short8 bf = *(const short8*)&Bs[m*40 + quad*8];
      acc = __builtin_amdgcn_mfma_f32_16x16x32_bf16(af, bf, acc, 0, 0, 0);
    }
    #pragma unroll
    for (int r = 0; r < 4; ++r)
      out[(size_t)(bM + wave*16 + quad*4 + r)*16 + m] = acc[r];
  }
}

extern "C" void kernel_launch(void* const* d_in, const int* in_sizes, int n_in,
                              void* d_out, int out_size, void* d_ws, size_t ws_size,
                              hipStream_t stream) {
  const float* equ    = (const float*)d_in[0];
  const float* h      = (const float*)d_in[1];
  const float* W_equ  = (const float*)d_in[4];
  const float* W_gproj= (const float*)d_in[5];
  const float* W_vg   = (const float*)d_in[6];
  const float* W_g1   = (const float*)d_in[7];
  const float* b_g1   = (const float*)d_in[8];
  const float* W_g2   = (const float*)d_in[9];
  const float* b_g2   = (const float*)d_in[10];
  const float* W_q    = (const float*)d_in[11];
  const float* b_q    = (const float*)d_in[12];
  const float* W_k    = (const float*)d_in[13];
  const float* b_k    = (const float*)d_in[14];
  const float* W_v    = (const float*)d_in[15];
  const float* b_v    = (const float*)d_in[16];
  const float* W_ng   = (const float*)d_in[17];
  const float* b_ng   = (const float*)d_in[18];
  const float* W_gout = (const float*)d_in[19];
  const float* W_gdec = (const float*)d_in[20];
  const float* W_hdec = (const float*)d_in[21];
  const float* b_hdec = (const float*)d_in[22];
  float* out = (float*)d_out;

  // ---- workspace layout (lifetimes annotated), peak 51.25 MiB (52 proven) ----
  char* wsb = (char*)d_ws;
  constexpr size_t MiB = 1048576;
  float*  q_ws    = (float*) (wsb +  0*MiB);            // 4 MiB [g34 -> k3]
  ushort* kh      = (ushort*)(wsb +  4*MiB);            // 2 MiB [g34 -> k3]
  ushort* kl      = (ushort*)(wsb +  6*MiB);            // 2 MiB [g34 -> k3]
  ushort* vt      = (ushort*)(wsb +  8*MiB);            // 9 MiB [prep/g34 -> k3]
  ushort* h2h     = (ushort*)(wsb + 17*MiB);            // 4 MiB [prep/g2 -> g34]
  ushort* h2l     = (ushort*)(wsb + 21*MiB);            // 4 MiB
  ushort* g_src_b = (ushort*)(wsb + 25*MiB);            // 6 MiB [prep -> g34,k56ab]
  ushort* wbase   = (ushort*)(wsb + 31*MiB);            // 2.875 MiB [prep -> g34]
  ushort* Wg1t = wbase;                                 // 512x1024
  ushort* Wg2t = wbase + 524288;                        // 256x512
  ushort* Wth  = wbase + 655360;                        // 768x512 hi
  ushort* Wtl  = wbase + 1048576;                       // 768x512 lo
  ushort* Wvgt = wbase + 1441792;                       // 256x256
  ushort* wbase2  = (ushort*)(wsb + 34*MiB);            // 0.4 MiB [prep -> k56*]
  ushort* Wngt   = wbase2;                              // 256x256
  ushort* Wgoutt = wbase2 + 65536;                      // 256x256
  ushort* Whdect = wbase2 + 131072;                     // 256x256
  ushort* Wgdect = wbase2 + 196608;                     // 16x256
  ushort* gram_b  = (ushort*)(wsb + 34*MiB + 524288);   // 8 MiB [prep -> g1]
  ushort* hidden  = (ushort*)(wsb + 42*MiB + 524288);   // 4 MiB [g1 -> g2]
  // split-K x3 attention partials (all alias dead regions):
  ushort* Po0     = (ushort*)(wsb + 17*MiB);            // 8 MiB [k3 -> merge] alias h2h/h2l
  ushort* Po1     = (ushort*)(wsb + 34*MiB + 524288);   // 8 MiB [k3 -> merge] alias gram_b
  ushort* Po2     = (ushort*)(wsb + 42*MiB + 524288);   // 8 MiB [k3 -> merge] alias hidden+
  float*  Pml     = (float*) (wsb + 50*MiB + 524288);   // 0.75 MiB [k3 -> merge]
  ushort* out_v_b = (ushort*)(wsb +  4*MiB);            // 2 MiB [merge -> k56ab] alias kh/kl
  ushort* out_g_b = (ushort*)(wsb +  8*MiB);            // 6 MiB [merge -> k56ab] alias vt
  ushort* tmp_b   = (ushort*)(wsb + 42*MiB + 524288);   // 2 MiB [k56ab -> k56cd] alias Po2
  ushort* gsum_b  = (ushort*)(wsb + 34*MiB + 524288);   // 6 MiB [k56ab -> k56cd] alias Po1

  // ---- 1 mega-prep launch (10 transposes + hsplit + vinit + k1) ----
  k_prep<<<11528, 256, 0, stream>>>(
      equ, h, W_equ, W_gproj, W_g1, W_g2, W_q, W_k, W_v,
      W_vg, W_ng, W_gout, W_hdec, W_gdec,
      Wg1t, Wg2t, Wth, Wtl, Wvgt, Wngt, Wgoutt, Whdect, Wgdect,
      h2h, h2l, vt, g_src_b, gram_b);

  // ---- GEMM chain (BK=64 double-pumped cores) ----
  k_g1<<<dim3(64, 8), 256, 0, stream>>>(gram_b, Wg1t, b_g1, hidden);
  k_g2<<<dim3(64, 4), 256, 0, stream>>>(hidden, Wg2t, b_g2, h2h, h2l);
  k_g34<<<dim3(192, 8), 256, 0, stream>>>(h2h, h2l, Wth, Wtl, b_q, b_k, b_v,
                                          g_src_b, Wvgt, q_ws, kh, kl, vt);

  // ---- attention (split-K x3) + merge ----
  dim3 g3(64, 8, 3);
  k3_attn<<<g3, 256, 0, stream>>>(q_ws, kh, kl, vt, Po0, Po1, Po2, Pml);
  k_merge<<<2048, 256, 0, stream>>>(Po0, Po1, Po2, Pml, out_v_b, out_g_b);

  // ---- epilogue GEMMs (fused pairs) ----
  k56ab<<<dim3(256, 4), 256, 0, stream>>>(out_v_b, Wngt, b_ng, h, tmp_b,
                                          out_g_b, Wgoutt, g_src_b, gsum_b);
  k56cd<<<dim3(256, 4), 256, 0, stream>>>(tmp_b, Whdect, b_hdec,
                                          gsum_b, Wgdect, out);
}